// Round 2
// baseline (3608.240 us; speedup 1.0000x reference)
//
#include <hip/hip_runtime.h>
#include <math.h>

#define NN   20000
#define EE   320000
#define ELG  600000
#define FE   64
#define HD   256
#define FOUT 40
#define MLG  (ELG + EE)

__device__ __forceinline__ float leaky02(float x) { return x > 0.f ? x : 0.2f * x; }

__device__ __forceinline__ void atomicMaxF(float* addr, float val) {
    unsigned int* ua = (unsigned int*)addr;
    unsigned int old = *ua;
    while (__uint_as_float(old) < val) {
        unsigned int assumed = old;
        old = atomicCAS(ua, assumed, __float_as_uint(val));
        if (old == assumed) break;
    }
}

__global__ void fill_f32(float* __restrict__ p, float v, int n) {
    int i = blockIdx.x * 256 + threadIdx.x;
    if (i < n) p[i] = v;
}

__global__ void copy_f32(float* __restrict__ d, const float* __restrict__ s, int n) {
    int i = blockIdx.x * 256 + threadIdx.x;
    if (i < n) d[i] = s[i];
}

// C[M,N] = A[M,K] @ B[K,N] (+C if flags&1) (+bias if bias) (relu if flags&2) (leaky if flags&4)
__global__ __launch_bounds__(256)
void gemm_f32(const float* __restrict__ A, const float* __restrict__ B,
              const float* __restrict__ bias, float* __restrict__ C,
              int M, int N, int K, int flags) {
    const int BM = 64, BN = 64, BK = 16;
    __shared__ float As[BK][BM + 1];
    __shared__ float Bs[BK][BN + 1];
    int tid = threadIdx.x;
    int tr = tid >> 4, tc = tid & 15;
    int brow = blockIdx.y * BM, bcol = blockIdx.x * BN;
    float acc[4][4] = {{0.f}};
    for (int k0 = 0; k0 < K; k0 += BK) {
#pragma unroll
        for (int i = 0; i < 4; ++i) {
            int e = tid + i * 256;
            int r = e >> 4, c = e & 15;
            int gr = brow + r, gc = k0 + c;
            As[c][r] = (gr < M && gc < K) ? A[(long)gr * K + gc] : 0.f;
        }
#pragma unroll
        for (int i = 0; i < 4; ++i) {
            int e = tid + i * 256;
            int r = e >> 6, c = e & 63;
            int gr = k0 + r, gc = bcol + c;
            Bs[r][c] = (gr < K && gc < N) ? B[(long)gr * N + gc] : 0.f;
        }
        __syncthreads();
#pragma unroll
        for (int k = 0; k < BK; ++k) {
            float ra[4], rb[4];
#pragma unroll
            for (int i = 0; i < 4; ++i) ra[i] = As[k][tr * 4 + i];
#pragma unroll
            for (int j = 0; j < 4; ++j) rb[j] = Bs[k][tc * 4 + j];
#pragma unroll
            for (int i = 0; i < 4; ++i)
#pragma unroll
                for (int j = 0; j < 4; ++j) acc[i][j] += ra[i] * rb[j];
        }
        __syncthreads();
    }
#pragma unroll
    for (int i = 0; i < 4; ++i) {
        int gr = brow + tr * 4 + i;
        if (gr >= M) continue;
#pragma unroll
        for (int j = 0; j < 4; ++j) {
            int gc = bcol + tc * 4 + j;
            if (gc >= N) continue;
            float v = acc[i][j];
            if (flags & 1) v += C[(long)gr * N + gc];
            if (bias) v += bias[gc];
            if (flags & 2) v = fmaxf(v, 0.f);
            if (flags & 4) v = leaky02(v);
            C[(long)gr * N + gc] = v;
        }
    }
}

// asv[i] = sum_j W[i,j]*a_s[j]; adv likewise. grid=FE blocks, 256 threads.
__global__ void wg_av(const float* __restrict__ W, const float* __restrict__ as_,
                      const float* __restrict__ ad_, float* __restrict__ asv,
                      float* __restrict__ adv) {
    __shared__ float sm[256];
    int i = blockIdx.x, t = threadIdx.x;
    float w = W[i * HD + t];
    sm[t] = w * as_[t];
    __syncthreads();
    for (int o = 128; o > 0; o >>= 1) { if (t < o) sm[t] += sm[t + o]; __syncthreads(); }
    if (t == 0) asv[i] = sm[0];
    __syncthreads();
    sm[t] = w * ad_[t];
    __syncthreads();
    for (int o = 128; o > 0; o >>= 1) { if (t < o) sm[t] += sm[t + o]; __syncthreads(); }
    if (t == 0) adv[i] = sm[0];
}

// b2[j] = sum_i b[i] * W[i*HD + j]; one block of 256
__global__ void bias_proj(const float* __restrict__ b, const float* __restrict__ W,
                          float* __restrict__ b2) {
    int j = threadIdx.x;
    float s = 0.f;
    for (int i = 0; i < HD; ++i) s += b[i] * W[i * HD + j];
    b2[j] = s;
}

// es[e] = et[e,:]@asv ; ed[e] = et[e,:]@adv  (wave per edge)
__global__ void edge_scores(const float* __restrict__ et, const float* __restrict__ asv,
                            const float* __restrict__ adv, float* __restrict__ es,
                            float* __restrict__ ed) {
    int e = blockIdx.x * 4 + (threadIdx.x >> 6);
    int l = threadIdx.x & 63;
    float x = et[(long)e * FE + l];
    float vs = x * asv[l];
    float vd = x * adv[l];
    for (int o = 32; o > 0; o >>= 1) { vs += __shfl_down(vs, o); vd += __shfl_down(vd, o); }
    if (l == 0) { es[e] = vs; ed[e] = vd; }
}

__global__ void gat_max(const int* __restrict__ lgs, const int* __restrict__ lgd,
                        const float* __restrict__ es, const float* __restrict__ ed,
                        float* __restrict__ m) {
    int j = blockIdx.x * 256 + threadIdx.x;
    if (j >= MLG) return;
    int s, d;
    if (j < ELG) { s = lgs[j]; d = lgd[j]; } else { s = d = j - ELG; }
    atomicMaxF(&m[d], leaky02(es[s] + ed[d]));
}

__global__ void gat_sum(const int* __restrict__ lgs, const int* __restrict__ lgd,
                        const float* __restrict__ es, const float* __restrict__ ed,
                        const float* __restrict__ m, float* __restrict__ ssum) {
    int j = blockIdx.x * 256 + threadIdx.x;
    if (j >= MLG) return;
    int s, d;
    if (j < ELG) { s = lgs[j]; d = lgd[j]; } else { s = d = j - ELG; }
    float sc = leaky02(es[s] + ed[d]);
    atomicAdd(&ssum[d], expf(sc - m[d]));
}

// agg_et[d,:] += alpha * et[s,:]   (64 lanes per lg-edge)
__global__ void gat_aggr_et(const int* __restrict__ lgs, const int* __restrict__ lgd,
                            const float* __restrict__ es, const float* __restrict__ ed,
                            const float* __restrict__ m, const float* __restrict__ ssum,
                            const float* __restrict__ et, float* __restrict__ agg) {
    int j = blockIdx.x * 4 + (threadIdx.x >> 6);
    int t = threadIdx.x & 63;
    if (j >= MLG) return;
    int s, d;
    if (j < ELG) { s = lgs[j]; d = lgd[j]; } else { s = d = j - ELG; }
    float sc = leaky02(es[s] + ed[d]);
    float alpha = expf(sc - m[d]) / (ssum[d] + 1e-16f);
    atomicAdd(&agg[(long)d * FE + t], alpha * et[(long)s * FE + t]);
}

// agg2[H0[e],:] += agg_et[e,:]; agg2[H1[e],:] += agg_et[e,:]; degE counts
__global__ void etn_scatter64(const float* __restrict__ agg_et, const int* __restrict__ Hm,
                              float* __restrict__ agg2, float* __restrict__ degE) {
    int e = blockIdx.x * 4 + (threadIdx.x >> 6);
    int t = threadIdx.x & 63;
    int n0 = Hm[e], n1 = Hm[EE + e];
    float v = agg_et[(long)e * FE + t];
    atomicAdd(&agg2[(long)n0 * FE + t], v);
    atomicAdd(&agg2[(long)n1 * FE + t], v);
    if (t == 0) { atomicAdd(&degE[n0], 1.f); atomicAdd(&degE[n1], 1.f); }
}

__global__ void div_by_deg(float* __restrict__ p, const float* __restrict__ deg, int sh, int n) {
    int i = blockIdx.x * 256 + threadIdx.x;
    if (i < n) p[i] /= fmaxf(deg[i >> sh], 1.f);
}

// etn rows with deg==0 must be exactly 0 (kill the b2 bias), then leaky
__global__ void etn_mask_leaky(float* __restrict__ p, const float* __restrict__ deg, int n) {
    int i = blockIdx.x * 256 + threadIdx.x;
    if (i >= n) return;
    float v = (deg[i >> 8] > 0.f) ? p[i] : 0.f;
    p[i] = leaky02(v);
}

__global__ void count_deg(const int* __restrict__ dst, float* __restrict__ deg, int n) {
    int e = blockIdx.x * 256 + threadIdx.x;
    if (e < n) atomicAdd(&deg[dst[e]], 1.f);
}

// mean[dst[e],:] += X[src[e],:]  (256 lanes per edge)
__global__ void scatter256(const float* __restrict__ X, const int* __restrict__ src,
                           const int* __restrict__ dst, float* __restrict__ mean) {
    int e = blockIdx.x;
    int t = threadIdx.x;
    int s = src[e], d = dst[e];
    atomicAdd(&mean[(long)d * HD + t], X[(long)s * HD + t]);
}

// sc[e] = (q[dst[e],:] . k[src[e],:]) / 16
__global__ void attn_scores(const float* __restrict__ q, const float* __restrict__ k,
                            const int* __restrict__ src, const int* __restrict__ dst,
                            float* __restrict__ sc) {
    int e = blockIdx.x * 4 + (threadIdx.x >> 6);
    int l = threadIdx.x & 63;
    int s = src[e], d = dst[e];
    float4 qa = ((const float4*)(q + (long)d * HD))[l];
    float4 kb = ((const float4*)(k + (long)s * HD))[l];
    float v = qa.x * kb.x + qa.y * kb.y + qa.z * kb.z + qa.w * kb.w;
    for (int o = 32; o > 0; o >>= 1) v += __shfl_down(v, o);
    if (l == 0) sc[e] = v * (1.f / 16.f);
}

__global__ void seg_max_edge(const float* __restrict__ sc, const int* __restrict__ dst,
                             float* __restrict__ m, int n) {
    int e = blockIdx.x * 256 + threadIdx.x;
    if (e < n) atomicMaxF(&m[dst[e]], sc[e]);
}

__global__ void seg_sumexp_edge(const float* __restrict__ sc, const int* __restrict__ dst,
                                const float* __restrict__ m, float* __restrict__ s, int n) {
    int e = blockIdx.x * 256 + threadIdx.x;
    if (e < n) atomicAdd(&s[dst[e]], expf(sc[e] - m[dst[e]]));
}

// mixed[dst[e],:] += alpha * v[src[e],:]
__global__ void attn_aggr(const float* __restrict__ sc, const int* __restrict__ src,
                          const int* __restrict__ dst, const float* __restrict__ m,
                          const float* __restrict__ s, const float* __restrict__ v,
                          float* __restrict__ mixed) {
    int e = blockIdx.x;
    int t = threadIdx.x;
    int ss = src[e], d = dst[e];
    float alpha = expf(sc[e] - m[d]) / (s[d] + 1e-16f);
    atomicAdd(&mixed[(long)d * HD + t], alpha * v[(long)ss * HD + t]);
}

__global__ void log_softmax_rows(float* __restrict__ out, int nrows) {
    int r = blockIdx.x * 256 + threadIdx.x;
    if (r >= nrows) return;
    float* p = out + (long)r * FOUT;
    float mx = -INFINITY;
    for (int i = 0; i < FOUT; ++i) mx = fmaxf(mx, p[i]);
    float s = 0.f;
    for (int i = 0; i < FOUT; ++i) s += expf(p[i] - mx);
    float ls = mx + logf(s);
    for (int i = 0; i < FOUT; ++i) p[i] -= ls;
}

extern "C" void kernel_launch(void* const* d_in, const int* in_sizes, int n_in,
                              void* d_out, int out_size, void* d_ws, size_t ws_size,
                              hipStream_t stream) {
    (void)in_sizes; (void)n_in; (void)out_size; (void)ws_size;
    const float* x     = (const float*)d_in[0];
    const float* et    = (const float*)d_in[1];
    const int*   Hm    = (const int*)d_in[2];
    const int*   raw   = (const int*)d_in[3];
    const int*   lg    = (const int*)d_in[4];
    const float* W_gat = (const float*)d_in[5];
    const float* a_src = (const float*)d_in[6];
    const float* a_dst = (const float*)d_in[7];
    const float* b_gat = (const float*)d_in[8];
    const float* W_etn = (const float*)d_in[9];
    const float* W_eg  = (const float*)d_in[10];
    const float* Wr_e1 = (const float*)d_in[11];
    const float* Wn_e1 = (const float*)d_in[12];
    const float* b_e1  = (const float*)d_in[13];
    const float* Wr_e2 = (const float*)d_in[14];
    const float* Wn_e2 = (const float*)d_in[15];
    const float* b_e2  = (const float*)d_in[16];
    const float* Wr_n1 = (const float*)d_in[17];
    const float* Wn_n1 = (const float*)d_in[18];
    const float* b_n1  = (const float*)d_in[19];
    const float* Wr_n2 = (const float*)d_in[20];
    const float* Wn_n2 = (const float*)d_in[21];
    const float* b_n2  = (const float*)d_in[22];
    const float* Wr_n3 = (const float*)d_in[23];
    const float* Wn_n3 = (const float*)d_in[24];
    const float* b_n3  = (const float*)d_in[25];
    const float* Wq    = (const float*)d_in[26];
    const float* Wk    = (const float*)d_in[27];
    const float* Wv    = (const float*)d_in[28];
    const float* W_out = (const float*)d_in[29];

    const int* srcN = raw;
    const int* dstN = raw + EE;
    const int* lgs  = lg;
    const int* lgd  = lg + ELG;

    float* ws = (float*)d_ws;
    size_t off = 0;
    auto alloc = [&](size_t n) { float* p = ws + off; off += (n + 63) & ~(size_t)63; return p; };

    float* agg_et = alloc((size_t)EE * FE);
    float* es     = alloc(EE);
    float* ed     = alloc(EE);
    float* mseg   = alloc(EE);
    float* sseg   = alloc(EE);
    float* Wcomb  = alloc((size_t)FE * HD);
    float* b2     = alloc(HD);
    float* asv    = alloc(FE);
    float* adv    = alloc(FE);
    float* agg2   = alloc((size_t)NN * FE);
    float* degE   = alloc(NN);
    float* etnL   = alloc((size_t)NN * HD);
    float* erep   = alloc((size_t)NN * HD);
    float* meanb  = alloc((size_t)NN * HD);
    float* t1     = alloc((size_t)NN * HD);
    float* aggr   = alloc((size_t)NN * HD);
    float* nrep   = alloc((size_t)NN * HD);
    float* qb     = alloc((size_t)NN * HD);
    float* kb     = alloc((size_t)NN * HD);
    float* vb     = alloc((size_t)NN * HD);
    float* degN   = alloc(NN);
    float* scb    = alloc(EE);
    float* mN     = alloc(NN);
    float* sN     = alloc(NN);
    float* ta     = etnL;  // attr-stack hidden 1 (etnL dead after erep GEMM)
    float* tb     = erep;  // attr-stack hidden 2 (erep dead after edge layer 1)
    float* mixed  = kb;    // kb dead after attn_scores
    float* outp   = (float*)d_out;

    dim3 g64x64((HD + 63) / 64, (NN + 63) / 64);

    // ---- GAT (line graph) with algebraic folding: W_comb = W_gat @ W_etn ----
    gemm_f32<<<dim3((HD + 63) / 64, (FE + 63) / 64), 256, 0, stream>>>(W_gat, W_etn, nullptr, Wcomb, FE, HD, HD, 0);
    bias_proj<<<1, 256, 0, stream>>>(b_gat, W_etn, b2);
    wg_av<<<FE, 256, 0, stream>>>(W_gat, a_src, a_dst, asv, adv);
    edge_scores<<<EE / 4, 256, 0, stream>>>(et, asv, adv, es, ed);
    fill_f32<<<(EE + 255) / 256, 256, 0, stream>>>(mseg, -INFINITY, EE);
    fill_f32<<<(EE + 255) / 256, 256, 0, stream>>>(sseg, 0.f, EE);
    fill_f32<<<(EE * FE + 255) / 256, 256, 0, stream>>>(agg_et, 0.f, EE * FE);
    gat_max<<<(MLG + 255) / 256, 256, 0, stream>>>(lgs, lgd, es, ed, mseg);
    gat_sum<<<(MLG + 255) / 256, 256, 0, stream>>>(lgs, lgd, es, ed, mseg, sseg);
    gat_aggr_et<<<(MLG + 3) / 4, 256, 0, stream>>>(lgs, lgd, es, ed, mseg, sseg, et, agg_et);

    // ---- EdgeToNode incidence aggregation (in 64-dim space) ----
    fill_f32<<<(NN * FE + 255) / 256, 256, 0, stream>>>(agg2, 0.f, NN * FE);
    fill_f32<<<(NN + 255) / 256, 256, 0, stream>>>(degE, 0.f, NN);
    etn_scatter64<<<EE / 4, 256, 0, stream>>>(agg_et, Hm, agg2, degE);
    div_by_deg<<<(NN * FE + 255) / 256, 256, 0, stream>>>(agg2, degE, 6, NN * FE);
    gemm_f32<<<g64x64, 256, 0, stream>>>(agg2, Wcomb, b2, etnL, NN, HD, FE, 0);
    etn_mask_leaky<<<(NN * HD + 255) / 256, 256, 0, stream>>>(etnL, degE, NN * HD);
    gemm_f32<<<g64x64, 256, 0, stream>>>(etnL, W_eg, nullptr, erep, NN, HD, HD, 0);

    // ---- degree of raw graph (shared by all SAGE layers + attention) ----
    fill_f32<<<(NN + 255) / 256, 256, 0, stream>>>(degN, 0.f, NN);
    count_deg<<<(EE + 255) / 256, 256, 0, stream>>>(dstN, degN, EE);

    // ---- edge_aggr SAGE layer 1 (relu) ----
    fill_f32<<<(NN * HD + 255) / 256, 256, 0, stream>>>(meanb, 0.f, NN * HD);
    scatter256<<<EE, 256, 0, stream>>>(erep, srcN, dstN, meanb);
    div_by_deg<<<(NN * HD + 255) / 256, 256, 0, stream>>>(meanb, degN, 8, NN * HD);
    gemm_f32<<<g64x64, 256, 0, stream>>>(erep, Wr_e1, nullptr, t1, NN, HD, HD, 0);
    gemm_f32<<<g64x64, 256, 0, stream>>>(meanb, Wn_e1, b_e1, t1, NN, HD, HD, 3);
    // ---- edge_aggr SAGE layer 2 ----
    fill_f32<<<(NN * HD + 255) / 256, 256, 0, stream>>>(meanb, 0.f, NN * HD);
    scatter256<<<EE, 256, 0, stream>>>(t1, srcN, dstN, meanb);
    div_by_deg<<<(NN * HD + 255) / 256, 256, 0, stream>>>(meanb, degN, 8, NN * HD);
    gemm_f32<<<g64x64, 256, 0, stream>>>(t1, Wr_e2, nullptr, aggr, NN, HD, HD, 0);
    gemm_f32<<<g64x64, 256, 0, stream>>>(meanb, Wn_e2, b_e2, aggr, NN, HD, HD, 1);

    // ---- attr_node SAGE layer 1 (relu) ----
    fill_f32<<<(NN * HD + 255) / 256, 256, 0, stream>>>(meanb, 0.f, NN * HD);
    scatter256<<<EE, 256, 0, stream>>>(x, srcN, dstN, meanb);
    div_by_deg<<<(NN * HD + 255) / 256, 256, 0, stream>>>(meanb, degN, 8, NN * HD);
    gemm_f32<<<g64x64, 256, 0, stream>>>(x, Wr_n1, nullptr, ta, NN, HD, HD, 0);
    gemm_f32<<<g64x64, 256, 0, stream>>>(meanb, Wn_n1, b_n1, ta, NN, HD, HD, 3);
    // ---- attr_node SAGE layer 2 (relu) ----
    fill_f32<<<(NN * HD + 255) / 256, 256, 0, stream>>>(meanb, 0.f, NN * HD);
    scatter256<<<EE, 256, 0, stream>>>(ta, srcN, dstN, meanb);
    div_by_deg<<<(NN * HD + 255) / 256, 256, 0, stream>>>(meanb, degN, 8, NN * HD);
    gemm_f32<<<g64x64, 256, 0, stream>>>(ta, Wr_n2, nullptr, tb, NN, HD, HD, 0);
    gemm_f32<<<g64x64, 256, 0, stream>>>(meanb, Wn_n2, b_n2, tb, NN, HD, HD, 3);
    // ---- attr_node SAGE layer 3 ----
    fill_f32<<<(NN * HD + 255) / 256, 256, 0, stream>>>(meanb, 0.f, NN * HD);
    scatter256<<<EE, 256, 0, stream>>>(tb, srcN, dstN, meanb);
    div_by_deg<<<(NN * HD + 255) / 256, 256, 0, stream>>>(meanb, degN, 8, NN * HD);
    gemm_f32<<<g64x64, 256, 0, stream>>>(tb, Wr_n3, nullptr, nrep, NN, HD, HD, 0);
    gemm_f32<<<g64x64, 256, 0, stream>>>(meanb, Wn_n3, b_n3, nrep, NN, HD, HD, 1);

    // ---- MixAttention ----
    gemm_f32<<<g64x64, 256, 0, stream>>>(nrep, Wq, nullptr, qb, NN, HD, HD, 0);
    gemm_f32<<<g64x64, 256, 0, stream>>>(aggr, Wk, nullptr, kb, NN, HD, HD, 0);
    gemm_f32<<<g64x64, 256, 0, stream>>>(aggr, Wv, nullptr, vb, NN, HD, HD, 0);
    attn_scores<<<EE / 4, 256, 0, stream>>>(qb, kb, srcN, dstN, scb);
    fill_f32<<<(NN + 255) / 256, 256, 0, stream>>>(mN, -INFINITY, NN);
    fill_f32<<<(NN + 255) / 256, 256, 0, stream>>>(sN, 0.f, NN);
    seg_max_edge<<<(EE + 255) / 256, 256, 0, stream>>>(scb, dstN, mN, EE);
    seg_sumexp_edge<<<(EE + 255) / 256, 256, 0, stream>>>(scb, dstN, mN, sN, EE);
    copy_f32<<<(NN * HD + 255) / 256, 256, 0, stream>>>(mixed, nrep, NN * HD);
    attn_aggr<<<EE, 256, 0, stream>>>(scb, srcN, dstN, mN, sN, vb, mixed);

    // ---- final linear + log_softmax ----
    gemm_f32<<<dim3((FOUT + 63) / 64, (NN + 63) / 64), 256, 0, stream>>>(mixed, W_out, nullptr, outp, NN, FOUT, HD, 0);
    log_softmax_rows<<<(NN + 255) / 256, 256, 0, stream>>>(outp, NN);
}

// Round 3
// 2144.826 us; speedup vs baseline: 1.6823x; 1.6823x over previous
//
#include <hip/hip_runtime.h>
#include <math.h>

#define NN   20000
#define EE   320000
#define ELG  600000
#define FE   64
#define HD   256
#define FOUT 40

__device__ __forceinline__ float leaky02(float x) { return x > 0.f ? x : 0.2f * x; }

// ---------------- small utility kernels ----------------
__global__ void zero_i32(int* __restrict__ p, int n) {
    int i = blockIdx.x * 256 + threadIdx.x;
    if (i < n) p[i] = 0;
}
__global__ void copy_i32(int* __restrict__ d, const int* __restrict__ s, int n) {
    int i = blockIdx.x * 256 + threadIdx.x;
    if (i < n) d[i] = s[i];
}
__global__ void set_i32(int* __restrict__ p, int v) { *p = v; }

__global__ void count_i32(const int* __restrict__ idx, int* __restrict__ cnt, int n) {
    int i = blockIdx.x * 256 + threadIdx.x;
    if (i < n) atomicAdd(&cnt[idx[i]], 1);
}
// counts both incidence rows (Hm is [2,EE] flat)
__global__ void count_h(const int* __restrict__ Hm, int* __restrict__ cnt) {
    int i = blockIdx.x * 256 + threadIdx.x;
    if (i < 2 * EE) atomicAdd(&cnt[Hm[i]], 1);
}

// ---------------- 3-pass exclusive scan (chunk = 1024 elems / block) ----------------
__global__ void scan_pass1(const int* __restrict__ in, int* __restrict__ bsum, int n) {
    __shared__ int sm[256];
    int base = blockIdx.x * 1024, t = threadIdx.x;
    int s = 0;
#pragma unroll
    for (int j = 0; j < 4; ++j) { int i = base + t * 4 + j; s += (i < n) ? in[i] : 0; }
    sm[t] = s; __syncthreads();
    for (int o = 128; o > 0; o >>= 1) { if (t < o) sm[t] += sm[t + o]; __syncthreads(); }
    if (t == 0) bsum[blockIdx.x] = sm[0];
}
__global__ void scan_pass2(int* __restrict__ bsum, int nb) {
    __shared__ int sm[1024];
    int t = threadIdx.x;
    for (int i = t; i < nb; i += 256) sm[i] = bsum[i];
    __syncthreads();
    if (t == 0) { int run = 0; for (int i = 0; i < nb; ++i) { int v = sm[i]; sm[i] = run; run += v; } }
    __syncthreads();
    for (int i = t; i < nb; i += 256) bsum[i] = sm[i];
}
__global__ void scan_pass3(const int* __restrict__ in, const int* __restrict__ boff,
                           int* __restrict__ out, int n) {
    __shared__ int tsum[256];
    int base = blockIdx.x * 1024, t = threadIdx.x;
    int v[4];
#pragma unroll
    for (int j = 0; j < 4; ++j) { int i = base + t * 4 + j; v[j] = (i < n) ? in[i] : 0; }
    int loc = v[0] + v[1] + v[2] + v[3];
    tsum[t] = loc; __syncthreads();
    for (int o = 1; o < 256; o <<= 1) {
        int x = (t >= o) ? tsum[t - o] : 0;
        __syncthreads();
        tsum[t] += x;
        __syncthreads();
    }
    int off = boff[blockIdx.x] + (tsum[t] - loc);
    int run = 0;
#pragma unroll
    for (int j = 0; j < 4; ++j) { int i = base + t * 4 + j; if (i < n) out[i] = off + run; run += v[j]; }
}

// ---------------- CSR placement ----------------
__global__ void place_pair(const int* __restrict__ seg, const int* __restrict__ val,
                           int* __restrict__ cursor, int* __restrict__ adj, int n) {
    int i = blockIdx.x * 256 + threadIdx.x;
    if (i >= n) return;
    int d = seg[i];
    int pos = atomicAdd(&cursor[d], 1);
    adj[pos] = val[i];
}
__global__ void place_h(const int* __restrict__ Hm, int* __restrict__ cursor, int* __restrict__ adj) {
    int i = blockIdx.x * 256 + threadIdx.x;
    if (i >= 2 * EE) return;
    int d = Hm[i];
    int pos = atomicAdd(&cursor[d], 1);
    adj[pos] = (i < EE) ? i : i - EE;
}

// ---------------- fp32 GEMM (unchanged from round 0) ----------------
// C[M,N] = A@B (+C if flags&1)(+bias)(relu if flags&2)(leaky if flags&4)
__global__ __launch_bounds__(256)
void gemm_f32(const float* __restrict__ A, const float* __restrict__ B,
              const float* __restrict__ bias, float* __restrict__ C,
              int M, int N, int K, int flags) {
    const int BM = 64, BN = 64, BK = 16;
    __shared__ float As[BK][BM + 1];
    __shared__ float Bs[BK][BN + 1];
    int tid = threadIdx.x;
    int tr = tid >> 4, tc = tid & 15;
    int brow = blockIdx.y * BM, bcol = blockIdx.x * BN;
    float acc[4][4] = {{0.f}};
    for (int k0 = 0; k0 < K; k0 += BK) {
#pragma unroll
        for (int i = 0; i < 4; ++i) {
            int e = tid + i * 256;
            int r = e >> 4, c = e & 15;
            int gr = brow + r, gc = k0 + c;
            As[c][r] = (gr < M && gc < K) ? A[(long)gr * K + gc] : 0.f;
        }
#pragma unroll
        for (int i = 0; i < 4; ++i) {
            int e = tid + i * 256;
            int r = e >> 6, c = e & 63;
            int gr = k0 + r, gc = bcol + c;
            Bs[r][c] = (gr < K && gc < N) ? B[(long)gr * N + gc] : 0.f;
        }
        __syncthreads();
#pragma unroll
        for (int k = 0; k < BK; ++k) {
            float ra[4], rb[4];
#pragma unroll
            for (int i = 0; i < 4; ++i) ra[i] = As[k][tr * 4 + i];
#pragma unroll
            for (int j = 0; j < 4; ++j) rb[j] = Bs[k][tc * 4 + j];
#pragma unroll
            for (int i = 0; i < 4; ++i)
#pragma unroll
                for (int j = 0; j < 4; ++j) acc[i][j] += ra[i] * rb[j];
        }
        __syncthreads();
    }
#pragma unroll
    for (int i = 0; i < 4; ++i) {
        int gr = brow + tr * 4 + i;
        if (gr >= M) continue;
#pragma unroll
        for (int j = 0; j < 4; ++j) {
            int gc = bcol + tc * 4 + j;
            if (gc >= N) continue;
            float v = acc[i][j];
            if (flags & 1) v += C[(long)gr * N + gc];
            if (bias) v += bias[gc];
            if (flags & 2) v = fmaxf(v, 0.f);
            if (flags & 4) v = leaky02(v);
            C[(long)gr * N + gc] = v;
        }
    }
}

// ---------------- GAT pre-computation ----------------
__global__ void wg_av(const float* __restrict__ W, const float* __restrict__ as_,
                      const float* __restrict__ ad_, float* __restrict__ asv,
                      float* __restrict__ adv) {
    __shared__ float sm[256];
    int i = blockIdx.x, t = threadIdx.x;
    float w = W[i * HD + t];
    sm[t] = w * as_[t];
    __syncthreads();
    for (int o = 128; o > 0; o >>= 1) { if (t < o) sm[t] += sm[t + o]; __syncthreads(); }
    if (t == 0) asv[i] = sm[0];
    __syncthreads();
    sm[t] = w * ad_[t];
    __syncthreads();
    for (int o = 128; o > 0; o >>= 1) { if (t < o) sm[t] += sm[t + o]; __syncthreads(); }
    if (t == 0) adv[i] = sm[0];
}

__global__ void bias_proj(const float* __restrict__ b, const float* __restrict__ W,
                          float* __restrict__ b2) {
    int j = threadIdx.x;
    float s = 0.f;
    for (int i = 0; i < HD; ++i) s += b[i] * W[i * HD + j];
    b2[j] = s;
}

// es[e] = et[e,:]@asv ; ed[e] = et[e,:]@adv  (wave per edge)
__global__ void edge_scores(const float* __restrict__ et, const float* __restrict__ asv,
                            const float* __restrict__ adv, float* __restrict__ es,
                            float* __restrict__ ed) {
    int e = blockIdx.x * 4 + (threadIdx.x >> 6);
    int l = threadIdx.x & 63;
    float x = et[(long)e * FE + l];
    float vs = x * asv[l];
    float vd = x * adv[l];
    for (int o = 32; o > 0; o >>= 1) { vs += __shfl_down(vs, o); vd += __shfl_down(vd, o); }
    if (l == 0) { es[e] = vs; ed[e] = vd; }
}

// ---------------- fused GAT softmax + aggregation (wave per lg-segment d) ----------------
// self-loop (s=d) handled analytically; adjLG holds only real lg edges.
__global__ void gat_fused(const int* __restrict__ rowptr, const int* __restrict__ adj,
                          const float* __restrict__ es, const float* __restrict__ ed,
                          const float* __restrict__ et, float* __restrict__ agg_et) {
    int d = blockIdx.x * 4 + (threadIdx.x >> 6);
    int lane = threadIdx.x & 63;
    if (d >= EE) return;
    int b = rowptr[d], e_ = rowptr[d + 1];
    float edd = ed[d];
    float self_sc = leaky02(es[d] + edd);
    // max over segment (incl. self)
    float m = self_sc;
    for (int i = b + lane; i < e_; i += 64) m = fmaxf(m, leaky02(es[adj[i]] + edd));
    for (int o = 32; o > 0; o >>= 1) m = fmaxf(m, __shfl_xor(m, o));
    // sum of exp
    float sl = 0.f;
    for (int i = b + lane; i < e_; i += 64) sl += expf(leaky02(es[adj[i]] + edd) - m);
    for (int o = 32; o > 0; o >>= 1) sl += __shfl_xor(sl, o);
    float s = sl + expf(self_sc - m);
    float inv = 1.f / (s + 1e-16f);
    // weighted feature accumulate (lane = feature)
    float acc = expf(self_sc - m) * inv * et[(long)d * FE + lane];
    for (int i = b; i < e_; ++i) {
        int sE = adj[i];
        float al = expf(leaky02(es[sE] + edd) - m) * inv;
        acc += al * et[(long)sE * FE + lane];
    }
    agg_et[(long)d * FE + lane] = acc;
}

// ---------------- incidence mean (wave per node) ----------------
__global__ void etn_gather(const int* __restrict__ rowptr, const int* __restrict__ adj,
                           const float* __restrict__ agg_et, float* __restrict__ agg2,
                           float* __restrict__ degE) {
    int n = blockIdx.x * 4 + (threadIdx.x >> 6);
    int lane = threadIdx.x & 63;
    if (n >= NN) return;
    int b = rowptr[n], e_ = rowptr[n + 1];
    float acc = 0.f;
    for (int i = b; i < e_; ++i) acc += agg_et[(long)adj[i] * FE + lane];
    float deg = (float)(e_ - b);
    agg2[(long)n * FE + lane] = acc / fmaxf(deg, 1.f);
    if (lane == 0) degE[n] = deg;
}

// etn rows with deg==0 must be exactly 0 (kill the b2 bias), then leaky
__global__ void etn_mask_leaky(float* __restrict__ p, const float* __restrict__ deg, int n) {
    int i = blockIdx.x * 256 + threadIdx.x;
    if (i >= n) return;
    float v = (deg[i >> 8] > 0.f) ? p[i] : 0.f;
    p[i] = leaky02(v);
}

// ---------------- SAGE mean aggregation via CSR gather (block per node) ----------------
__global__ void sage_gather(const float* __restrict__ X, const int* __restrict__ rowptr,
                            const int* __restrict__ adjS, float* __restrict__ mean) {
    int n = blockIdx.x;
    int t = threadIdx.x;
    int b = rowptr[n], e_ = rowptr[n + 1];
    float acc = 0.f;
    for (int i = b; i < e_; ++i) acc += X[(long)adjS[i] * HD + t];
    mean[(long)n * HD + t] = acc / fmaxf((float)(e_ - b), 1.f);
}

// ---------------- fused MixAttention (wave per node, q cached in regs) ----------------
__global__ void attn_fused(const float* __restrict__ q, const float* __restrict__ k,
                           const float* __restrict__ v, const float* __restrict__ nrep,
                           const int* __restrict__ rowptr, const int* __restrict__ adjS,
                           float* __restrict__ scb, float* __restrict__ mixed) {
    int n = blockIdx.x * 4 + (threadIdx.x >> 6);
    int lane = threadIdx.x & 63;
    if (n >= NN) return;
    int b = rowptr[n], e_ = rowptr[n + 1];
    float4 qv = ((const float4*)(q + (long)n * HD))[lane];
    float m = -INFINITY;
    for (int i = b; i < e_; ++i) {
        int s = adjS[i];
        float4 kv = ((const float4*)(k + (long)s * HD))[lane];
        float p = qv.x * kv.x + qv.y * kv.y + qv.z * kv.z + qv.w * kv.w;
        for (int o = 32; o > 0; o >>= 1) p += __shfl_xor(p, o);
        p *= 0.0625f;                       // 1/sqrt(256)
        if (lane == 0) scb[i] = p;          // p uniform across lanes after xor-reduce
        m = fmaxf(m, p);
    }
    float ssum = 0.f;
    for (int i = b; i < e_; ++i) ssum += expf(scb[i] - m);
    float inv = 1.f / (ssum + 1e-16f);
    float4 acc = make_float4(0.f, 0.f, 0.f, 0.f);
    for (int i = b; i < e_; ++i) {
        int s = adjS[i];
        float al = expf(scb[i] - m) * inv;
        float4 vv = ((const float4*)(v + (long)s * HD))[lane];
        acc.x += al * vv.x; acc.y += al * vv.y; acc.z += al * vv.z; acc.w += al * vv.w;
    }
    float4 nr = ((const float4*)(nrep + (long)n * HD))[lane];
    acc.x += nr.x; acc.y += nr.y; acc.z += nr.z; acc.w += nr.w;
    ((float4*)(mixed + (long)n * HD))[lane] = acc;
}

__global__ void log_softmax_rows(float* __restrict__ out, int nrows) {
    int r = blockIdx.x * 256 + threadIdx.x;
    if (r >= nrows) return;
    float* p = out + (long)r * FOUT;
    float mx = -INFINITY;
    for (int i = 0; i < FOUT; ++i) mx = fmaxf(mx, p[i]);
    float s = 0.f;
    for (int i = 0; i < FOUT; ++i) s += expf(p[i] - mx);
    float ls = mx + logf(s);
    for (int i = 0; i < FOUT; ++i) p[i] -= ls;
}

// ---------------- host launch ----------------
static void build_scan(const int* cnt, int* rowptr, int* bsum, int n, int total, hipStream_t stream) {
    int nb = (n + 1023) / 1024;
    scan_pass1<<<nb, 256, 0, stream>>>(cnt, bsum, n);
    scan_pass2<<<1, 256, 0, stream>>>(bsum, nb);
    scan_pass3<<<nb, 256, 0, stream>>>(cnt, bsum, rowptr, n);
    set_i32<<<1, 1, 0, stream>>>(rowptr + n, total);
}

extern "C" void kernel_launch(void* const* d_in, const int* in_sizes, int n_in,
                              void* d_out, int out_size, void* d_ws, size_t ws_size,
                              hipStream_t stream) {
    (void)in_sizes; (void)n_in; (void)out_size; (void)ws_size;
    const float* x     = (const float*)d_in[0];
    const float* et    = (const float*)d_in[1];
    const int*   Hm    = (const int*)d_in[2];
    const int*   raw   = (const int*)d_in[3];
    const int*   lg    = (const int*)d_in[4];
    const float* W_gat = (const float*)d_in[5];
    const float* a_src = (const float*)d_in[6];
    const float* a_dst = (const float*)d_in[7];
    const float* b_gat = (const float*)d_in[8];
    const float* W_etn = (const float*)d_in[9];
    const float* W_eg  = (const float*)d_in[10];
    const float* Wr_e1 = (const float*)d_in[11];
    const float* Wn_e1 = (const float*)d_in[12];
    const float* b_e1  = (const float*)d_in[13];
    const float* Wr_e2 = (const float*)d_in[14];
    const float* Wn_e2 = (const float*)d_in[15];
    const float* b_e2  = (const float*)d_in[16];
    const float* Wr_n1 = (const float*)d_in[17];
    const float* Wn_n1 = (const float*)d_in[18];
    const float* b_n1  = (const float*)d_in[19];
    const float* Wr_n2 = (const float*)d_in[20];
    const float* Wn_n2 = (const float*)d_in[21];
    const float* b_n2  = (const float*)d_in[22];
    const float* Wr_n3 = (const float*)d_in[23];
    const float* Wn_n3 = (const float*)d_in[24];
    const float* b_n3  = (const float*)d_in[25];
    const float* Wq    = (const float*)d_in[26];
    const float* Wk    = (const float*)d_in[27];
    const float* Wv    = (const float*)d_in[28];
    const float* W_out = (const float*)d_in[29];

    const int* srcN = raw;
    const int* dstN = raw + EE;
    const int* lgs  = lg;
    const int* lgd  = lg + ELG;

    float* ws = (float*)d_ws;
    size_t off = 0;
    auto alloc = [&](size_t n) { float* p = ws + off; off += (n + 63) & ~(size_t)63; return p; };

    float* agg_et = alloc((size_t)EE * FE);      // 20.48M f; later reused for q/k/v
    float* es     = alloc(EE);
    float* ed     = alloc(EE);
    float* Wcomb  = alloc((size_t)FE * HD);
    float* b2     = alloc(HD);
    float* asv    = alloc(FE);
    float* adv    = alloc(FE);
    float* agg2   = alloc((size_t)NN * FE);
    float* degE   = alloc(NN);
    float* etnL   = alloc((size_t)NN * HD);
    float* erep   = alloc((size_t)NN * HD);
    float* meanb  = alloc((size_t)NN * HD);
    float* t1     = alloc((size_t)NN * HD);
    float* aggr   = alloc((size_t)NN * HD);
    float* nrep   = alloc((size_t)NN * HD);
    float* scb    = alloc(EE);
    // int region
    int* rowptrD  = (int*)alloc(NN + 64);
    int* cursD    = (int*)alloc(NN);
    int* adjS     = (int*)alloc(EE);
    int* rowptrLG = (int*)alloc(EE + 64);
    int* cursLG   = (int*)alloc(EE);
    int* adjLG    = (int*)alloc(ELG);
    int* rowptrH  = (int*)alloc(NN + 64);
    int* cursH    = (int*)alloc(NN);
    int* adjH     = (int*)alloc(2 * EE);
    int* cntbuf   = (int*)alloc(EE);             // count scratch (max segment count = EE)
    int* bsum     = (int*)alloc(1024);
    // aliases (lifetime-checked)
    float* ta    = etnL;          // attr hidden 1 (etnL dead after erep GEMM)
    float* tb    = erep;          // attr hidden 2 (erep dead after edge layer 1)
    float* qb    = agg_et;                        // agg_et dead after etn_gather
    float* kb    = agg_et + (size_t)NN * HD;
    float* vb    = agg_et + (size_t)2 * NN * HD;
    float* mixed = t1;            // t1 dead after aggr GEMMs
    float* outp  = (float*)d_out;

    dim3 g64x64((HD + 63) / 64, (NN + 63) / 64);

    // ================= CSR builds =================
    // CSR over raw graph by dst (adjS[pos] = src node)
    zero_i32<<<(NN + 255) / 256, 256, 0, stream>>>(cntbuf, NN);
    count_i32<<<(EE + 255) / 256, 256, 0, stream>>>(dstN, cntbuf, EE);
    build_scan(cntbuf, rowptrD, bsum, NN, EE, stream);
    copy_i32<<<(NN + 255) / 256, 256, 0, stream>>>(cursD, rowptrD, NN);
    place_pair<<<(EE + 255) / 256, 256, 0, stream>>>(dstN, srcN, cursD, adjS, EE);
    // CSR over line graph by lgd (adjLG[pos] = source edge id)
    zero_i32<<<(EE + 255) / 256, 256, 0, stream>>>(cntbuf, EE);
    count_i32<<<(ELG + 255) / 256, 256, 0, stream>>>(lgd, cntbuf, ELG);
    build_scan(cntbuf, rowptrLG, bsum, EE, ELG, stream);
    copy_i32<<<(EE + 255) / 256, 256, 0, stream>>>(cursLG, rowptrLG, EE);
    place_pair<<<(ELG + 255) / 256, 256, 0, stream>>>(lgd, lgs, cursLG, adjLG, ELG);
    // CSR over incidence H (adjH[pos] = edge id)
    zero_i32<<<(NN + 255) / 256, 256, 0, stream>>>(cntbuf, NN);
    count_h<<<(2 * EE + 255) / 256, 256, 0, stream>>>(Hm, cntbuf);
    build_scan(cntbuf, rowptrH, bsum, NN, 2 * EE, stream);
    copy_i32<<<(NN + 255) / 256, 256, 0, stream>>>(cursH, rowptrH, NN);
    place_h<<<(2 * EE + 255) / 256, 256, 0, stream>>>(Hm, cursH, adjH);

    // ================= GAT (line graph), folded: Wcomb = W_gat@W_etn =================
    gemm_f32<<<dim3(4, 1), 256, 0, stream>>>(W_gat, W_etn, nullptr, Wcomb, FE, HD, HD, 0);
    bias_proj<<<1, 256, 0, stream>>>(b_gat, W_etn, b2);
    wg_av<<<FE, 256, 0, stream>>>(W_gat, a_src, a_dst, asv, adv);
    edge_scores<<<EE / 4, 256, 0, stream>>>(et, asv, adv, es, ed);
    gat_fused<<<(EE + 3) / 4, 256, 0, stream>>>(rowptrLG, adjLG, es, ed, et, agg_et);

    // ================= EdgeToNode incidence mean + GEMMs =================
    etn_gather<<<(NN + 3) / 4, 256, 0, stream>>>(rowptrH, adjH, agg_et, agg2, degE);
    gemm_f32<<<g64x64, 256, 0, stream>>>(agg2, Wcomb, b2, etnL, NN, HD, FE, 0);
    etn_mask_leaky<<<(NN * HD + 255) / 256, 256, 0, stream>>>(etnL, degE, NN * HD);
    gemm_f32<<<g64x64, 256, 0, stream>>>(etnL, W_eg, nullptr, erep, NN, HD, HD, 0);

    // ================= edge_aggr SAGE (2 layers) =================
    sage_gather<<<NN, 256, 0, stream>>>(erep, rowptrD, adjS, meanb);
    gemm_f32<<<g64x64, 256, 0, stream>>>(erep, Wr_e1, nullptr, t1, NN, HD, HD, 0);
    gemm_f32<<<g64x64, 256, 0, stream>>>(meanb, Wn_e1, b_e1, t1, NN, HD, HD, 3);
    sage_gather<<<NN, 256, 0, stream>>>(t1, rowptrD, adjS, meanb);
    gemm_f32<<<g64x64, 256, 0, stream>>>(t1, Wr_e2, nullptr, aggr, NN, HD, HD, 0);
    gemm_f32<<<g64x64, 256, 0, stream>>>(meanb, Wn_e2, b_e2, aggr, NN, HD, HD, 1);

    // ================= attr_node SAGE (3 layers) =================
    sage_gather<<<NN, 256, 0, stream>>>(x, rowptrD, adjS, meanb);
    gemm_f32<<<g64x64, 256, 0, stream>>>(x, Wr_n1, nullptr, ta, NN, HD, HD, 0);
    gemm_f32<<<g64x64, 256, 0, stream>>>(meanb, Wn_n1, b_n1, ta, NN, HD, HD, 3);
    sage_gather<<<NN, 256, 0, stream>>>(ta, rowptrD, adjS, meanb);
    gemm_f32<<<g64x64, 256, 0, stream>>>(ta, Wr_n2, nullptr, tb, NN, HD, HD, 0);
    gemm_f32<<<g64x64, 256, 0, stream>>>(meanb, Wn_n2, b_n2, tb, NN, HD, HD, 3);
    sage_gather<<<NN, 256, 0, stream>>>(tb, rowptrD, adjS, meanb);
    gemm_f32<<<g64x64, 256, 0, stream>>>(tb, Wr_n3, nullptr, nrep, NN, HD, HD, 0);
    gemm_f32<<<g64x64, 256, 0, stream>>>(meanb, Wn_n3, b_n3, nrep, NN, HD, HD, 1);

    // ================= MixAttention (fused) =================
    gemm_f32<<<g64x64, 256, 0, stream>>>(nrep, Wq, nullptr, qb, NN, HD, HD, 0);
    gemm_f32<<<g64x64, 256, 0, stream>>>(aggr, Wk, nullptr, kb, NN, HD, HD, 0);
    gemm_f32<<<g64x64, 256, 0, stream>>>(aggr, Wv, nullptr, vb, NN, HD, HD, 0);
    attn_fused<<<(NN + 3) / 4, 256, 0, stream>>>(qb, kb, vb, nrep, rowptrD, adjS, scb, mixed);

    // ================= final linear + log_softmax =================
    gemm_f32<<<dim3(1, (NN + 63) / 64), 256, 0, stream>>>(mixed, W_out, nullptr, outp, NN, FOUT, HD, 0);
    log_softmax_rows<<<(NN + 255) / 256, 256, 0, stream>>>(outp, NN);
}

// Round 4
// 1403.015 us; speedup vs baseline: 2.5718x; 1.5287x over previous
//
#include <hip/hip_runtime.h>
#include <math.h>

#define NN   20000
#define EE   320000
#define ELG  600000
#define FE   64
#define HD   256
#define FOUT 40

typedef __attribute__((ext_vector_type(8))) short bf16x8;
typedef __attribute__((ext_vector_type(4))) float f32x4;

__device__ __forceinline__ float leaky02(float x) { return x > 0.f ? x : 0.2f * x; }

__device__ __forceinline__ unsigned short bf16rne(float f) {
    unsigned int u = __float_as_uint(f);
    u = (u + 0x7FFFu + ((u >> 16) & 1u)) >> 16;
    return (unsigned short)u;
}

// ---------------- small utility kernels ----------------
__global__ void zero_i32(int* __restrict__ p, int n) {
    int i = blockIdx.x * 256 + threadIdx.x;
    if (i < n) p[i] = 0;
}
__global__ void copy_i32(int* __restrict__ d, const int* __restrict__ s, int n) {
    int i = blockIdx.x * 256 + threadIdx.x;
    if (i < n) d[i] = s[i];
}
__global__ void set_i32(int* __restrict__ p, int v) { *p = v; }

__global__ void count_i32(const int* __restrict__ idx, int* __restrict__ cnt, int n) {
    int i = blockIdx.x * 256 + threadIdx.x;
    if (i < n) atomicAdd(&cnt[idx[i]], 1);
}
__global__ void count_h(const int* __restrict__ Hm, int* __restrict__ cnt) {
    int i = blockIdx.x * 256 + threadIdx.x;
    if (i < 2 * EE) atomicAdd(&cnt[Hm[i]], 1);
}

// ---------------- 3-pass exclusive scan ----------------
__global__ void scan_pass1(const int* __restrict__ in, int* __restrict__ bsum, int n) {
    __shared__ int sm[256];
    int base = blockIdx.x * 1024, t = threadIdx.x;
    int s = 0;
#pragma unroll
    for (int j = 0; j < 4; ++j) { int i = base + t * 4 + j; s += (i < n) ? in[i] : 0; }
    sm[t] = s; __syncthreads();
    for (int o = 128; o > 0; o >>= 1) { if (t < o) sm[t] += sm[t + o]; __syncthreads(); }
    if (t == 0) bsum[blockIdx.x] = sm[0];
}
__global__ void scan_pass2(int* __restrict__ bsum, int nb) {
    __shared__ int sm[1024];
    int t = threadIdx.x;
    for (int i = t; i < nb; i += 256) sm[i] = bsum[i];
    __syncthreads();
    if (t == 0) { int run = 0; for (int i = 0; i < nb; ++i) { int v = sm[i]; sm[i] = run; run += v; } }
    __syncthreads();
    for (int i = t; i < nb; i += 256) bsum[i] = sm[i];
}
__global__ void scan_pass3(const int* __restrict__ in, const int* __restrict__ boff,
                           int* __restrict__ out, int n) {
    __shared__ int tsum[256];
    int base = blockIdx.x * 1024, t = threadIdx.x;
    int v[4];
#pragma unroll
    for (int j = 0; j < 4; ++j) { int i = base + t * 4 + j; v[j] = (i < n) ? in[i] : 0; }
    int loc = v[0] + v[1] + v[2] + v[3];
    tsum[t] = loc; __syncthreads();
    for (int o = 1; o < 256; o <<= 1) {
        int x = (t >= o) ? tsum[t - o] : 0;
        __syncthreads();
        tsum[t] += x;
        __syncthreads();
    }
    int off = boff[blockIdx.x] + (tsum[t] - loc);
    int run = 0;
#pragma unroll
    for (int j = 0; j < 4; ++j) { int i = base + t * 4 + j; if (i < n) out[i] = off + run; run += v[j]; }
}

// ---------------- CSR placement ----------------
__global__ void place_pair(const int* __restrict__ seg, const int* __restrict__ val,
                           int* __restrict__ cursor, int* __restrict__ adj, int n) {
    int i = blockIdx.x * 256 + threadIdx.x;
    if (i >= n) return;
    int d = seg[i];
    int pos = atomicAdd(&cursor[d], 1);
    adj[pos] = val[i];
}
__global__ void place_h(const int* __restrict__ Hm, int* __restrict__ cursor, int* __restrict__ adj) {
    int i = blockIdx.x * 256 + threadIdx.x;
    if (i >= 2 * EE) return;
    int d = Hm[i];
    int pos = atomicAdd(&cursor[d], 1);
    adj[pos] = (i < EE) ? i : i - EE;
}

// ---------------- weight transpose+convert: 14x [256][256] f32 -> [N][K] bf16 ----------------
struct Ptr14 { const float* p[14]; };
__global__ void wtrans14(Ptr14 srcs, unsigned short* __restrict__ dst) {
    int m = blockIdx.x >> 6;
    int tile = blockIdx.x & 63;
    const float* src = srcs.p[m];
    unsigned short* out = dst + (size_t)m * 65536;
    int kb = (tile >> 3) * 32, nb = (tile & 7) * 32;
    __shared__ float sm[32][33];
    int t = threadIdx.x;
#pragma unroll
    for (int i = 0; i < 4; ++i) {
        int e = t + i * 256; int r = e >> 5, c = e & 31;
        sm[r][c] = src[(kb + r) * 256 + nb + c];
    }
    __syncthreads();
#pragma unroll
    for (int i = 0; i < 4; ++i) {
        int e = t + i * 256; int nr = e >> 5, kc = e & 31;
        out[(size_t)(nb + nr) * 256 + kb + kc] = bf16rne(sm[kc][nr]);
    }
}
// generic one-matrix transpose (for Wcomb [K=64][N=256])
__global__ void wtrans_one(const float* __restrict__ src, unsigned short* __restrict__ dst,
                           int K, int N) {
    int tilesN = N >> 5;
    int kb = (blockIdx.x / tilesN) * 32, nb = (blockIdx.x % tilesN) * 32;
    __shared__ float sm[32][33];
    int t = threadIdx.x;
#pragma unroll
    for (int i = 0; i < 4; ++i) {
        int e = t + i * 256; int r = e >> 5, c = e & 31;
        sm[r][c] = src[(kb + r) * N + nb + c];
    }
    __syncthreads();
#pragma unroll
    for (int i = 0; i < 4; ++i) {
        int e = t + i * 256; int nr = e >> 5, kc = e & 31;
        dst[(size_t)(nb + nr) * K + kb + kc] = bf16rne(sm[kc][nr]);
    }
}

// ---------------- bf16 MFMA GEMM: C[M,256] = A1@W1 (+A2@W2) (+bias)(relu|leaky) ----------------
// W layouts are transposed bf16 [256][K]. A is f32, converted to bf16 during LDS staging.
// BM=128 BN=64 BK=32, 4 waves (2x2), wave tile 64x32 = 4x2 frags of 16x16.
// flags: 1=relu, 2=leaky
__global__ __launch_bounds__(256)
void gemm_bf16(const float* __restrict__ A1, const float* __restrict__ A2,
               const unsigned short* __restrict__ W1, const unsigned short* __restrict__ W2,
               const float* __restrict__ bias, float* __restrict__ C,
               int M, int K1, int flags) {
    __shared__ unsigned short As[128][40];
    __shared__ unsigned short Bs[64][40];
    int tid = threadIdx.x;
    int w = tid >> 6, l = tid & 63;
    int wr = w >> 1, wc = w & 1;
    int brow = blockIdx.y * 128, bcol = blockIdx.x * 64;
    int Ktot = K1 + (A2 ? 256 : 0);
    f32x4 acc[4][2] = {};
    for (int k0 = 0; k0 < Ktot; k0 += 32) {
        const float* Ap; const unsigned short* Wp; int kk, Klen;
        if (k0 < K1) { Ap = A1; Wp = W1; kk = k0; Klen = K1; }
        else         { Ap = A2; Wp = W2; kk = k0 - K1; Klen = 256; }
        // stage A: 128x32 f32 -> bf16 (4 x float4 per thread)
#pragma unroll
        for (int i = 0; i < 4; ++i) {
            int q = tid + i * 256;
            int r = q >> 3, kb = (q & 7) * 4;
            int gr = brow + r;
            float4 v = (gr < M) ? *(const float4*)(Ap + (size_t)gr * Klen + kk + kb)
                                : make_float4(0.f, 0.f, 0.f, 0.f);
            ushort4 u;
            u.x = bf16rne(v.x); u.y = bf16rne(v.y); u.z = bf16rne(v.z); u.w = bf16rne(v.w);
            *(ushort4*)(&As[r][kb]) = u;
        }
        // stage B: 64x32 bf16 (2 x ushort4 per thread)
#pragma unroll
        for (int i = 0; i < 2; ++i) {
            int q = tid + i * 256;
            int n = q >> 3, kb = (q & 7) * 4;
            *(ushort4*)(&Bs[n][kb]) = *(const ushort4*)(Wp + (size_t)(bcol + n) * Klen + kk + kb);
        }
        __syncthreads();
        bf16x8 af[4], bfr[2];
#pragma unroll
        for (int fr = 0; fr < 4; ++fr)
            af[fr] = *(const bf16x8*)(&As[wr * 64 + fr * 16 + (l & 15)][(l >> 4) * 8]);
#pragma unroll
        for (int fc = 0; fc < 2; ++fc)
            bfr[fc] = *(const bf16x8*)(&Bs[wc * 32 + fc * 16 + (l & 15)][(l >> 4) * 8]);
#pragma unroll
        for (int fr = 0; fr < 4; ++fr)
#pragma unroll
            for (int fc = 0; fc < 2; ++fc)
                acc[fr][fc] = __builtin_amdgcn_mfma_f32_16x16x32_bf16(af[fr], bfr[fc], acc[fr][fc], 0, 0, 0);
        __syncthreads();
    }
#pragma unroll
    for (int fr = 0; fr < 4; ++fr) {
#pragma unroll
        for (int fc = 0; fc < 2; ++fc) {
            int col = bcol + wc * 32 + fc * 16 + (l & 15);
#pragma unroll
            for (int i = 0; i < 4; ++i) {
                int row = brow + wr * 64 + fr * 16 + (l >> 4) * 4 + i;
                if (row >= M) continue;
                float v = acc[fr][fc][i];
                if (bias) v += bias[col];
                if (flags & 1) v = fmaxf(v, 0.f);
                if (flags & 2) v = leaky02(v);
                C[(size_t)row * 256 + col] = v;
            }
        }
    }
}

// ---------------- fp32 GEMM (small cases: Wcomb, final W_out) ----------------
__global__ __launch_bounds__(256)
void gemm_f32(const float* __restrict__ A, const float* __restrict__ B,
              const float* __restrict__ bias, float* __restrict__ C,
              int M, int N, int K, int flags) {
    const int BM = 64, BN = 64, BK = 16;
    __shared__ float As[BK][BM + 1];
    __shared__ float Bs[BK][BN + 1];
    int tid = threadIdx.x;
    int tr = tid >> 4, tc = tid & 15;
    int brow = blockIdx.y * BM, bcol = blockIdx.x * BN;
    float acc[4][4] = {{0.f}};
    for (int k0 = 0; k0 < K; k0 += BK) {
#pragma unroll
        for (int i = 0; i < 4; ++i) {
            int e = tid + i * 256;
            int r = e >> 4, c = e & 15;
            int gr = brow + r, gc = k0 + c;
            As[c][r] = (gr < M && gc < K) ? A[(long)gr * K + gc] : 0.f;
        }
#pragma unroll
        for (int i = 0; i < 4; ++i) {
            int e = tid + i * 256;
            int r = e >> 6, c = e & 63;
            int gr = k0 + r, gc = bcol + c;
            Bs[r][c] = (gr < K && gc < N) ? B[(long)gr * N + gc] : 0.f;
        }
        __syncthreads();
#pragma unroll
        for (int k = 0; k < BK; ++k) {
            float ra[4], rb[4];
#pragma unroll
            for (int i = 0; i < 4; ++i) ra[i] = As[k][tr * 4 + i];
#pragma unroll
            for (int j = 0; j < 4; ++j) rb[j] = Bs[k][tc * 4 + j];
#pragma unroll
            for (int i = 0; i < 4; ++i)
#pragma unroll
                for (int j = 0; j < 4; ++j) acc[i][j] += ra[i] * rb[j];
        }
        __syncthreads();
    }
#pragma unroll
    for (int i = 0; i < 4; ++i) {
        int gr = brow + tr * 4 + i;
        if (gr >= M) continue;
#pragma unroll
        for (int j = 0; j < 4; ++j) {
            int gc = bcol + tc * 4 + j;
            if (gc >= N) continue;
            float v = acc[i][j];
            if (flags & 1) v += C[(long)gr * N + gc];
            if (bias) v += bias[gc];
            if (flags & 2) v = fmaxf(v, 0.f);
            if (flags & 4) v = leaky02(v);
            C[(long)gr * N + gc] = v;
        }
    }
}

// ---------------- GAT pre-computation ----------------
__global__ void wg_av(const float* __restrict__ W, const float* __restrict__ as_,
                      const float* __restrict__ ad_, float* __restrict__ asv,
                      float* __restrict__ adv) {
    __shared__ float sm[256];
    int i = blockIdx.x, t = threadIdx.x;
    float w = W[i * HD + t];
    sm[t] = w * as_[t];
    __syncthreads();
    for (int o = 128; o > 0; o >>= 1) { if (t < o) sm[t] += sm[t + o]; __syncthreads(); }
    if (t == 0) asv[i] = sm[0];
    __syncthreads();
    sm[t] = w * ad_[t];
    __syncthreads();
    for (int o = 128; o > 0; o >>= 1) { if (t < o) sm[t] += sm[t + o]; __syncthreads(); }
    if (t == 0) adv[i] = sm[0];
}

__global__ void bias_proj(const float* __restrict__ b, const float* __restrict__ W,
                          float* __restrict__ b2) {
    int j = threadIdx.x;
    float s = 0.f;
    for (int i = 0; i < HD; ++i) s += b[i] * W[i * HD + j];
    b2[j] = s;
}

__global__ void edge_scores(const float* __restrict__ et, const float* __restrict__ asv,
                            const float* __restrict__ adv, float* __restrict__ es,
                            float* __restrict__ ed) {
    int e = blockIdx.x * 4 + (threadIdx.x >> 6);
    int l = threadIdx.x & 63;
    float x = et[(long)e * FE + l];
    float vs = x * asv[l];
    float vd = x * adv[l];
    for (int o = 32; o > 0; o >>= 1) { vs += __shfl_down(vs, o); vd += __shfl_down(vd, o); }
    if (l == 0) { es[e] = vs; ed[e] = vd; }
}

// ---------------- fused GAT softmax + aggregation (wave per lg-segment d) ----------------
__global__ void gat_fused(const int* __restrict__ rowptr, const int* __restrict__ adj,
                          const float* __restrict__ es, const float* __restrict__ ed,
                          const float* __restrict__ et, float* __restrict__ agg_et) {
    int d = blockIdx.x * 4 + (threadIdx.x >> 6);
    int lane = threadIdx.x & 63;
    if (d >= EE) return;
    int b = rowptr[d], e_ = rowptr[d + 1];
    float edd = ed[d];
    float self_sc = leaky02(es[d] + edd);
    float m = self_sc;
    for (int i = b + lane; i < e_; i += 64) m = fmaxf(m, leaky02(es[adj[i]] + edd));
    for (int o = 32; o > 0; o >>= 1) m = fmaxf(m, __shfl_xor(m, o));
    float sl = 0.f;
    for (int i = b + lane; i < e_; i += 64) sl += expf(leaky02(es[adj[i]] + edd) - m);
    for (int o = 32; o > 0; o >>= 1) sl += __shfl_xor(sl, o);
    float s = sl + expf(self_sc - m);
    float inv = 1.f / (s + 1e-16f);
    float acc = expf(self_sc - m) * inv * et[(long)d * FE + lane];
    for (int i = b; i < e_; ++i) {
        int sE = adj[i];
        float al = expf(leaky02(es[sE] + edd) - m) * inv;
        acc += al * et[(long)sE * FE + lane];
    }
    agg_et[(long)d * FE + lane] = acc;
}

// ---------------- incidence mean (wave per node) ----------------
__global__ void etn_gather(const int* __restrict__ rowptr, const int* __restrict__ adj,
                           const float* __restrict__ agg_et, float* __restrict__ agg2,
                           float* __restrict__ degE) {
    int n = blockIdx.x * 4 + (threadIdx.x >> 6);
    int lane = threadIdx.x & 63;
    if (n >= NN) return;
    int b = rowptr[n], e_ = rowptr[n + 1];
    float acc = 0.f;
    for (int i = b; i < e_; ++i) acc += agg_et[(long)adj[i] * FE + lane];
    float deg = (float)(e_ - b);
    agg2[(long)n * FE + lane] = acc / fmaxf(deg, 1.f);
    if (lane == 0) degE[n] = deg;
}

__global__ void etn_mask_leaky(float* __restrict__ p, const float* __restrict__ deg, int n) {
    int i = blockIdx.x * 256 + threadIdx.x;
    if (i >= n) return;
    float v = (deg[i >> 8] > 0.f) ? p[i] : 0.f;
    p[i] = leaky02(v);
}

// ---------------- SAGE mean aggregation via CSR gather (block per node) ----------------
__global__ void sage_gather(const float* __restrict__ X, const int* __restrict__ rowptr,
                            const int* __restrict__ adjS, float* __restrict__ mean) {
    int n = blockIdx.x;
    int t = threadIdx.x;
    int b = rowptr[n], e_ = rowptr[n + 1];
    float acc = 0.f;
    for (int i = b; i < e_; ++i) acc += X[(long)adjS[i] * HD + t];
    mean[(long)n * HD + t] = acc / fmaxf((float)(e_ - b), 1.f);
}

// ---------------- fused MixAttention (wave per node, q cached in regs) ----------------
__global__ void attn_fused(const float* __restrict__ q, const float* __restrict__ k,
                           const float* __restrict__ v, const float* __restrict__ nrep,
                           const int* __restrict__ rowptr, const int* __restrict__ adjS,
                           float* __restrict__ scb, float* __restrict__ mixed) {
    int n = blockIdx.x * 4 + (threadIdx.x >> 6);
    int lane = threadIdx.x & 63;
    if (n >= NN) return;
    int b = rowptr[n], e_ = rowptr[n + 1];
    float4 qv = ((const float4*)(q + (long)n * HD))[lane];
    float m = -INFINITY;
    for (int i = b; i < e_; ++i) {
        int s = adjS[i];
        float4 kv = ((const float4*)(k + (long)s * HD))[lane];
        float p = qv.x * kv.x + qv.y * kv.y + qv.z * kv.z + qv.w * kv.w;
        for (int o = 32; o > 0; o >>= 1) p += __shfl_xor(p, o);
        p *= 0.0625f;
        if (lane == 0) scb[i] = p;
        m = fmaxf(m, p);
    }
    float ssum = 0.f;
    for (int i = b; i < e_; ++i) ssum += expf(scb[i] - m);
    float inv = 1.f / (ssum + 1e-16f);
    float4 acc = make_float4(0.f, 0.f, 0.f, 0.f);
    for (int i = b; i < e_; ++i) {
        int s = adjS[i];
        float al = expf(scb[i] - m) * inv;
        float4 vv = ((const float4*)(v + (long)s * HD))[lane];
        acc.x += al * vv.x; acc.y += al * vv.y; acc.z += al * vv.z; acc.w += al * vv.w;
    }
    float4 nr = ((const float4*)(nrep + (long)n * HD))[lane];
    acc.x += nr.x; acc.y += nr.y; acc.z += nr.z; acc.w += nr.w;
    ((float4*)(mixed + (long)n * HD))[lane] = acc;
}

__global__ void log_softmax_rows(float* __restrict__ out, int nrows) {
    int r = blockIdx.x * 256 + threadIdx.x;
    if (r >= nrows) return;
    float* p = out + (long)r * FOUT;
    float mx = -INFINITY;
    for (int i = 0; i < FOUT; ++i) mx = fmaxf(mx, p[i]);
    float s = 0.f;
    for (int i = 0; i < FOUT; ++i) s += expf(p[i] - mx);
    float ls = mx + logf(s);
    for (int i = 0; i < FOUT; ++i) p[i] -= ls;
}

// ---------------- host launch ----------------
static void build_scan(const int* cnt, int* rowptr, int* bsum, int n, int total, hipStream_t stream) {
    int nb = (n + 1023) / 1024;
    scan_pass1<<<nb, 256, 0, stream>>>(cnt, bsum, n);
    scan_pass2<<<1, 256, 0, stream>>>(bsum, nb);
    scan_pass3<<<nb, 256, 0, stream>>>(cnt, bsum, rowptr, n);
    set_i32<<<1, 1, 0, stream>>>(rowptr + n, total);
}

extern "C" void kernel_launch(void* const* d_in, const int* in_sizes, int n_in,
                              void* d_out, int out_size, void* d_ws, size_t ws_size,
                              hipStream_t stream) {
    (void)in_sizes; (void)n_in; (void)out_size; (void)ws_size;
    const float* x     = (const float*)d_in[0];
    const float* et    = (const float*)d_in[1];
    const int*   Hm    = (const int*)d_in[2];
    const int*   raw   = (const int*)d_in[3];
    const int*   lg    = (const int*)d_in[4];
    const float* W_gat = (const float*)d_in[5];
    const float* a_src = (const float*)d_in[6];
    const float* a_dst = (const float*)d_in[7];
    const float* b_gat = (const float*)d_in[8];
    const float* W_etn = (const float*)d_in[9];
    const float* W_eg  = (const float*)d_in[10];
    const float* Wr_e1 = (const float*)d_in[11];
    const float* Wn_e1 = (const float*)d_in[12];
    const float* b_e1  = (const float*)d_in[13];
    const float* Wr_e2 = (const float*)d_in[14];
    const float* Wn_e2 = (const float*)d_in[15];
    const float* b_e2  = (const float*)d_in[16];
    const float* Wr_n1 = (const float*)d_in[17];
    const float* Wn_n1 = (const float*)d_in[18];
    const float* b_n1  = (const float*)d_in[19];
    const float* Wr_n2 = (const float*)d_in[20];
    const float* Wn_n2 = (const float*)d_in[21];
    const float* b_n2  = (const float*)d_in[22];
    const float* Wr_n3 = (const float*)d_in[23];
    const float* Wn_n3 = (const float*)d_in[24];
    const float* b_n3  = (const float*)d_in[25];
    const float* Wq    = (const float*)d_in[26];
    const float* Wk    = (const float*)d_in[27];
    const float* Wv    = (const float*)d_in[28];
    const float* W_out = (const float*)d_in[29];

    const int* srcN = raw;
    const int* dstN = raw + EE;
    const int* lgs  = lg;
    const int* lgd  = lg + ELG;

    float* ws = (float*)d_ws;
    size_t off = 0;
    auto alloc = [&](size_t n) { float* p = ws + off; off += (n + 63) & ~(size_t)63; return p; };

    float* agg_et = alloc((size_t)EE * FE);      // later reused for q/k/v
    float* es     = alloc(EE);
    float* ed     = alloc(EE);
    float* Wcomb  = alloc((size_t)FE * HD);
    float* b2     = alloc(HD);
    float* asv    = alloc(FE);
    float* adv    = alloc(FE);
    float* agg2   = alloc((size_t)NN * FE);
    float* degE   = alloc(NN);
    float* etnL   = alloc((size_t)NN * HD);
    float* erep   = alloc((size_t)NN * HD);
    float* meanb  = alloc((size_t)NN * HD);
    float* t1     = alloc((size_t)NN * HD);
    float* aggr   = alloc((size_t)NN * HD);
    float* nrep   = alloc((size_t)NN * HD);
    float* scb    = alloc(EE);
    // bf16 weights region (ushort)
    unsigned short* wtb    = (unsigned short*)alloc(14 * 65536 / 2);
    unsigned short* wcombt = (unsigned short*)alloc(HD * FE / 2 + 64);
    // int region
    int* rowptrD  = (int*)alloc(NN + 64);
    int* cursD    = (int*)alloc(NN);
    int* adjS     = (int*)alloc(EE);
    int* rowptrLG = (int*)alloc(EE + 64);
    int* cursLG   = (int*)alloc(EE);
    int* adjLG    = (int*)alloc(ELG);
    int* rowptrH  = (int*)alloc(NN + 64);
    int* cursH    = (int*)alloc(NN);
    int* adjH     = (int*)alloc(2 * EE);
    int* cntbuf   = (int*)alloc(EE);
    int* bsum     = (int*)alloc(1024);
    // aliases (lifetime-checked)
    float* ta    = etnL;
    float* tb    = erep;
    float* qb    = agg_et;
    float* kb    = agg_et + (size_t)NN * HD;
    float* vb    = agg_et + (size_t)2 * NN * HD;
    float* mixed = t1;
    float* outp  = (float*)d_out;

    // bf16 transposed weight slots in wtb (order fixed)
    unsigned short* W_eg_t  = wtb + 0 * 65536;
    unsigned short* Wr_e1_t = wtb + 1 * 65536;
    unsigned short* Wn_e1_t = wtb + 2 * 65536;
    unsigned short* Wr_e2_t = wtb + 3 * 65536;
    unsigned short* Wn_e2_t = wtb + 4 * 65536;
    unsigned short* Wr_n1_t = wtb + 5 * 65536;
    unsigned short* Wn_n1_t = wtb + 6 * 65536;
    unsigned short* Wr_n2_t = wtb + 7 * 65536;
    unsigned short* Wn_n2_t = wtb + 8 * 65536;
    unsigned short* Wr_n3_t = wtb + 9 * 65536;
    unsigned short* Wn_n3_t = wtb + 10 * 65536;
    unsigned short* Wq_t    = wtb + 11 * 65536;
    unsigned short* Wk_t    = wtb + 12 * 65536;
    unsigned short* Wv_t    = wtb + 13 * 65536;

    dim3 gB(4, (NN + 127) / 128);   // bf16 GEMM grid: N=256/BN=64, M/BM=128

    // ================= weight conversion (independent, do first) =================
    Ptr14 p14;
    p14.p[0] = W_eg;  p14.p[1] = Wr_e1; p14.p[2] = Wn_e1; p14.p[3] = Wr_e2;
    p14.p[4] = Wn_e2; p14.p[5] = Wr_n1; p14.p[6] = Wn_n1; p14.p[7] = Wr_n2;
    p14.p[8] = Wn_n2; p14.p[9] = Wr_n3; p14.p[10] = Wn_n3; p14.p[11] = Wq;
    p14.p[12] = Wk;   p14.p[13] = Wv;
    wtrans14<<<14 * 64, 256, 0, stream>>>(p14, wtb);

    // ================= CSR builds =================
    zero_i32<<<(NN + 255) / 256, 256, 0, stream>>>(cntbuf, NN);
    count_i32<<<(EE + 255) / 256, 256, 0, stream>>>(dstN, cntbuf, EE);
    build_scan(cntbuf, rowptrD, bsum, NN, EE, stream);
    copy_i32<<<(NN + 255) / 256, 256, 0, stream>>>(cursD, rowptrD, NN);
    place_pair<<<(EE + 255) / 256, 256, 0, stream>>>(dstN, srcN, cursD, adjS, EE);
    zero_i32<<<(EE + 255) / 256, 256, 0, stream>>>(cntbuf, EE);
    count_i32<<<(ELG + 255) / 256, 256, 0, stream>>>(lgd, cntbuf, ELG);
    build_scan(cntbuf, rowptrLG, bsum, EE, ELG, stream);
    copy_i32<<<(EE + 255) / 256, 256, 0, stream>>>(cursLG, rowptrLG, EE);
    place_pair<<<(ELG + 255) / 256, 256, 0, stream>>>(lgd, lgs, cursLG, adjLG, ELG);
    zero_i32<<<(NN + 255) / 256, 256, 0, stream>>>(cntbuf, NN);
    count_h<<<(2 * EE + 255) / 256, 256, 0, stream>>>(Hm, cntbuf);
    build_scan(cntbuf, rowptrH, bsum, NN, 2 * EE, stream);
    copy_i32<<<(NN + 255) / 256, 256, 0, stream>>>(cursH, rowptrH, NN);
    place_h<<<(2 * EE + 255) / 256, 256, 0, stream>>>(Hm, cursH, adjH);

    // ================= GAT (line graph), folded: Wcomb = W_gat@W_etn =================
    gemm_f32<<<dim3(4, 1), 256, 0, stream>>>(W_gat, W_etn, nullptr, Wcomb, FE, HD, HD, 0);
    wtrans_one<<<(FE / 32) * (HD / 32), 256, 0, stream>>>(Wcomb, wcombt, FE, HD);
    bias_proj<<<1, 256, 0, stream>>>(b_gat, W_etn, b2);
    wg_av<<<FE, 256, 0, stream>>>(W_gat, a_src, a_dst, asv, adv);
    edge_scores<<<EE / 4, 256, 0, stream>>>(et, asv, adv, es, ed);
    gat_fused<<<(EE + 3) / 4, 256, 0, stream>>>(rowptrLG, adjLG, es, ed, et, agg_et);

    // ================= EdgeToNode incidence mean + GEMMs =================
    etn_gather<<<(NN + 3) / 4, 256, 0, stream>>>(rowptrH, adjH, agg_et, agg2, degE);
    gemm_bf16<<<gB, 256, 0, stream>>>(agg2, nullptr, wcombt, nullptr, b2, etnL, NN, FE, 0);
    etn_mask_leaky<<<(NN * HD + 255) / 256, 256, 0, stream>>>(etnL, degE, NN * HD);
    gemm_bf16<<<gB, 256, 0, stream>>>(etnL, nullptr, W_eg_t, nullptr, nullptr, erep, NN, HD, 0);

    // ================= edge_aggr SAGE (2 layers, dual-K fused) =================
    sage_gather<<<NN, 256, 0, stream>>>(erep, rowptrD, adjS, meanb);
    gemm_bf16<<<gB, 256, 0, stream>>>(erep, meanb, Wr_e1_t, Wn_e1_t, b_e1, t1, NN, HD, 1);
    sage_gather<<<NN, 256, 0, stream>>>(t1, rowptrD, adjS, meanb);
    gemm_bf16<<<gB, 256, 0, stream>>>(t1, meanb, Wr_e2_t, Wn_e2_t, b_e2, aggr, NN, HD, 0);

    // ================= attr_node SAGE (3 layers, dual-K fused) =================
    sage_gather<<<NN, 256, 0, stream>>>(x, rowptrD, adjS, meanb);
    gemm_bf16<<<gB, 256, 0, stream>>>(x, meanb, Wr_n1_t, Wn_n1_t, b_n1, ta, NN, HD, 1);
    sage_gather<<<NN, 256, 0, stream>>>(ta, rowptrD, adjS, meanb);
    gemm_bf16<<<gB, 256, 0, stream>>>(ta, meanb, Wr_n2_t, Wn_n2_t, b_n2, tb, NN, HD, 1);
    sage_gather<<<NN, 256, 0, stream>>>(tb, rowptrD, adjS, meanb);
    gemm_bf16<<<gB, 256, 0, stream>>>(tb, meanb, Wr_n3_t, Wn_n3_t, b_n3, nrep, NN, HD, 0);

    // ================= MixAttention (fused) =================
    gemm_bf16<<<gB, 256, 0, stream>>>(nrep, nullptr, Wq_t, nullptr, nullptr, qb, NN, HD, 0);
    gemm_bf16<<<gB, 256, 0, stream>>>(aggr, nullptr, Wk_t, nullptr, nullptr, kb, NN, HD, 0);
    gemm_bf16<<<gB, 256, 0, stream>>>(aggr, nullptr, Wv_t, nullptr, nullptr, vb, NN, HD, 0);
    attn_fused<<<(NN + 3) / 4, 256, 0, stream>>>(qb, kb, vb, nrep, rowptrD, adjS, scb, mixed);

    // ================= final linear + log_softmax =================
    gemm_f32<<<dim3(1, (NN + 63) / 64), 256, 0, stream>>>(mixed, W_out, nullptr, outp, NN, FOUT, HD, 0);
    log_softmax_rows<<<(NN + 255) / 256, 256, 0, stream>>>(outp, NN);
}

// Round 5
// 1081.401 us; speedup vs baseline: 3.3366x; 1.2974x over previous
//
#include <hip/hip_runtime.h>
#include <math.h>

#define NN   20000
#define EE   320000
#define ELG  600000
#define FE   64
#define HD   256
#define FOUT 40

typedef __attribute__((ext_vector_type(8))) short bf16x8;
typedef __attribute__((ext_vector_type(4))) float f32x4;

__device__ __forceinline__ float leaky02(float x) { return x > 0.f ? x : 0.2f * x; }

__device__ __forceinline__ unsigned short bf16rne(float f) {
    unsigned int u = __float_as_uint(f);
    u = (u + 0x7FFFu + ((u >> 16) & 1u)) >> 16;
    return (unsigned short)u;
}
__device__ __forceinline__ float bflo(unsigned int u) { return __uint_as_float(u << 16); }
__device__ __forceinline__ float bfhi(unsigned int u) { return __uint_as_float(u & 0xffff0000u); }
__device__ __forceinline__ unsigned int bfpack(float a, float b) {
    return (unsigned int)bf16rne(a) | ((unsigned int)bf16rne(b) << 16);
}

// ---------------- small utility kernels ----------------
__global__ void zero_i32(int* __restrict__ p, int n) {
    int i = blockIdx.x * 256 + threadIdx.x;
    if (i < n) p[i] = 0;
}
__global__ void copy_i32(int* __restrict__ d, const int* __restrict__ s, int n) {
    int i = blockIdx.x * 256 + threadIdx.x;
    if (i < n) d[i] = s[i];
}
__global__ void set_i32(int* __restrict__ p, int v) { *p = v; }

__global__ void count_i32(const int* __restrict__ idx, int* __restrict__ cnt, int n) {
    int i = blockIdx.x * 256 + threadIdx.x;
    if (i < n) atomicAdd(&cnt[idx[i]], 1);
}
__global__ void count_h(const int* __restrict__ Hm, int* __restrict__ cnt) {
    int i = blockIdx.x * 256 + threadIdx.x;
    if (i < 2 * EE) atomicAdd(&cnt[Hm[i]], 1);
}
// f32 -> packed bf16 (2 elems/thread)
__global__ void conv_bf16(const float* __restrict__ in, unsigned int* __restrict__ out, int n2) {
    int i = blockIdx.x * 256 + threadIdx.x;
    if (i < n2) { float2 v = ((const float2*)in)[i]; out[i] = bfpack(v.x, v.y); }
}

// ---------------- 3-pass exclusive scan ----------------
__global__ void scan_pass1(const int* __restrict__ in, int* __restrict__ bsum, int n) {
    __shared__ int sm[256];
    int base = blockIdx.x * 1024, t = threadIdx.x;
    int s = 0;
#pragma unroll
    for (int j = 0; j < 4; ++j) { int i = base + t * 4 + j; s += (i < n) ? in[i] : 0; }
    sm[t] = s; __syncthreads();
    for (int o = 128; o > 0; o >>= 1) { if (t < o) sm[t] += sm[t + o]; __syncthreads(); }
    if (t == 0) bsum[blockIdx.x] = sm[0];
}
__global__ void scan_pass2(int* __restrict__ bsum, int nb) {
    __shared__ int sm[1024];
    int t = threadIdx.x;
    for (int i = t; i < nb; i += 256) sm[i] = bsum[i];
    __syncthreads();
    if (t == 0) { int run = 0; for (int i = 0; i < nb; ++i) { int v = sm[i]; sm[i] = run; run += v; } }
    __syncthreads();
    for (int i = t; i < nb; i += 256) bsum[i] = sm[i];
}
__global__ void scan_pass3(const int* __restrict__ in, const int* __restrict__ boff,
                           int* __restrict__ out, int n) {
    __shared__ int tsum[256];
    int base = blockIdx.x * 1024, t = threadIdx.x;
    int v[4];
#pragma unroll
    for (int j = 0; j < 4; ++j) { int i = base + t * 4 + j; v[j] = (i < n) ? in[i] : 0; }
    int loc = v[0] + v[1] + v[2] + v[3];
    tsum[t] = loc; __syncthreads();
    for (int o = 1; o < 256; o <<= 1) {
        int x = (t >= o) ? tsum[t - o] : 0;
        __syncthreads();
        tsum[t] += x;
        __syncthreads();
    }
    int off = boff[blockIdx.x] + (tsum[t] - loc);
    int run = 0;
#pragma unroll
    for (int j = 0; j < 4; ++j) { int i = base + t * 4 + j; if (i < n) out[i] = off + run; run += v[j]; }
}

// ---------------- CSR placement ----------------
__global__ void place_pair(const int* __restrict__ seg, const int* __restrict__ val,
                           int* __restrict__ cursor, int* __restrict__ adj, int n) {
    int i = blockIdx.x * 256 + threadIdx.x;
    if (i >= n) return;
    int d = seg[i];
    int pos = atomicAdd(&cursor[d], 1);
    adj[pos] = val[i];
}
__global__ void place_h(const int* __restrict__ Hm, int* __restrict__ cursor, int* __restrict__ adj) {
    int i = blockIdx.x * 256 + threadIdx.x;
    if (i >= 2 * EE) return;
    int d = Hm[i];
    int pos = atomicAdd(&cursor[d], 1);
    adj[pos] = (i < EE) ? i : i - EE;
}

// ---------------- weight transpose+convert ----------------
struct Ptr14 { const float* p[14]; };
__global__ void wtrans14(Ptr14 srcs, unsigned short* __restrict__ dst) {
    int m = blockIdx.x >> 6;
    int tile = blockIdx.x & 63;
    const float* src = srcs.p[m];
    unsigned short* out = dst + (size_t)m * 65536;
    int kb = (tile >> 3) * 32, nb = (tile & 7) * 32;
    __shared__ float sm[32][33];
    int t = threadIdx.x;
#pragma unroll
    for (int i = 0; i < 4; ++i) {
        int e = t + i * 256; int r = e >> 5, c = e & 31;
        sm[r][c] = src[(kb + r) * 256 + nb + c];
    }
    __syncthreads();
#pragma unroll
    for (int i = 0; i < 4; ++i) {
        int e = t + i * 256; int nr = e >> 5, kc = e & 31;
        out[(size_t)(nb + nr) * 256 + kb + kc] = bf16rne(sm[kc][nr]);
    }
}
__global__ void wtrans_one(const float* __restrict__ src, unsigned short* __restrict__ dst,
                           int K, int N) {
    int tilesN = N >> 5;
    int kb = (blockIdx.x / tilesN) * 32, nb = (blockIdx.x % tilesN) * 32;
    __shared__ float sm[32][33];
    int t = threadIdx.x;
#pragma unroll
    for (int i = 0; i < 4; ++i) {
        int e = t + i * 256; int r = e >> 5, c = e & 31;
        sm[r][c] = src[(kb + r) * N + nb + c];
    }
    __syncthreads();
#pragma unroll
    for (int i = 0; i < 4; ++i) {
        int e = t + i * 256; int nr = e >> 5, kc = e & 31;
        dst[(size_t)(nb + nr) * K + kb + kc] = bf16rne(sm[kc][nr]);
    }
}

// ---------------- bf16 MFMA GEMM: C_bf16[M,256] = A1@W1 (+A2@W2) (+bias)(act) ----------------
// A1/A2 bf16 [M][Klen]; W transposed bf16 [256][Klen].
// flags: 1=relu, 4=degE-mask + leaky
__global__ __launch_bounds__(256)
void gemm_bf16(const unsigned short* __restrict__ A1, const unsigned short* __restrict__ A2,
               const unsigned short* __restrict__ W1, const unsigned short* __restrict__ W2,
               const float* __restrict__ bias, const float* __restrict__ degmask,
               unsigned short* __restrict__ C, int M, int K1, int flags) {
    __shared__ unsigned short As[128][40];
    __shared__ unsigned short Bs[64][40];
    int tid = threadIdx.x;
    int w = tid >> 6, l = tid & 63;
    int wr = w >> 1, wc = w & 1;
    int brow = blockIdx.y * 128, bcol = blockIdx.x * 64;
    int Ktot = K1 + (A2 ? 256 : 0);
    f32x4 acc[4][2] = {};
    for (int k0 = 0; k0 < Ktot; k0 += 32) {
        const unsigned short* Ap; const unsigned short* Wp; int kk, Klen;
        if (k0 < K1) { Ap = A1; Wp = W1; kk = k0; Klen = K1; }
        else         { Ap = A2; Wp = W2; kk = k0 - K1; Klen = 256; }
#pragma unroll
        for (int i = 0; i < 4; ++i) {
            int q = tid + i * 256;
            int r = q >> 3, kb = (q & 7) * 4;
            int gr = brow + r;
            ushort4 u;
            if (gr < M) u = *(const ushort4*)(Ap + (size_t)gr * Klen + kk + kb);
            else { u.x = 0; u.y = 0; u.z = 0; u.w = 0; }
            *(ushort4*)(&As[r][kb]) = u;
        }
#pragma unroll
        for (int i = 0; i < 2; ++i) {
            int q = tid + i * 256;
            int n = q >> 3, kb = (q & 7) * 4;
            *(ushort4*)(&Bs[n][kb]) = *(const ushort4*)(Wp + (size_t)(bcol + n) * Klen + kk + kb);
        }
        __syncthreads();
        bf16x8 af[4], bfr[2];
#pragma unroll
        for (int fr = 0; fr < 4; ++fr)
            af[fr] = *(const bf16x8*)(&As[wr * 64 + fr * 16 + (l & 15)][(l >> 4) * 8]);
#pragma unroll
        for (int fc = 0; fc < 2; ++fc)
            bfr[fc] = *(const bf16x8*)(&Bs[wc * 32 + fc * 16 + (l & 15)][(l >> 4) * 8]);
#pragma unroll
        for (int fr = 0; fr < 4; ++fr)
#pragma unroll
            for (int fc = 0; fc < 2; ++fc)
                acc[fr][fc] = __builtin_amdgcn_mfma_f32_16x16x32_bf16(af[fr], bfr[fc], acc[fr][fc], 0, 0, 0);
        __syncthreads();
    }
#pragma unroll
    for (int fr = 0; fr < 4; ++fr) {
#pragma unroll
        for (int fc = 0; fc < 2; ++fc) {
            int col = bcol + wc * 32 + fc * 16 + (l & 15);
#pragma unroll
            for (int i = 0; i < 4; ++i) {
                int row = brow + wr * 64 + fr * 16 + (l >> 4) * 4 + i;
                if (row >= M) continue;
                float v = acc[fr][fc][i];
                if (bias) v += bias[col];
                if (flags & 1) v = fmaxf(v, 0.f);
                if (flags & 4) { v = (degmask[row] > 0.f) ? v : 0.f; v = leaky02(v); }
                C[(size_t)row * 256 + col] = bf16rne(v);
            }
        }
    }
}

// ---------------- fp32 GEMM (Wcomb build, final W_out) ----------------
__global__ __launch_bounds__(256)
void gemm_f32(const float* __restrict__ A, const float* __restrict__ B,
              const float* __restrict__ bias, float* __restrict__ C,
              int M, int N, int K, int flags) {
    const int BM = 64, BN = 64, BK = 16;
    __shared__ float As[BK][BM + 1];
    __shared__ float Bs[BK][BN + 1];
    int tid = threadIdx.x;
    int tr = tid >> 4, tc = tid & 15;
    int brow = blockIdx.y * BM, bcol = blockIdx.x * BN;
    float acc[4][4] = {{0.f}};
    for (int k0 = 0; k0 < K; k0 += BK) {
#pragma unroll
        for (int i = 0; i < 4; ++i) {
            int e = tid + i * 256;
            int r = e >> 4, c = e & 15;
            int gr = brow + r, gc = k0 + c;
            As[c][r] = (gr < M && gc < K) ? A[(long)gr * K + gc] : 0.f;
        }
#pragma unroll
        for (int i = 0; i < 4; ++i) {
            int e = tid + i * 256;
            int r = e >> 6, c = e & 63;
            int gr = k0 + r, gc = bcol + c;
            Bs[r][c] = (gr < K && gc < N) ? B[(long)gr * N + gc] : 0.f;
        }
        __syncthreads();
#pragma unroll
        for (int k = 0; k < BK; ++k) {
            float ra[4], rb[4];
#pragma unroll
            for (int i = 0; i < 4; ++i) ra[i] = As[k][tr * 4 + i];
#pragma unroll
            for (int j = 0; j < 4; ++j) rb[j] = Bs[k][tc * 4 + j];
#pragma unroll
            for (int i = 0; i < 4; ++i)
#pragma unroll
                for (int j = 0; j < 4; ++j) acc[i][j] += ra[i] * rb[j];
        }
        __syncthreads();
    }
#pragma unroll
    for (int i = 0; i < 4; ++i) {
        int gr = brow + tr * 4 + i;
        if (gr >= M) continue;
#pragma unroll
        for (int j = 0; j < 4; ++j) {
            int gc = bcol + tc * 4 + j;
            if (gc >= N) continue;
            float v = acc[i][j];
            if (bias) v += bias[gc];
            C[(long)gr * N + gc] = v;
        }
    }
}

// ---------------- GAT pre-computation ----------------
__global__ void wg_av(const float* __restrict__ W, const float* __restrict__ as_,
                      const float* __restrict__ ad_, float* __restrict__ asv,
                      float* __restrict__ adv) {
    __shared__ float sm[256];
    int i = blockIdx.x, t = threadIdx.x;
    float w = W[i * HD + t];
    sm[t] = w * as_[t];
    __syncthreads();
    for (int o = 128; o > 0; o >>= 1) { if (t < o) sm[t] += sm[t + o]; __syncthreads(); }
    if (t == 0) asv[i] = sm[0];
    __syncthreads();
    sm[t] = w * ad_[t];
    __syncthreads();
    for (int o = 128; o > 0; o >>= 1) { if (t < o) sm[t] += sm[t + o]; __syncthreads(); }
    if (t == 0) adv[i] = sm[0];
}

__global__ void bias_proj(const float* __restrict__ b, const float* __restrict__ W,
                          float* __restrict__ b2) {
    int j = threadIdx.x;
    float s = 0.f;
    for (int i = 0; i < HD; ++i) s += b[i] * W[i * HD + j];
    b2[j] = s;
}

// es/ed scores + et -> bf16 conversion fused (wave per edge)
__global__ void edge_scores_conv(const float* __restrict__ et, const float* __restrict__ asv,
                                 const float* __restrict__ adv, float* __restrict__ es,
                                 float* __restrict__ ed, unsigned short* __restrict__ et_bf) {
    int e = blockIdx.x * 4 + (threadIdx.x >> 6);
    int l = threadIdx.x & 63;
    float x = et[(long)e * FE + l];
    et_bf[(long)e * FE + l] = bf16rne(x);
    float vs = x * asv[l];
    float vd = x * adv[l];
    for (int o = 32; o > 0; o >>= 1) { vs += __shfl_down(vs, o); vd += __shfl_down(vd, o); }
    if (l == 0) { es[e] = vs; ed[e] = vd; }
}

// ---------------- GAT: scalar alpha (thread per segment) ----------------
__global__ void seg_alpha(const int* __restrict__ rowptr, const int* __restrict__ adj,
                          const float* __restrict__ es, const float* __restrict__ ed,
                          float* __restrict__ alphaS, float* __restrict__ alphaL) {
    int d = blockIdx.x * 256 + threadIdx.x;
    if (d >= EE) return;
    int b = rowptr[d], e_ = rowptr[d + 1];
    float edd = ed[d];
    float selfsc = leaky02(es[d] + edd);
    float m = selfsc;
    for (int i = b; i < e_; ++i) m = fmaxf(m, leaky02(es[adj[i]] + edd));
    float s = expf(selfsc - m);
    for (int i = b; i < e_; ++i) s += expf(leaky02(es[adj[i]] + edd) - m);
    float inv = 1.f / (s + 1e-16f);
    alphaS[d] = expf(selfsc - m) * inv;
    for (int i = b; i < e_; ++i) alphaL[i] = expf(leaky02(es[adj[i]] + edd) - m) * inv;
}

// ---------------- GAT: weighted gather (wave per segment, 2-entry-parallel) ----------------
__global__ void gat_gather(const int* __restrict__ rowptr, const int* __restrict__ adj,
                           const float* __restrict__ alphaS, const float* __restrict__ alphaL,
                           const unsigned short* __restrict__ et_bf,
                           unsigned short* __restrict__ agg_et) {
    int d = blockIdx.x * 4 + (threadIdx.x >> 6);
    int lane = threadIdx.x & 63;
    if (d >= EE) return;
    int b = rowptr[d], e_ = rowptr[d + 1];
    int cnt = e_ - b + 1;                      // + self
    int hl = lane & 31, half = lane >> 5;
    const unsigned int* etu = (const unsigned int*)et_bf;
    float a0 = 0.f, a1 = 0.f;
    for (int j = half; j < cnt; j += 2) {
        int row; float al;
        if (j == 0) { row = d; al = alphaS[d]; }
        else { int i = b + j - 1; row = adj[i]; al = alphaL[i]; }
        unsigned int u = etu[(size_t)row * 32 + hl];
        a0 += al * bflo(u); a1 += al * bfhi(u);
    }
    a0 += __shfl_xor(a0, 32);
    a1 += __shfl_xor(a1, 32);
    if (half == 0)
        ((unsigned int*)agg_et)[(size_t)d * 32 + hl] = bfpack(a0, a1);
}

// ---------------- incidence mean (wave per node, 2-entry-parallel) ----------------
__global__ void etn_gather_bf(const int* __restrict__ rowptr, const int* __restrict__ adj,
                              const unsigned short* __restrict__ agg_et,
                              unsigned short* __restrict__ agg2, float* __restrict__ degE) {
    int n = blockIdx.x * 4 + (threadIdx.x >> 6);
    int lane = threadIdx.x & 63;
    if (n >= NN) return;
    int b = rowptr[n], e_ = rowptr[n + 1];
    int hl = lane & 31, half = lane >> 5;
    const unsigned int* au = (const unsigned int*)agg_et;
    float a0 = 0.f, a1 = 0.f;
    for (int i = b + half; i < e_; i += 2) {
        unsigned int u = au[(size_t)adj[i] * 32 + hl];
        a0 += bflo(u); a1 += bfhi(u);
    }
    a0 += __shfl_xor(a0, 32);
    a1 += __shfl_xor(a1, 32);
    float deg = (float)(e_ - b);
    float inv = 1.f / fmaxf(deg, 1.f);
    if (half == 0) ((unsigned int*)agg2)[(size_t)n * 32 + hl] = bfpack(a0 * inv, a1 * inv);
    if (lane == 0) degE[n] = deg;
}

// ---------------- SAGE mean aggregation (bf16, block=128, node per block) ----------------
__global__ void sage_gather_bf(const unsigned short* __restrict__ X, const int* __restrict__ rowptr,
                               const int* __restrict__ adjS, unsigned short* __restrict__ mean) {
    int n = blockIdx.x;
    int t = threadIdx.x;                       // 0..127, covers features 2t, 2t+1
    int b = rowptr[n], e_ = rowptr[n + 1];
    const unsigned int* Xu = (const unsigned int*)X;
    float a0 = 0.f, a1 = 0.f;
    for (int i = b; i < e_; ++i) {
        unsigned int u = Xu[(size_t)adjS[i] * 128 + t];
        a0 += bflo(u); a1 += bfhi(u);
    }
    float inv = 1.f / fmaxf((float)(e_ - b), 1.f);
    ((unsigned int*)mean)[(size_t)n * 128 + t] = bfpack(a0 * inv, a1 * inv);
}

// ---------------- fused MixAttention (bf16 q/k/v, wave per node) ----------------
__global__ void attn_fused_bf(const unsigned short* __restrict__ q, const unsigned short* __restrict__ k,
                              const unsigned short* __restrict__ v, const unsigned short* __restrict__ nrep,
                              const int* __restrict__ rowptr, const int* __restrict__ adjS,
                              float* __restrict__ scb, float* __restrict__ mixed) {
    int n = blockIdx.x * 4 + (threadIdx.x >> 6);
    int lane = threadIdx.x & 63;
    if (n >= NN) return;
    int b = rowptr[n], e_ = rowptr[n + 1];
    uint2 qu = ((const uint2*)(q + (size_t)n * HD))[lane];
    float q0 = bflo(qu.x), q1 = bfhi(qu.x), q2 = bflo(qu.y), q3 = bfhi(qu.y);
    float m = -INFINITY;
    for (int i = b; i < e_; ++i) {
        int s = adjS[i];
        uint2 ku = ((const uint2*)(k + (size_t)s * HD))[lane];
        float p = q0 * bflo(ku.x) + q1 * bfhi(ku.x) + q2 * bflo(ku.y) + q3 * bfhi(ku.y);
        for (int o = 32; o > 0; o >>= 1) p += __shfl_xor(p, o);
        p *= 0.0625f;
        if (lane == 0) scb[i] = p;
        m = fmaxf(m, p);
    }
    float ssum = 0.f;
    for (int i = b; i < e_; ++i) ssum += expf(scb[i] - m);
    float inv = 1.f / (ssum + 1e-16f);
    float a0 = 0.f, a1 = 0.f, a2 = 0.f, a3 = 0.f;
    for (int i = b; i < e_; ++i) {
        int s = adjS[i];
        float al = expf(scb[i] - m) * inv;
        uint2 vu = ((const uint2*)(v + (size_t)s * HD))[lane];
        a0 += al * bflo(vu.x); a1 += al * bfhi(vu.x); a2 += al * bflo(vu.y); a3 += al * bfhi(vu.y);
    }
    uint2 nu = ((const uint2*)(nrep + (size_t)n * HD))[lane];
    float4 o;
    o.x = a0 + bflo(nu.x); o.y = a1 + bfhi(nu.x); o.z = a2 + bflo(nu.y); o.w = a3 + bfhi(nu.y);
    ((float4*)(mixed + (size_t)n * HD))[lane] = o;
}

__global__ void log_softmax_rows(float* __restrict__ out, int nrows) {
    int r = blockIdx.x * 256 + threadIdx.x;
    if (r >= nrows) return;
    float* p = out + (long)r * FOUT;
    float mx = -INFINITY;
    for (int i = 0; i < FOUT; ++i) mx = fmaxf(mx, p[i]);
    float s = 0.f;
    for (int i = 0; i < FOUT; ++i) s += expf(p[i] - mx);
    float ls = mx + logf(s);
    for (int i = 0; i < FOUT; ++i) p[i] -= ls;
}

// ---------------- host launch ----------------
static void build_scan(const int* cnt, int* rowptr, int* bsum, int n, int total, hipStream_t stream) {
    int nb = (n + 1023) / 1024;
    scan_pass1<<<nb, 256, 0, stream>>>(cnt, bsum, n);
    scan_pass2<<<1, 256, 0, stream>>>(bsum, nb);
    scan_pass3<<<nb, 256, 0, stream>>>(cnt, bsum, rowptr, n);
    set_i32<<<1, 1, 0, stream>>>(rowptr + n, total);
}

extern "C" void kernel_launch(void* const* d_in, const int* in_sizes, int n_in,
                              void* d_out, int out_size, void* d_ws, size_t ws_size,
                              hipStream_t stream) {
    (void)in_sizes; (void)n_in; (void)out_size; (void)ws_size;
    const float* x     = (const float*)d_in[0];
    const float* et    = (const float*)d_in[1];
    const int*   Hm    = (const int*)d_in[2];
    const int*   raw   = (const int*)d_in[3];
    const int*   lg    = (const int*)d_in[4];
    const float* W_gat = (const float*)d_in[5];
    const float* a_src = (const float*)d_in[6];
    const float* a_dst = (const float*)d_in[7];
    const float* b_gat = (const float*)d_in[8];
    const float* W_etn = (const float*)d_in[9];
    const float* W_eg  = (const float*)d_in[10];
    const float* Wr_e1 = (const float*)d_in[11];
    const float* Wn_e1 = (const float*)d_in[12];
    const float* b_e1  = (const float*)d_in[13];
    const float* Wr_e2 = (const float*)d_in[14];
    const float* Wn_e2 = (const float*)d_in[15];
    const float* b_e2  = (const float*)d_in[16];
    const float* Wr_n1 = (const float*)d_in[17];
    const float* Wn_n1 = (const float*)d_in[18];
    const float* b_n1  = (const float*)d_in[19];
    const float* Wr_n2 = (const float*)d_in[20];
    const float* Wn_n2 = (const float*)d_in[21];
    const float* b_n2  = (const float*)d_in[22];
    const float* Wr_n3 = (const float*)d_in[23];
    const float* Wn_n3 = (const float*)d_in[24];
    const float* b_n3  = (const float*)d_in[25];
    const float* Wq    = (const float*)d_in[26];
    const float* Wk    = (const float*)d_in[27];
    const float* Wv    = (const float*)d_in[28];
    const float* W_out = (const float*)d_in[29];

    const int* srcN = raw;
    const int* dstN = raw + EE;
    const int* lgs  = lg;
    const int* lgd  = lg + ELG;

    float* ws = (float*)d_ws;
    size_t off = 0;
    auto alloc = [&](size_t n) { float* p = ws + off; off += (n + 63) & ~(size_t)63; return p; };
    auto allocU = [&](size_t nus) { return (unsigned short*)alloc(nus / 2 + 64); };

    unsigned short* et_bf   = allocU((size_t)EE * FE);
    unsigned short* agg_et  = allocU((size_t)EE * FE);   // reused later as q/k/v
    float* es     = alloc(EE);
    float* ed     = alloc(EE);
    float* alphaS = alloc(EE);
    float* alphaL = alloc(ELG);
    float* Wcomb  = alloc((size_t)FE * HD);
    float* b2     = alloc(HD);
    float* asv    = alloc(FE);
    float* adv    = alloc(FE);
    unsigned short* agg2_bf = allocU((size_t)NN * FE);
    float* degE   = alloc(NN);
    unsigned short* etnL  = allocU((size_t)NN * HD);
    unsigned short* erep  = allocU((size_t)NN * HD);
    unsigned short* meanb = allocU((size_t)NN * HD);
    unsigned short* t1    = allocU((size_t)NN * HD);
    unsigned short* aggr  = allocU((size_t)NN * HD);
    unsigned short* nrep  = allocU((size_t)NN * HD);
    unsigned short* x_bf  = allocU((size_t)NN * HD);
    float* mixed  = alloc((size_t)NN * HD);
    float* scb    = alloc(EE);
    unsigned short* wtb    = allocU((size_t)14 * 65536);
    unsigned short* wcombt = allocU((size_t)HD * FE);
    int* rowptrD  = (int*)alloc(NN + 64);
    int* cursD    = (int*)alloc(NN);
    int* adjS     = (int*)alloc(EE);
    int* rowptrLG = (int*)alloc(EE + 64);
    int* cursLG   = (int*)alloc(EE);
    int* adjLG    = (int*)alloc(ELG);
    int* rowptrH  = (int*)alloc(NN + 64);
    int* cursH    = (int*)alloc(NN);
    int* adjH     = (int*)alloc(2 * EE);
    int* cntbuf   = (int*)alloc(EE);
    int* bsum     = (int*)alloc(1024);
    // aliases (lifetime-checked)
    unsigned short* ta = etnL;                 // etnL dead after erep GEMM
    unsigned short* tb = erep;                 // erep dead after edge layer 1
    unsigned short* qb = agg_et;               // agg_et dead after etn_gather
    unsigned short* kb = agg_et + (size_t)NN * HD;
    unsigned short* vb = agg_et + (size_t)2 * NN * HD;
    float* outp = (float*)d_out;

    unsigned short* W_eg_t  = wtb + 0 * 65536;
    unsigned short* Wr_e1_t = wtb + 1 * 65536;
    unsigned short* Wn_e1_t = wtb + 2 * 65536;
    unsigned short* Wr_e2_t = wtb + 3 * 65536;
    unsigned short* Wn_e2_t = wtb + 4 * 65536;
    unsigned short* Wr_n1_t = wtb + 5 * 65536;
    unsigned short* Wn_n1_t = wtb + 6 * 65536;
    unsigned short* Wr_n2_t = wtb + 7 * 65536;
    unsigned short* Wn_n2_t = wtb + 8 * 65536;
    unsigned short* Wr_n3_t = wtb + 9 * 65536;
    unsigned short* Wn_n3_t = wtb + 10 * 65536;
    unsigned short* Wq_t    = wtb + 11 * 65536;
    unsigned short* Wk_t    = wtb + 12 * 65536;
    unsigned short* Wv_t    = wtb + 13 * 65536;

    dim3 gB(4, (NN + 127) / 128);

    // ======== weight conversion + x conversion (independent) ========
    Ptr14 p14;
    p14.p[0] = W_eg;  p14.p[1] = Wr_e1; p14.p[2] = Wn_e1; p14.p[3] = Wr_e2;
    p14.p[4] = Wn_e2; p14.p[5] = Wr_n1; p14.p[6] = Wn_n1; p14.p[7] = Wr_n2;
    p14.p[8] = Wn_n2; p14.p[9] = Wr_n3; p14.p[10] = Wn_n3; p14.p[11] = Wq;
    p14.p[12] = Wk;   p14.p[13] = Wv;
    wtrans14<<<14 * 64, 256, 0, stream>>>(p14, wtb);
    conv_bf16<<<(NN * HD / 2 + 255) / 256, 256, 0, stream>>>(x, (unsigned int*)x_bf, NN * HD / 2);

    // ======== CSR builds ========
    zero_i32<<<(NN + 255) / 256, 256, 0, stream>>>(cntbuf, NN);
    count_i32<<<(EE + 255) / 256, 256, 0, stream>>>(dstN, cntbuf, EE);
    build_scan(cntbuf, rowptrD, bsum, NN, EE, stream);
    copy_i32<<<(NN + 255) / 256, 256, 0, stream>>>(cursD, rowptrD, NN);
    place_pair<<<(EE + 255) / 256, 256, 0, stream>>>(dstN, srcN, cursD, adjS, EE);
    zero_i32<<<(EE + 255) / 256, 256, 0, stream>>>(cntbuf, EE);
    count_i32<<<(ELG + 255) / 256, 256, 0, stream>>>(lgd, cntbuf, ELG);
    build_scan(cntbuf, rowptrLG, bsum, EE, ELG, stream);
    copy_i32<<<(EE + 255) / 256, 256, 0, stream>>>(cursLG, rowptrLG, EE);
    place_pair<<<(ELG + 255) / 256, 256, 0, stream>>>(lgd, lgs, cursLG, adjLG, ELG);
    zero_i32<<<(NN + 255) / 256, 256, 0, stream>>>(cntbuf, NN);
    count_h<<<(2 * EE + 255) / 256, 256, 0, stream>>>(Hm, cntbuf);
    build_scan(cntbuf, rowptrH, bsum, NN, 2 * EE, stream);
    copy_i32<<<(NN + 255) / 256, 256, 0, stream>>>(cursH, rowptrH, NN);
    place_h<<<(2 * EE + 255) / 256, 256, 0, stream>>>(Hm, cursH, adjH);

    // ======== GAT (folded Wcomb = W_gat@W_etn) ========
    gemm_f32<<<dim3(4, 1), 256, 0, stream>>>(W_gat, W_etn, nullptr, Wcomb, FE, HD, HD, 0);
    wtrans_one<<<(FE / 32) * (HD / 32), 256, 0, stream>>>(Wcomb, wcombt, FE, HD);
    bias_proj<<<1, 256, 0, stream>>>(b_gat, W_etn, b2);
    wg_av<<<FE, 256, 0, stream>>>(W_gat, a_src, a_dst, asv, adv);
    edge_scores_conv<<<EE / 4, 256, 0, stream>>>(et, asv, adv, es, ed, et_bf);
    seg_alpha<<<(EE + 255) / 256, 256, 0, stream>>>(rowptrLG, adjLG, es, ed, alphaS, alphaL);
    gat_gather<<<(EE + 3) / 4, 256, 0, stream>>>(rowptrLG, adjLG, alphaS, alphaL, et_bf, agg_et);

    // ======== EdgeToNode incidence mean + GEMMs ========
    etn_gather_bf<<<(NN + 3) / 4, 256, 0, stream>>>(rowptrH, adjH, agg_et, agg2_bf, degE);
    gemm_bf16<<<gB, 256, 0, stream>>>(agg2_bf, nullptr, wcombt, nullptr, b2, degE, etnL, NN, FE, 4);
    gemm_bf16<<<gB, 256, 0, stream>>>(etnL, nullptr, W_eg_t, nullptr, nullptr, nullptr, erep, NN, HD, 0);

    // ======== edge_aggr SAGE (2 layers, dual-K fused) ========
    sage_gather_bf<<<NN, 128, 0, stream>>>(erep, rowptrD, adjS, meanb);
    gemm_bf16<<<gB, 256, 0, stream>>>(erep, meanb, Wr_e1_t, Wn_e1_t, b_e1, nullptr, t1, NN, HD, 1);
    sage_gather_bf<<<NN, 128, 0, stream>>>(t1, rowptrD, adjS, meanb);
    gemm_bf16<<<gB, 256, 0, stream>>>(t1, meanb, Wr_e2_t, Wn_e2_t, b_e2, nullptr, aggr, NN, HD, 0);

    // ======== attr_node SAGE (3 layers, dual-K fused) ========
    sage_gather_bf<<<NN, 128, 0, stream>>>(x_bf, rowptrD, adjS, meanb);
    gemm_bf16<<<gB, 256, 0, stream>>>(x_bf, meanb, Wr_n1_t, Wn_n1_t, b_n1, nullptr, ta, NN, HD, 1);
    sage_gather_bf<<<NN, 128, 0, stream>>>(ta, rowptrD, adjS, meanb);
    gemm_bf16<<<gB, 256, 0, stream>>>(ta, meanb, Wr_n2_t, Wn_n2_t, b_n2, nullptr, tb, NN, HD, 1);
    sage_gather_bf<<<NN, 128, 0, stream>>>(tb, rowptrD, adjS, meanb);
    gemm_bf16<<<gB, 256, 0, stream>>>(tb, meanb, Wr_n3_t, Wn_n3_t, b_n3, nullptr, nrep, NN, HD, 0);

    // ======== MixAttention ========
    gemm_bf16<<<gB, 256, 0, stream>>>(nrep, nullptr, Wq_t, nullptr, nullptr, nullptr, qb, NN, HD, 0);
    gemm_bf16<<<gB, 256, 0, stream>>>(aggr, nullptr, Wk_t, nullptr, nullptr, nullptr, kb, NN, HD, 0);
    gemm_bf16<<<gB, 256, 0, stream>>>(aggr, nullptr, Wv_t, nullptr, nullptr, nullptr, vb, NN, HD, 0);
    attn_fused_bf<<<(NN + 3) / 4, 256, 0, stream>>>(qb, kb, vb, nrep, rowptrD, adjS, scb, mixed);

    // ======== final linear + log_softmax ========
    gemm_f32<<<dim3(1, (NN + 63) / 64), 256, 0, stream>>>(mixed, W_out, nullptr, outp, NN, FOUT, HD, 0);
    log_softmax_rows<<<(NN + 255) / 256, 256, 0, stream>>>(outp, NN);
}

// Round 6
// 977.892 us; speedup vs baseline: 3.6898x; 1.1058x over previous
//
#include <hip/hip_runtime.h>
#include <math.h>

#define NN   20000
#define EE   320000
#define ELG  600000
#define FE   64
#define HD   256
#define FOUT 40
#define LOG2E 1.44269504f

typedef __attribute__((ext_vector_type(8))) short bf16x8;
typedef __attribute__((ext_vector_type(4))) float f32x4;

__device__ __forceinline__ float leaky02(float x) { return x > 0.f ? x : 0.2f * x; }

__device__ __forceinline__ unsigned short bf16rne(float f) {
    unsigned int u = __float_as_uint(f);
    u = (u + 0x7FFFu + ((u >> 16) & 1u)) >> 16;
    return (unsigned short)u;
}
__device__ __forceinline__ float bflo(unsigned int u) { return __uint_as_float(u << 16); }
__device__ __forceinline__ float bfhi(unsigned int u) { return __uint_as_float(u & 0xffff0000u); }
__device__ __forceinline__ unsigned int bfpack(float a, float b) {
    return (unsigned int)bf16rne(a) | ((unsigned int)bf16rne(b) << 16);
}

// ---------------- small utility kernels ----------------
__global__ void zero_i32(int* __restrict__ p, int n) {
    int i = blockIdx.x * 256 + threadIdx.x;
    if (i < n) p[i] = 0;
}
__global__ void copy_i32(int* __restrict__ d, const int* __restrict__ s, int n) {
    int i = blockIdx.x * 256 + threadIdx.x;
    if (i < n) d[i] = s[i];
}
__global__ void set_i32(int* __restrict__ p, int v) { *p = v; }

__global__ void count_i32(const int* __restrict__ idx, int* __restrict__ cnt, int n) {
    int i = blockIdx.x * 256 + threadIdx.x;
    if (i < n) atomicAdd(&cnt[idx[i]], 1);
}
__global__ void count_h(const int* __restrict__ Hm, int* __restrict__ cnt) {
    int i = blockIdx.x * 256 + threadIdx.x;
    if (i < 2 * EE) atomicAdd(&cnt[Hm[i]], 1);
}
__global__ void conv_bf16(const float* __restrict__ in, unsigned int* __restrict__ out, int n2) {
    int i = blockIdx.x * 256 + threadIdx.x;
    if (i < n2) { float2 v = ((const float2*)in)[i]; out[i] = bfpack(v.x, v.y); }
}

// ---------------- 3-pass exclusive scan ----------------
__global__ void scan_pass1(const int* __restrict__ in, int* __restrict__ bsum, int n) {
    __shared__ int sm[256];
    int base = blockIdx.x * 1024, t = threadIdx.x;
    int s = 0;
#pragma unroll
    for (int j = 0; j < 4; ++j) { int i = base + t * 4 + j; s += (i < n) ? in[i] : 0; }
    sm[t] = s; __syncthreads();
    for (int o = 128; o > 0; o >>= 1) { if (t < o) sm[t] += sm[t + o]; __syncthreads(); }
    if (t == 0) bsum[blockIdx.x] = sm[0];
}
__global__ void scan_pass2(int* __restrict__ bsum, int nb) {
    __shared__ int sm[1024];
    int t = threadIdx.x;
    for (int i = t; i < nb; i += 256) sm[i] = bsum[i];
    __syncthreads();
    if (t == 0) { int run = 0; for (int i = 0; i < nb; ++i) { int v = sm[i]; sm[i] = run; run += v; } }
    __syncthreads();
    for (int i = t; i < nb; i += 256) bsum[i] = sm[i];
}
__global__ void scan_pass3(const int* __restrict__ in, const int* __restrict__ boff,
                           int* __restrict__ out, int n) {
    __shared__ int tsum[256];
    int base = blockIdx.x * 1024, t = threadIdx.x;
    int v[4];
#pragma unroll
    for (int j = 0; j < 4; ++j) { int i = base + t * 4 + j; v[j] = (i < n) ? in[i] : 0; }
    int loc = v[0] + v[1] + v[2] + v[3];
    tsum[t] = loc; __syncthreads();
    for (int o = 1; o < 256; o <<= 1) {
        int x = (t >= o) ? tsum[t - o] : 0;
        __syncthreads();
        tsum[t] += x;
        __syncthreads();
    }
    int off = boff[blockIdx.x] + (tsum[t] - loc);
    int run = 0;
#pragma unroll
    for (int j = 0; j < 4; ++j) { int i = base + t * 4 + j; if (i < n) out[i] = off + run; run += v[j]; }
}

// ---------------- CSR placement ----------------
__global__ void place_pair(const int* __restrict__ seg, const int* __restrict__ val,
                           int* __restrict__ cursor, int* __restrict__ adj, int n) {
    int i = blockIdx.x * 256 + threadIdx.x;
    if (i >= n) return;
    int d = seg[i];
    int pos = atomicAdd(&cursor[d], 1);
    adj[pos] = val[i];
}
__global__ void place_h(const int* __restrict__ Hm, int* __restrict__ cursor, int* __restrict__ adj) {
    int i = blockIdx.x * 256 + threadIdx.x;
    if (i >= 2 * EE) return;
    int d = Hm[i];
    int pos = atomicAdd(&cursor[d], 1);
    adj[pos] = (i < EE) ? i : i - EE;
}

// ---------------- weight transpose+convert ----------------
struct Ptr14 { const float* p[14]; };
__global__ void wtrans14(Ptr14 srcs, unsigned short* __restrict__ dst) {
    int m = blockIdx.x >> 6;
    int tile = blockIdx.x & 63;
    const float* src = srcs.p[m];
    unsigned short* out = dst + (size_t)m * 65536;
    int kb = (tile >> 3) * 32, nb = (tile & 7) * 32;
    __shared__ float sm[32][33];
    int t = threadIdx.x;
#pragma unroll
    for (int i = 0; i < 4; ++i) {
        int e = t + i * 256; int r = e >> 5, c = e & 31;
        sm[r][c] = src[(kb + r) * 256 + nb + c];
    }
    __syncthreads();
#pragma unroll
    for (int i = 0; i < 4; ++i) {
        int e = t + i * 256; int nr = e >> 5, kc = e & 31;
        out[(size_t)(nb + nr) * 256 + kb + kc] = bf16rne(sm[kc][nr]);
    }
}
__global__ void wtrans_one(const float* __restrict__ src, unsigned short* __restrict__ dst,
                           int K, int N) {
    int tilesN = N >> 5;
    int kb = (blockIdx.x / tilesN) * 32, nb = (blockIdx.x % tilesN) * 32;
    __shared__ float sm[32][33];
    int t = threadIdx.x;
#pragma unroll
    for (int i = 0; i < 4; ++i) {
        int e = t + i * 256; int r = e >> 5, c = e & 31;
        sm[r][c] = src[(kb + r) * N + nb + c];
    }
    __syncthreads();
#pragma unroll
    for (int i = 0; i < 4; ++i) {
        int e = t + i * 256; int nr = e >> 5, kc = e & 31;
        dst[(size_t)(nb + nr) * K + kb + kc] = bf16rne(sm[kc][nr]);
    }
}

// ---------------- bf16 MFMA GEMM ----------------
// flags: 1=relu, 4=degE-mask + leaky
__global__ __launch_bounds__(256)
void gemm_bf16(const unsigned short* __restrict__ A1, const unsigned short* __restrict__ A2,
               const unsigned short* __restrict__ W1, const unsigned short* __restrict__ W2,
               const float* __restrict__ bias, const float* __restrict__ degmask,
               unsigned short* __restrict__ C, int M, int K1, int flags) {
    __shared__ unsigned short As[128][40];
    __shared__ unsigned short Bs[64][40];
    int tid = threadIdx.x;
    int w = tid >> 6, l = tid & 63;
    int wr = w >> 1, wc = w & 1;
    int brow = blockIdx.y * 128, bcol = blockIdx.x * 64;
    int Ktot = K1 + (A2 ? 256 : 0);
    f32x4 acc[4][2] = {};
    for (int k0 = 0; k0 < Ktot; k0 += 32) {
        const unsigned short* Ap; const unsigned short* Wp; int kk, Klen;
        if (k0 < K1) { Ap = A1; Wp = W1; kk = k0; Klen = K1; }
        else         { Ap = A2; Wp = W2; kk = k0 - K1; Klen = 256; }
#pragma unroll
        for (int i = 0; i < 4; ++i) {
            int q = tid + i * 256;
            int r = q >> 3, kb = (q & 7) * 4;
            int gr = brow + r;
            ushort4 u;
            if (gr < M) u = *(const ushort4*)(Ap + (size_t)gr * Klen + kk + kb);
            else { u.x = 0; u.y = 0; u.z = 0; u.w = 0; }
            *(ushort4*)(&As[r][kb]) = u;
        }
#pragma unroll
        for (int i = 0; i < 2; ++i) {
            int q = tid + i * 256;
            int n = q >> 3, kb = (q & 7) * 4;
            *(ushort4*)(&Bs[n][kb]) = *(const ushort4*)(Wp + (size_t)(bcol + n) * Klen + kk + kb);
        }
        __syncthreads();
        bf16x8 af[4], bfr[2];
#pragma unroll
        for (int fr = 0; fr < 4; ++fr)
            af[fr] = *(const bf16x8*)(&As[wr * 64 + fr * 16 + (l & 15)][(l >> 4) * 8]);
#pragma unroll
        for (int fc = 0; fc < 2; ++fc)
            bfr[fc] = *(const bf16x8*)(&Bs[wc * 32 + fc * 16 + (l & 15)][(l >> 4) * 8]);
#pragma unroll
        for (int fr = 0; fr < 4; ++fr)
#pragma unroll
            for (int fc = 0; fc < 2; ++fc)
                acc[fr][fc] = __builtin_amdgcn_mfma_f32_16x16x32_bf16(af[fr], bfr[fc], acc[fr][fc], 0, 0, 0);
        __syncthreads();
    }
#pragma unroll
    for (int fr = 0; fr < 4; ++fr) {
#pragma unroll
        for (int fc = 0; fc < 2; ++fc) {
            int col = bcol + wc * 32 + fc * 16 + (l & 15);
#pragma unroll
            for (int i = 0; i < 4; ++i) {
                int row = brow + wr * 64 + fr * 16 + (l >> 4) * 4 + i;
                if (row >= M) continue;
                float v = acc[fr][fc][i];
                if (bias) v += bias[col];
                if (flags & 1) v = fmaxf(v, 0.f);
                if (flags & 4) { v = (degmask[row] > 0.f) ? v : 0.f; v = leaky02(v); }
                C[(size_t)row * 256 + col] = bf16rne(v);
            }
        }
    }
}

// ---------------- fp32 GEMM (Wcomb build, final W_out) ----------------
__global__ __launch_bounds__(256)
void gemm_f32(const float* __restrict__ A, const float* __restrict__ B,
              const float* __restrict__ bias, float* __restrict__ C,
              int M, int N, int K, int flags) {
    const int BM = 64, BN = 64, BK = 16;
    __shared__ float As[BK][BM + 1];
    __shared__ float Bs[BK][BN + 1];
    int tid = threadIdx.x;
    int tr = tid >> 4, tc = tid & 15;
    int brow = blockIdx.y * BM, bcol = blockIdx.x * BN;
    float acc[4][4] = {{0.f}};
    for (int k0 = 0; k0 < K; k0 += BK) {
#pragma unroll
        for (int i = 0; i < 4; ++i) {
            int e = tid + i * 256;
            int r = e >> 4, c = e & 15;
            int gr = brow + r, gc = k0 + c;
            As[c][r] = (gr < M && gc < K) ? A[(long)gr * K + gc] : 0.f;
        }
#pragma unroll
        for (int i = 0; i < 4; ++i) {
            int e = tid + i * 256;
            int r = e >> 6, c = e & 63;
            int gr = k0 + r, gc = bcol + c;
            Bs[r][c] = (gr < K && gc < N) ? B[(long)gr * N + gc] : 0.f;
        }
        __syncthreads();
#pragma unroll
        for (int k = 0; k < BK; ++k) {
            float ra[4], rb[4];
#pragma unroll
            for (int i = 0; i < 4; ++i) ra[i] = As[k][tr * 4 + i];
#pragma unroll
            for (int j = 0; j < 4; ++j) rb[j] = Bs[k][tc * 4 + j];
#pragma unroll
            for (int i = 0; i < 4; ++i)
#pragma unroll
                for (int j = 0; j < 4; ++j) acc[i][j] += ra[i] * rb[j];
        }
        __syncthreads();
    }
#pragma unroll
    for (int i = 0; i < 4; ++i) {
        int gr = brow + tr * 4 + i;
        if (gr >= M) continue;
#pragma unroll
        for (int j = 0; j < 4; ++j) {
            int gc = bcol + tc * 4 + j;
            if (gc >= N) continue;
            float v = acc[i][j];
            if (bias) v += bias[gc];
            C[(long)gr * N + gc] = v;
        }
    }
}

// ---------------- GAT pre-computation ----------------
__global__ void wg_av(const float* __restrict__ W, const float* __restrict__ as_,
                      const float* __restrict__ ad_, float* __restrict__ asv,
                      float* __restrict__ adv) {
    __shared__ float sm[256];
    int i = blockIdx.x, t = threadIdx.x;
    float w = W[i * HD + t];
    sm[t] = w * as_[t];
    __syncthreads();
    for (int o = 128; o > 0; o >>= 1) { if (t < o) sm[t] += sm[t + o]; __syncthreads(); }
    if (t == 0) asv[i] = sm[0];
    __syncthreads();
    sm[t] = w * ad_[t];
    __syncthreads();
    for (int o = 128; o > 0; o >>= 1) { if (t < o) sm[t] += sm[t + o]; __syncthreads(); }
    if (t == 0) adv[i] = sm[0];
}

__global__ void bias_proj(const float* __restrict__ b, const float* __restrict__ W,
                          float* __restrict__ b2) {
    int j = threadIdx.x;
    float s = 0.f;
    for (int i = 0; i < HD; ++i) s += b[i] * W[i * HD + j];
    b2[j] = s;
}

__global__ void edge_scores_conv(const float* __restrict__ et, const float* __restrict__ asv,
                                 const float* __restrict__ adv, float* __restrict__ es,
                                 float* __restrict__ ed, unsigned short* __restrict__ et_bf) {
    int e = blockIdx.x * 4 + (threadIdx.x >> 6);
    int l = threadIdx.x & 63;
    float x = et[(long)e * FE + l];
    et_bf[(long)e * FE + l] = bf16rne(x);
    float vs = x * asv[l];
    float vd = x * adv[l];
    for (int o = 32; o > 0; o >>= 1) { vs += __shfl_down(vs, o); vd += __shfl_down(vd, o); }
    if (l == 0) { es[e] = vs; ed[e] = vd; }
}

// ---------------- GAT: scalar alpha (thread per segment) ----------------
__global__ void seg_alpha(const int* __restrict__ rowptr, const int* __restrict__ adj,
                          const float* __restrict__ es, const float* __restrict__ ed,
                          float* __restrict__ alphaS, float* __restrict__ alphaL) {
    int d = blockIdx.x * 256 + threadIdx.x;
    if (d >= EE) return;
    int b = rowptr[d], e_ = rowptr[d + 1];
    float edd = ed[d];
    float selfsc = leaky02(es[d] + edd);
    float m = selfsc;
    for (int i = b; i < e_; ++i) m = fmaxf(m, leaky02(es[adj[i]] + edd));
    float s = __expf(selfsc - m);
    for (int i = b; i < e_; ++i) s += __expf(leaky02(es[adj[i]] + edd) - m);
    float inv = 1.f / (s + 1e-16f);
    alphaS[d] = __expf(selfsc - m) * inv;
    for (int i = b; i < e_; ++i) alphaL[i] = __expf(leaky02(es[adj[i]] + edd) - m) * inv;
}

// ---------------- GAT: weighted gather (wave per segment, 4x16-lane quarters) ----------------
__global__ void gat_gather2(const int* __restrict__ rowptr, const int* __restrict__ adj,
                            const float* __restrict__ alphaS, const float* __restrict__ alphaL,
                            const unsigned short* __restrict__ et_bf,
                            unsigned short* __restrict__ agg_et) {
    int d = blockIdx.x * 4 + (threadIdx.x >> 6);
    int lane = threadIdx.x & 63;
    if (d >= EE) return;
    int q = lane >> 4, hl = lane & 15;
    int b = rowptr[d], e_ = rowptr[d + 1];
    int cnt = e_ - b + 1;                      // + self
    const uint2* etu = (const uint2*)et_bf;    // row = 16 x uint2
    float a0 = 0.f, a1 = 0.f, a2 = 0.f, a3 = 0.f;
    for (int j = q; j < cnt; j += 4) {
        int row; float al;
        if (j == 0) { row = d; al = alphaS[d]; }
        else { int i = b + j - 1; row = adj[i]; al = alphaL[i]; }
        uint2 u = etu[(size_t)row * 16 + hl];
        a0 += al * bflo(u.x); a1 += al * bfhi(u.x);
        a2 += al * bflo(u.y); a3 += al * bfhi(u.y);
    }
    a0 += __shfl_xor(a0, 16); a1 += __shfl_xor(a1, 16);
    a2 += __shfl_xor(a2, 16); a3 += __shfl_xor(a3, 16);
    a0 += __shfl_xor(a0, 32); a1 += __shfl_xor(a1, 32);
    a2 += __shfl_xor(a2, 32); a3 += __shfl_xor(a3, 32);
    if (q == 0) {
        uint2 o; o.x = bfpack(a0, a1); o.y = bfpack(a2, a3);
        ((uint2*)agg_et)[(size_t)d * 16 + hl] = o;
    }
}

// ---------------- incidence mean (4 nodes per wave, 16-lane quarters) ----------------
__global__ void etn_gather2(const int* __restrict__ rowptr, const int* __restrict__ adj,
                            const unsigned short* __restrict__ agg_et,
                            unsigned short* __restrict__ agg2, float* __restrict__ degE) {
    int base = (blockIdx.x * 4 + (threadIdx.x >> 6)) * 4;
    int lane = threadIdx.x & 63;
    int q = lane >> 4, hl = lane & 15;
    int n = base + q;
    if (n >= NN) return;
    int b = rowptr[n], e_ = rowptr[n + 1];
    const uint2* au = (const uint2*)agg_et;
    float a0 = 0.f, a1 = 0.f, a2 = 0.f, a3 = 0.f;
    for (int i = b; i < e_; ++i) {
        uint2 u = au[(size_t)adj[i] * 16 + hl];
        a0 += bflo(u.x); a1 += bfhi(u.x); a2 += bflo(u.y); a3 += bfhi(u.y);
    }
    float deg = (float)(e_ - b);
    float inv = 1.f / fmaxf(deg, 1.f);
    uint2 o; o.x = bfpack(a0 * inv, a1 * inv); o.y = bfpack(a2 * inv, a3 * inv);
    ((uint2*)agg2)[(size_t)n * 16 + hl] = o;
    if (hl == 0) degE[n] = deg;
}

// ---------------- SAGE mean (2 nodes per wave, 32-lane halves, uint4 loads) ----------------
__global__ void sage_gather2(const unsigned short* __restrict__ X, const int* __restrict__ rowptr,
                             const int* __restrict__ adjS, unsigned short* __restrict__ mean) {
    int base = (blockIdx.x * 4 + (threadIdx.x >> 6)) * 2;
    int lane = threadIdx.x & 63;
    int half = lane >> 5, hl = lane & 31;
    int n = base + half;
    if (n >= NN) return;
    int b = rowptr[n], e_ = rowptr[n + 1];
    const uint4* Xu = (const uint4*)X;         // row = 32 x uint4
    float a0 = 0.f, a1 = 0.f, a2 = 0.f, a3 = 0.f, a4 = 0.f, a5 = 0.f, a6 = 0.f, a7 = 0.f;
    for (int i = b; i < e_; ++i) {
        uint4 u = Xu[(size_t)adjS[i] * 32 + hl];
        a0 += bflo(u.x); a1 += bfhi(u.x); a2 += bflo(u.y); a3 += bfhi(u.y);
        a4 += bflo(u.z); a5 += bfhi(u.z); a6 += bflo(u.w); a7 += bfhi(u.w);
    }
    float inv = 1.f / fmaxf((float)(e_ - b), 1.f);
    uint4 o;
    o.x = bfpack(a0 * inv, a1 * inv); o.y = bfpack(a2 * inv, a3 * inv);
    o.z = bfpack(a4 * inv, a5 * inv); o.w = bfpack(a6 * inv, a7 * inv);
    ((uint4*)mean)[(size_t)n * 32 + hl] = o;
}

// ---------------- MixAttention: single-pass online softmax (wave/node, 2 edges in flight) ----------------
__global__ void attn_online(const unsigned short* __restrict__ q, const unsigned short* __restrict__ k,
                            const unsigned short* __restrict__ v, const unsigned short* __restrict__ nrep,
                            const int* __restrict__ rowptr, const int* __restrict__ adjS,
                            float* __restrict__ mixed) {
    int n = blockIdx.x * 4 + (threadIdx.x >> 6);
    int lane = threadIdx.x & 63;
    if (n >= NN) return;
    int half = lane >> 5, hl = lane & 31;
    int b = rowptr[n], e_ = rowptr[n + 1];
    const uint4* qu4 = (const uint4*)q;
    const uint4* ku4 = (const uint4*)k;
    const uint4* vu4 = (const uint4*)v;
    const uint4* nu4 = (const uint4*)nrep;
    uint4 nu = nu4[(size_t)n * 32 + hl];
    float nr0 = bflo(nu.x), nr1 = bfhi(nu.x), nr2 = bflo(nu.y), nr3 = bfhi(nu.y);
    float nr4 = bflo(nu.z), nr5 = bfhi(nu.z), nr6 = bflo(nu.w), nr7 = bfhi(nu.w);
    float* mrow = mixed + (size_t)n * HD;
    if (b == e_) {                              // empty segment: mixed = nrep
        if (half == 0) {
            ((float4*)mrow)[2 * hl]     = make_float4(nr0, nr1, nr2, nr3);
            ((float4*)mrow)[2 * hl + 1] = make_float4(nr4, nr5, nr6, nr7);
        }
        return;
    }
    uint4 qv = qu4[(size_t)n * 32 + hl];
    float q0 = bflo(qv.x), q1 = bfhi(qv.x), q2 = bflo(qv.y), q3 = bfhi(qv.y);
    float q4 = bflo(qv.z), q5 = bfhi(qv.z), q6 = bflo(qv.w), q7 = bfhi(qv.w);
    float m = -INFINITY, srun = 0.f;
    float a0 = 0.f, a1 = 0.f, a2 = 0.f, a3 = 0.f, a4 = 0.f, a5 = 0.f, a6 = 0.f, a7 = 0.f;
    for (int i = b + half; i < e_; i += 2) {
        int s = adjS[i];
        uint4 ku = ku4[(size_t)s * 32 + hl];
        float p = q0 * bflo(ku.x) + q1 * bfhi(ku.x) + q2 * bflo(ku.y) + q3 * bfhi(ku.y)
                + q4 * bflo(ku.z) + q5 * bfhi(ku.z) + q6 * bflo(ku.w) + q7 * bfhi(ku.w);
        p += __shfl_xor(p, 1); p += __shfl_xor(p, 2); p += __shfl_xor(p, 4);
        p += __shfl_xor(p, 8); p += __shfl_xor(p, 16);
        p *= 0.0625f;
        uint4 vu = vu4[(size_t)s * 32 + hl];
        float mn = fmaxf(m, p);
        float scale = exp2f((m - mn) * LOG2E);
        float w = exp2f((p - mn) * LOG2E);
        m = mn;
        srun = srun * scale + w;
        a0 = a0 * scale + w * bflo(vu.x); a1 = a1 * scale + w * bfhi(vu.x);
        a2 = a2 * scale + w * bflo(vu.y); a3 = a3 * scale + w * bfhi(vu.y);
        a4 = a4 * scale + w * bflo(vu.z); a5 = a5 * scale + w * bfhi(vu.z);
        a6 = a6 * scale + w * bflo(vu.w); a7 = a7 * scale + w * bfhi(vu.w);
    }
    // merge the two halves (deg>=1 so merged max is finite)
    float mo = __shfl_xor(m, 32);
    float so = __shfl_xor(srun, 32);
    float mn = fmaxf(m, mo);
    float cs = exp2f((m - mn) * LOG2E);
    float co = exp2f((mo - mn) * LOG2E);
    float st = srun * cs + so * co;
    float inv = 1.f / (st + 1e-16f);
    float o0 = (a0 * cs + __shfl_xor(a0, 32) * co) * inv + nr0;
    float o1 = (a1 * cs + __shfl_xor(a1, 32) * co) * inv + nr1;
    float o2 = (a2 * cs + __shfl_xor(a2, 32) * co) * inv + nr2;
    float o3 = (a3 * cs + __shfl_xor(a3, 32) * co) * inv + nr3;
    float o4 = (a4 * cs + __shfl_xor(a4, 32) * co) * inv + nr4;
    float o5 = (a5 * cs + __shfl_xor(a5, 32) * co) * inv + nr5;
    float o6 = (a6 * cs + __shfl_xor(a6, 32) * co) * inv + nr6;
    float o7 = (a7 * cs + __shfl_xor(a7, 32) * co) * inv + nr7;
    if (half == 0) {
        ((float4*)mrow)[2 * hl]     = make_float4(o0, o1, o2, o3);
        ((float4*)mrow)[2 * hl + 1] = make_float4(o4, o5, o6, o7);
    }
}

__global__ void log_softmax_rows(float* __restrict__ out, int nrows) {
    int r = blockIdx.x * 256 + threadIdx.x;
    if (r >= nrows) return;
    float* p = out + (long)r * FOUT;
    float mx = -INFINITY;
    for (int i = 0; i < FOUT; ++i) mx = fmaxf(mx, p[i]);
    float s = 0.f;
    for (int i = 0; i < FOUT; ++i) s += __expf(p[i] - mx);
    float ls = mx + logf(s);
    for (int i = 0; i < FOUT; ++i) p[i] -= ls;
}

// ---------------- host launch ----------------
static void build_scan(const int* cnt, int* rowptr, int* bsum, int n, int total, hipStream_t stream) {
    int nb = (n + 1023) / 1024;
    scan_pass1<<<nb, 256, 0, stream>>>(cnt, bsum, n);
    scan_pass2<<<1, 256, 0, stream>>>(bsum, nb);
    scan_pass3<<<nb, 256, 0, stream>>>(cnt, bsum, rowptr, n);
    set_i32<<<1, 1, 0, stream>>>(rowptr + n, total);
}

extern "C" void kernel_launch(void* const* d_in, const int* in_sizes, int n_in,
                              void* d_out, int out_size, void* d_ws, size_t ws_size,
                              hipStream_t stream) {
    (void)in_sizes; (void)n_in; (void)out_size; (void)ws_size;
    const float* x     = (const float*)d_in[0];
    const float* et    = (const float*)d_in[1];
    const int*   Hm    = (const int*)d_in[2];
    const int*   raw   = (const int*)d_in[3];
    const int*   lg    = (const int*)d_in[4];
    const float* W_gat = (const float*)d_in[5];
    const float* a_src = (const float*)d_in[6];
    const float* a_dst = (const float*)d_in[7];
    const float* b_gat = (const float*)d_in[8];
    const float* W_etn = (const float*)d_in[9];
    const float* W_eg  = (const float*)d_in[10];
    const float* Wr_e1 = (const float*)d_in[11];
    const float* Wn_e1 = (const float*)d_in[12];
    const float* b_e1  = (const float*)d_in[13];
    const float* Wr_e2 = (const float*)d_in[14];
    const float* Wn_e2 = (const float*)d_in[15];
    const float* b_e2  = (const float*)d_in[16];
    const float* Wr_n1 = (const float*)d_in[17];
    const float* Wn_n1 = (const float*)d_in[18];
    const float* b_n1  = (const float*)d_in[19];
    const float* Wr_n2 = (const float*)d_in[20];
    const float* Wn_n2 = (const float*)d_in[21];
    const float* b_n2  = (const float*)d_in[22];
    const float* Wr_n3 = (const float*)d_in[23];
    const float* Wn_n3 = (const float*)d_in[24];
    const float* b_n3  = (const float*)d_in[25];
    const float* Wq    = (const float*)d_in[26];
    const float* Wk    = (const float*)d_in[27];
    const float* Wv    = (const float*)d_in[28];
    const float* W_out = (const float*)d_in[29];

    const int* srcN = raw;
    const int* dstN = raw + EE;
    const int* lgs  = lg;
    const int* lgd  = lg + ELG;

    float* ws = (float*)d_ws;
    size_t off = 0;
    auto alloc = [&](size_t n) { float* p = ws + off; off += (n + 63) & ~(size_t)63; return p; };
    auto allocU = [&](size_t nus) { return (unsigned short*)alloc(nus / 2 + 64); };

    unsigned short* et_bf   = allocU((size_t)EE * FE);
    unsigned short* agg_et  = allocU((size_t)EE * FE);   // reused later as q/k/v
    float* es     = alloc(EE);
    float* ed     = alloc(EE);
    float* alphaS = alloc(EE);
    float* alphaL = alloc(ELG);
    float* Wcomb  = alloc((size_t)FE * HD);
    float* b2     = alloc(HD);
    float* asv    = alloc(FE);
    float* adv    = alloc(FE);
    unsigned short* agg2_bf = allocU((size_t)NN * FE);
    float* degE   = alloc(NN);
    unsigned short* etnL  = allocU((size_t)NN * HD);
    unsigned short* erep  = allocU((size_t)NN * HD);
    unsigned short* meanb = allocU((size_t)NN * HD);
    unsigned short* t1    = allocU((size_t)NN * HD);
    unsigned short* aggr  = allocU((size_t)NN * HD);
    unsigned short* nrep  = allocU((size_t)NN * HD);
    unsigned short* x_bf  = allocU((size_t)NN * HD);
    float* mixed  = alloc((size_t)NN * HD);
    unsigned short* wtb    = allocU((size_t)14 * 65536);
    unsigned short* wcombt = allocU((size_t)HD * FE);
    int* rowptrD  = (int*)alloc(NN + 64);
    int* cursD    = (int*)alloc(NN);
    int* adjS     = (int*)alloc(EE);
    int* rowptrLG = (int*)alloc(EE + 64);
    int* cursLG   = (int*)alloc(EE);
    int* adjLG    = (int*)alloc(ELG);
    int* rowptrH  = (int*)alloc(NN + 64);
    int* cursH    = (int*)alloc(NN);
    int* adjH     = (int*)alloc(2 * EE);
    int* cntbuf   = (int*)alloc(EE);
    int* bsum     = (int*)alloc(1024);
    // aliases (lifetime-checked)
    unsigned short* ta = etnL;                 // etnL dead after erep GEMM
    unsigned short* tb = erep;                 // erep dead after edge layer 1
    unsigned short* qb = agg_et;               // agg_et dead after etn_gather
    unsigned short* kb = agg_et + (size_t)NN * HD;
    unsigned short* vb = agg_et + (size_t)2 * NN * HD;
    float* outp = (float*)d_out;

    unsigned short* W_eg_t  = wtb + 0 * 65536;
    unsigned short* Wr_e1_t = wtb + 1 * 65536;
    unsigned short* Wn_e1_t = wtb + 2 * 65536;
    unsigned short* Wr_e2_t = wtb + 3 * 65536;
    unsigned short* Wn_e2_t = wtb + 4 * 65536;
    unsigned short* Wr_n1_t = wtb + 5 * 65536;
    unsigned short* Wn_n1_t = wtb + 6 * 65536;
    unsigned short* Wr_n2_t = wtb + 7 * 65536;
    unsigned short* Wn_n2_t = wtb + 8 * 65536;
    unsigned short* Wr_n3_t = wtb + 9 * 65536;
    unsigned short* Wn_n3_t = wtb + 10 * 65536;
    unsigned short* Wq_t    = wtb + 11 * 65536;
    unsigned short* Wk_t    = wtb + 12 * 65536;
    unsigned short* Wv_t    = wtb + 13 * 65536;

    dim3 gB(4, (NN + 127) / 128);

    // ======== weight conversion + x conversion ========
    Ptr14 p14;
    p14.p[0] = W_eg;  p14.p[1] = Wr_e1; p14.p[2] = Wn_e1; p14.p[3] = Wr_e2;
    p14.p[4] = Wn_e2; p14.p[5] = Wr_n1; p14.p[6] = Wn_n1; p14.p[7] = Wr_n2;
    p14.p[8] = Wn_n2; p14.p[9] = Wr_n3; p14.p[10] = Wn_n3; p14.p[11] = Wq;
    p14.p[12] = Wk;   p14.p[13] = Wv;
    wtrans14<<<14 * 64, 256, 0, stream>>>(p14, wtb);
    conv_bf16<<<(NN * HD / 2 + 255) / 256, 256, 0, stream>>>(x, (unsigned int*)x_bf, NN * HD / 2);

    // ======== CSR builds ========
    zero_i32<<<(NN + 255) / 256, 256, 0, stream>>>(cntbuf, NN);
    count_i32<<<(EE + 255) / 256, 256, 0, stream>>>(dstN, cntbuf, EE);
    build_scan(cntbuf, rowptrD, bsum, NN, EE, stream);
    copy_i32<<<(NN + 255) / 256, 256, 0, stream>>>(cursD, rowptrD, NN);
    place_pair<<<(EE + 255) / 256, 256, 0, stream>>>(dstN, srcN, cursD, adjS, EE);
    zero_i32<<<(EE + 255) / 256, 256, 0, stream>>>(cntbuf, EE);
    count_i32<<<(ELG + 255) / 256, 256, 0, stream>>>(lgd, cntbuf, ELG);
    build_scan(cntbuf, rowptrLG, bsum, EE, ELG, stream);
    copy_i32<<<(EE + 255) / 256, 256, 0, stream>>>(cursLG, rowptrLG, EE);
    place_pair<<<(ELG + 255) / 256, 256, 0, stream>>>(lgd, lgs, cursLG, adjLG, ELG);
    zero_i32<<<(NN + 255) / 256, 256, 0, stream>>>(cntbuf, NN);
    count_h<<<(2 * EE + 255) / 256, 256, 0, stream>>>(Hm, cntbuf);
    build_scan(cntbuf, rowptrH, bsum, NN, 2 * EE, stream);
    copy_i32<<<(NN + 255) / 256, 256, 0, stream>>>(cursH, rowptrH, NN);
    place_h<<<(2 * EE + 255) / 256, 256, 0, stream>>>(Hm, cursH, adjH);

    // ======== GAT (folded Wcomb = W_gat@W_etn) ========
    gemm_f32<<<dim3(4, 1), 256, 0, stream>>>(W_gat, W_etn, nullptr, Wcomb, FE, HD, HD, 0);
    wtrans_one<<<(FE / 32) * (HD / 32), 256, 0, stream>>>(Wcomb, wcombt, FE, HD);
    bias_proj<<<1, 256, 0, stream>>>(b_gat, W_etn, b2);
    wg_av<<<FE, 256, 0, stream>>>(W_gat, a_src, a_dst, asv, adv);
    edge_scores_conv<<<EE / 4, 256, 0, stream>>>(et, asv, adv, es, ed, et_bf);
    seg_alpha<<<(EE + 255) / 256, 256, 0, stream>>>(rowptrLG, adjLG, es, ed, alphaS, alphaL);
    gat_gather2<<<(EE + 3) / 4, 256, 0, stream>>>(rowptrLG, adjLG, alphaS, alphaL, et_bf, agg_et);

    // ======== EdgeToNode incidence mean + GEMMs ========
    etn_gather2<<<(NN + 15) / 16, 256, 0, stream>>>(rowptrH, adjH, agg_et, agg2_bf, degE);
    gemm_bf16<<<gB, 256, 0, stream>>>(agg2_bf, nullptr, wcombt, nullptr, b2, degE, etnL, NN, FE, 4);
    gemm_bf16<<<gB, 256, 0, stream>>>(etnL, nullptr, W_eg_t, nullptr, nullptr, nullptr, erep, NN, HD, 0);

    // ======== edge_aggr SAGE (2 layers, dual-K fused) ========
    sage_gather2<<<(NN + 7) / 8, 256, 0, stream>>>(erep, rowptrD, adjS, meanb);
    gemm_bf16<<<gB, 256, 0, stream>>>(erep, meanb, Wr_e1_t, Wn_e1_t, b_e1, nullptr, t1, NN, HD, 1);
    sage_gather2<<<(NN + 7) / 8, 256, 0, stream>>>(t1, rowptrD, adjS, meanb);
    gemm_bf16<<<gB, 256, 0, stream>>>(t1, meanb, Wr_e2_t, Wn_e2_t, b_e2, nullptr, aggr, NN, HD, 0);

    // ======== attr_node SAGE (3 layers, dual-K fused) ========
    sage_gather2<<<(NN + 7) / 8, 256, 0, stream>>>(x_bf, rowptrD, adjS, meanb);
    gemm_bf16<<<gB, 256, 0, stream>>>(x_bf, meanb, Wr_n1_t, Wn_n1_t, b_n1, nullptr, ta, NN, HD, 1);
    sage_gather2<<<(NN + 7) / 8, 256, 0, stream>>>(ta, rowptrD, adjS, meanb);
    gemm_bf16<<<gB, 256, 0, stream>>>(ta, meanb, Wr_n2_t, Wn_n2_t, b_n2, nullptr, tb, NN, HD, 1);
    sage_gather2<<<(NN + 7) / 8, 256, 0, stream>>>(tb, rowptrD, adjS, meanb);
    gemm_bf16<<<gB, 256, 0, stream>>>(tb, meanb, Wr_n3_t, Wn_n3_t, b_n3, nullptr, nrep, NN, HD, 0);

    // ======== MixAttention ========
    gemm_bf16<<<gB, 256, 0, stream>>>(nrep, nullptr, Wq_t, nullptr, nullptr, nullptr, qb, NN, HD, 0);
    gemm_bf16<<<gB, 256, 0, stream>>>(aggr, nullptr, Wk_t, nullptr, nullptr, nullptr, kb, NN, HD, 0);
    gemm_bf16<<<gB, 256, 0, stream>>>(aggr, nullptr, Wv_t, nullptr, nullptr, nullptr, vb, NN, HD, 0);
    attn_online<<<(NN + 3) / 4, 256, 0, stream>>>(qb, kb, vb, nrep, rowptrD, adjS, mixed);

    // ======== final linear + log_softmax ========
    gemm_f32<<<dim3(1, (NN + 63) / 64), 256, 0, stream>>>(mixed, W_out, nullptr, outp, NN, FOUT, HD, 0);
    log_softmax_rows<<<(NN + 255) / 256, 256, 0, stream>>>(outp, NN);
}

// Round 7
// 883.810 us; speedup vs baseline: 4.0826x; 1.1065x over previous
//
#include <hip/hip_runtime.h>
#include <math.h>

#define NN   20000
#define EE   320000
#define ELG  600000
#define FE   64
#define HD   256
#define FOUT 40
#define LOG2E 1.44269504f
#define NTOTC (NN + EE + NN)            // concatenated count-buffer size
#define NIDX  (EE + ELG + 2 * EE)       // concatenated index-stream size

typedef __attribute__((ext_vector_type(8))) short bf16x8;
typedef __attribute__((ext_vector_type(4))) float f32x4;

__device__ __forceinline__ float leaky02(float x) { return x > 0.f ? x : 0.2f * x; }

__device__ __forceinline__ unsigned short bf16rne(float f) {
    unsigned int u = __float_as_uint(f);
    u = (u + 0x7FFFu + ((u >> 16) & 1u)) >> 16;
    return (unsigned short)u;
}
__device__ __forceinline__ float bflo(unsigned int u) { return __uint_as_float(u << 16); }
__device__ __forceinline__ float bfhi(unsigned int u) { return __uint_as_float(u & 0xffff0000u); }
__device__ __forceinline__ unsigned int bfpack(float a, float b) {
    return (unsigned int)bf16rne(a) | ((unsigned int)bf16rne(b) << 16);
}

// ---------------- small utility kernels ----------------
__global__ void zero_i32(int* __restrict__ p, int n) {
    int i = blockIdx.x * 256 + threadIdx.x;
    if (i < n) p[i] = 0;
}
__global__ void conv_bf16(const float* __restrict__ in, unsigned int* __restrict__ out, int n2) {
    int i = blockIdx.x * 256 + threadIdx.x;
    if (i < n2) { float2 v = ((const float2*)in)[i]; out[i] = bfpack(v.x, v.y); }
}

// ---------------- consolidated CSR build ----------------
// cntAll sections: [0,NN) = raw-by-dst, [NN,NN+EE) = lg-by-lgd, [NN+EE,NN+EE+NN) = incidence H
__global__ void count_all(const int* __restrict__ dstN, const int* __restrict__ lgd,
                          const int* __restrict__ Hm, int* __restrict__ cntAll) {
    int i = blockIdx.x * 256 + threadIdx.x;
    if (i >= NIDX) return;
    if (i < EE) atomicAdd(&cntAll[dstN[i]], 1);
    else if (i < EE + ELG) atomicAdd(&cntAll[NN + lgd[i - EE]], 1);
    else atomicAdd(&cntAll[NN + EE + Hm[i - EE - ELG]], 1);
}

__global__ void scan_pass1(const int* __restrict__ in, int* __restrict__ bsum, int n) {
    __shared__ int sm[256];
    int base = blockIdx.x * 1024, t = threadIdx.x;
    int s = 0;
#pragma unroll
    for (int j = 0; j < 4; ++j) { int i = base + t * 4 + j; s += (i < n) ? in[i] : 0; }
    sm[t] = s; __syncthreads();
    for (int o = 128; o > 0; o >>= 1) { if (t < o) sm[t] += sm[t + o]; __syncthreads(); }
    if (t == 0) bsum[blockIdx.x] = sm[0];
}
__global__ void scan_pass2(int* __restrict__ bsum, int nb) {
    __shared__ int sm[1024];
    int t = threadIdx.x;
    for (int i = t; i < nb; i += 256) sm[i] = bsum[i];
    __syncthreads();
    if (t == 0) { int run = 0; for (int i = 0; i < nb; ++i) { int v = sm[i]; sm[i] = run; run += v; } }
    __syncthreads();
    for (int i = t; i < nb; i += 256) bsum[i] = sm[i];
}
__global__ void scan_pass3(const int* __restrict__ in, const int* __restrict__ boff,
                           int* __restrict__ out, int n) {
    __shared__ int tsum[256];
    int base = blockIdx.x * 1024, t = threadIdx.x;
    int v[4];
#pragma unroll
    for (int j = 0; j < 4; ++j) { int i = base + t * 4 + j; v[j] = (i < n) ? in[i] : 0; }
    int loc = v[0] + v[1] + v[2] + v[3];
    tsum[t] = loc; __syncthreads();
    for (int o = 1; o < 256; o <<= 1) {
        int x = (t >= o) ? tsum[t - o] : 0;
        __syncthreads();
        tsum[t] += x;
        __syncthreads();
    }
    int off = boff[blockIdx.x] + (tsum[t] - loc);
    int run = 0;
#pragma unroll
    for (int j = 0; j < 4; ++j) { int i = base + t * 4 + j; if (i < n) out[i] = off + run; run += v[j]; }
}

// section-rebased rowptr + cursor init (one pass)
__global__ void rebase_all(const int* __restrict__ scanAll,
                           int* __restrict__ rowptrD, int* __restrict__ cursD,
                           int* __restrict__ rowptrLG, int* __restrict__ cursLG,
                           int* __restrict__ rowptrH, int* __restrict__ cursH) {
    int i = blockIdx.x * 256 + threadIdx.x;
    if (i == 0) { rowptrD[NN] = EE; rowptrLG[EE] = ELG; rowptrH[NN] = 2 * EE; }
    if (i >= NTOTC) return;
    if (i < NN) { int v = scanAll[i]; rowptrD[i] = v; cursD[i] = v; }
    else if (i < NN + EE) { int v = scanAll[i] - EE; rowptrLG[i - NN] = v; cursLG[i - NN] = v; }
    else { int v = scanAll[i] - (EE + ELG); rowptrH[i - NN - EE] = v; cursH[i - NN - EE] = v; }
}

__global__ void place_all(const int* __restrict__ srcN, const int* __restrict__ dstN,
                          const int* __restrict__ lgs, const int* __restrict__ lgd,
                          const int* __restrict__ Hm,
                          int* __restrict__ cursD, int* __restrict__ cursLG, int* __restrict__ cursH,
                          int* __restrict__ adjS, int* __restrict__ adjLG, int* __restrict__ adjH) {
    int i = blockIdx.x * 256 + threadIdx.x;
    if (i >= NIDX) return;
    if (i < EE) {
        int pos = atomicAdd(&cursD[dstN[i]], 1);
        adjS[pos] = srcN[i];
    } else if (i < EE + ELG) {
        int j = i - EE;
        int pos = atomicAdd(&cursLG[lgd[j]], 1);
        adjLG[pos] = lgs[j];
    } else {
        int j = i - EE - ELG;
        int pos = atomicAdd(&cursH[Hm[j]], 1);
        adjH[pos] = (j < EE) ? j : j - EE;
    }
}

// ---------------- weight transpose+convert ----------------
struct Ptr14 { const float* p[14]; };
__global__ void wtrans14(Ptr14 srcs, unsigned short* __restrict__ dst) {
    int m = blockIdx.x >> 6;
    int tile = blockIdx.x & 63;
    const float* src = srcs.p[m];
    unsigned short* out = dst + (size_t)m * 65536;
    int kb = (tile >> 3) * 32, nb = (tile & 7) * 32;
    __shared__ float sm[32][33];
    int t = threadIdx.x;
#pragma unroll
    for (int i = 0; i < 4; ++i) {
        int e = t + i * 256; int r = e >> 5, c = e & 31;
        sm[r][c] = src[(kb + r) * 256 + nb + c];
    }
    __syncthreads();
#pragma unroll
    for (int i = 0; i < 4; ++i) {
        int e = t + i * 256; int nr = e >> 5, kc = e & 31;
        out[(size_t)(nb + nr) * 256 + kb + kc] = bf16rne(sm[kc][nr]);
    }
}
__global__ void wtrans_one(const float* __restrict__ src, unsigned short* __restrict__ dst,
                           int K, int N) {
    int tilesN = N >> 5;
    int kb = (blockIdx.x / tilesN) * 32, nb = (blockIdx.x % tilesN) * 32;
    __shared__ float sm[32][33];
    int t = threadIdx.x;
#pragma unroll
    for (int i = 0; i < 4; ++i) {
        int e = t + i * 256; int r = e >> 5, c = e & 31;
        sm[r][c] = src[(kb + r) * N + nb + c];
    }
    __syncthreads();
#pragma unroll
    for (int i = 0; i < 4; ++i) {
        int e = t + i * 256; int nr = e >> 5, kc = e & 31;
        dst[(size_t)(nb + nr) * K + kb + kc] = bf16rne(sm[kc][nr]);
    }
}

// ---------------- bf16 MFMA GEMM ----------------
// flags: 1=relu, 4=degE-mask + leaky
__global__ __launch_bounds__(256)
void gemm_bf16(const unsigned short* __restrict__ A1, const unsigned short* __restrict__ A2,
               const unsigned short* __restrict__ W1, const unsigned short* __restrict__ W2,
               const float* __restrict__ bias, const float* __restrict__ degmask,
               unsigned short* __restrict__ C, int M, int K1, int flags) {
    __shared__ unsigned short As[128][40];
    __shared__ unsigned short Bs[64][40];
    int tid = threadIdx.x;
    int w = tid >> 6, l = tid & 63;
    int wr = w >> 1, wc = w & 1;
    int brow = blockIdx.y * 128, bcol = blockIdx.x * 64;
    int Ktot = K1 + (A2 ? 256 : 0);
    f32x4 acc[4][2] = {};
    for (int k0 = 0; k0 < Ktot; k0 += 32) {
        const unsigned short* Ap; const unsigned short* Wp; int kk, Klen;
        if (k0 < K1) { Ap = A1; Wp = W1; kk = k0; Klen = K1; }
        else         { Ap = A2; Wp = W2; kk = k0 - K1; Klen = 256; }
#pragma unroll
        for (int i = 0; i < 4; ++i) {
            int q = tid + i * 256;
            int r = q >> 3, kb = (q & 7) * 4;
            int gr = brow + r;
            ushort4 u;
            if (gr < M) u = *(const ushort4*)(Ap + (size_t)gr * Klen + kk + kb);
            else { u.x = 0; u.y = 0; u.z = 0; u.w = 0; }
            *(ushort4*)(&As[r][kb]) = u;
        }
#pragma unroll
        for (int i = 0; i < 2; ++i) {
            int q = tid + i * 256;
            int n = q >> 3, kb = (q & 7) * 4;
            *(ushort4*)(&Bs[n][kb]) = *(const ushort4*)(Wp + (size_t)(bcol + n) * Klen + kk + kb);
        }
        __syncthreads();
        bf16x8 af[4], bfr[2];
#pragma unroll
        for (int fr = 0; fr < 4; ++fr)
            af[fr] = *(const bf16x8*)(&As[wr * 64 + fr * 16 + (l & 15)][(l >> 4) * 8]);
#pragma unroll
        for (int fc = 0; fc < 2; ++fc)
            bfr[fc] = *(const bf16x8*)(&Bs[wc * 32 + fc * 16 + (l & 15)][(l >> 4) * 8]);
#pragma unroll
        for (int fr = 0; fr < 4; ++fr)
#pragma unroll
            for (int fc = 0; fc < 2; ++fc)
                acc[fr][fc] = __builtin_amdgcn_mfma_f32_16x16x32_bf16(af[fr], bfr[fc], acc[fr][fc], 0, 0, 0);
        __syncthreads();
    }
#pragma unroll
    for (int fr = 0; fr < 4; ++fr) {
#pragma unroll
        for (int fc = 0; fc < 2; ++fc) {
            int col = bcol + wc * 32 + fc * 16 + (l & 15);
#pragma unroll
            for (int i = 0; i < 4; ++i) {
                int row = brow + wr * 64 + fr * 16 + (l >> 4) * 4 + i;
                if (row >= M) continue;
                float v = acc[fr][fc][i];
                if (bias) v += bias[col];
                if (flags & 1) v = fmaxf(v, 0.f);
                if (flags & 4) { v = (degmask[row] > 0.f) ? v : 0.f; v = leaky02(v); }
                C[(size_t)row * 256 + col] = bf16rne(v);
            }
        }
    }
}

// three single-K GEMMs in one launch: blocks [0,4)->(A0,W0,C0), [4,8)->(A1,W1,C1), [8,12)->(A2,W2,C2)
__global__ __launch_bounds__(256)
void gemm_bf16_tri(const unsigned short* __restrict__ A0, const unsigned short* __restrict__ W0,
                   unsigned short* __restrict__ C0,
                   const unsigned short* __restrict__ A1, const unsigned short* __restrict__ W1,
                   unsigned short* __restrict__ C1,
                   const unsigned short* __restrict__ A2, const unsigned short* __restrict__ W2,
                   unsigned short* __restrict__ C2, int M) {
    __shared__ unsigned short As[128][40];
    __shared__ unsigned short Bs[64][40];
    int sel = blockIdx.x >> 2;
    const unsigned short* A = (sel == 0) ? A0 : (sel == 1) ? A1 : A2;
    const unsigned short* W = (sel == 0) ? W0 : (sel == 1) ? W1 : W2;
    unsigned short* C = (sel == 0) ? C0 : (sel == 1) ? C1 : C2;
    int tid = threadIdx.x;
    int w = tid >> 6, l = tid & 63;
    int wr = w >> 1, wc = w & 1;
    int brow = blockIdx.y * 128, bcol = (blockIdx.x & 3) * 64;
    f32x4 acc[4][2] = {};
    for (int k0 = 0; k0 < 256; k0 += 32) {
#pragma unroll
        for (int i = 0; i < 4; ++i) {
            int q = tid + i * 256;
            int r = q >> 3, kb = (q & 7) * 4;
            int gr = brow + r;
            ushort4 u;
            if (gr < M) u = *(const ushort4*)(A + (size_t)gr * 256 + k0 + kb);
            else { u.x = 0; u.y = 0; u.z = 0; u.w = 0; }
            *(ushort4*)(&As[r][kb]) = u;
        }
#pragma unroll
        for (int i = 0; i < 2; ++i) {
            int q = tid + i * 256;
            int n = q >> 3, kb = (q & 7) * 4;
            *(ushort4*)(&Bs[n][kb]) = *(const ushort4*)(W + (size_t)(bcol + n) * 256 + k0 + kb);
        }
        __syncthreads();
        bf16x8 af[4], bfr[2];
#pragma unroll
        for (int fr = 0; fr < 4; ++fr)
            af[fr] = *(const bf16x8*)(&As[wr * 64 + fr * 16 + (l & 15)][(l >> 4) * 8]);
#pragma unroll
        for (int fc = 0; fc < 2; ++fc)
            bfr[fc] = *(const bf16x8*)(&Bs[wc * 32 + fc * 16 + (l & 15)][(l >> 4) * 8]);
#pragma unroll
        for (int fr = 0; fr < 4; ++fr)
#pragma unroll
            for (int fc = 0; fc < 2; ++fc)
                acc[fr][fc] = __builtin_amdgcn_mfma_f32_16x16x32_bf16(af[fr], bfr[fc], acc[fr][fc], 0, 0, 0);
        __syncthreads();
    }
#pragma unroll
    for (int fr = 0; fr < 4; ++fr) {
#pragma unroll
        for (int fc = 0; fc < 2; ++fc) {
            int col = bcol + wc * 32 + fc * 16 + (l & 15);
#pragma unroll
            for (int i = 0; i < 4; ++i) {
                int row = brow + wr * 64 + fr * 16 + (l >> 4) * 4 + i;
                if (row >= M) continue;
                C[(size_t)row * 256 + col] = bf16rne(acc[fr][fc][i]);
            }
        }
    }
}

// ---------------- fp32 GEMM (Wcomb build only) ----------------
__global__ __launch_bounds__(256)
void gemm_f32(const float* __restrict__ A, const float* __restrict__ B,
              float* __restrict__ C, int M, int N, int K) {
    const int BM = 64, BN = 64, BK = 16;
    __shared__ float As[BK][BM + 1];
    __shared__ float Bs[BK][BN + 1];
    int tid = threadIdx.x;
    int tr = tid >> 4, tc = tid & 15;
    int brow = blockIdx.y * BM, bcol = blockIdx.x * BN;
    float acc[4][4] = {{0.f}};
    for (int k0 = 0; k0 < K; k0 += BK) {
#pragma unroll
        for (int i = 0; i < 4; ++i) {
            int e = tid + i * 256;
            int r = e >> 4, c = e & 15;
            int gr = brow + r, gc = k0 + c;
            As[c][r] = (gr < M && gc < K) ? A[(long)gr * K + gc] : 0.f;
        }
#pragma unroll
        for (int i = 0; i < 4; ++i) {
            int e = tid + i * 256;
            int r = e >> 6, c = e & 63;
            int gr = k0 + r, gc = bcol + c;
            Bs[r][c] = (gr < K && gc < N) ? B[(long)gr * N + gc] : 0.f;
        }
        __syncthreads();
#pragma unroll
        for (int k = 0; k < BK; ++k) {
            float ra[4], rb[4];
#pragma unroll
            for (int i = 0; i < 4; ++i) ra[i] = As[k][tr * 4 + i];
#pragma unroll
            for (int j = 0; j < 4; ++j) rb[j] = Bs[k][tc * 4 + j];
#pragma unroll
            for (int i = 0; i < 4; ++i)
#pragma unroll
                for (int j = 0; j < 4; ++j) acc[i][j] += ra[i] * rb[j];
        }
        __syncthreads();
    }
#pragma unroll
    for (int i = 0; i < 4; ++i) {
        int gr = brow + tr * 4 + i;
        if (gr >= M) continue;
#pragma unroll
        for (int j = 0; j < 4; ++j) {
            int gc = bcol + tc * 4 + j;
            if (gc < N) C[(long)gr * N + gc] = acc[i][j];
        }
    }
}

// ---------------- final linear + log_softmax fused ----------------
// A = mixed [M][256] f32, B = W_out [256][40] f32, out [M][40]
__global__ __launch_bounds__(256)
void gemm_out_lsm(const float* __restrict__ A, const float* __restrict__ B,
                  float* __restrict__ out, int M) {
    const int BK = 16;
    __shared__ float As[BK][65];
    __shared__ float Bs[BK][65];
    __shared__ float tile[64][41];
    __shared__ float lsb[64];
    int tid = threadIdx.x;
    int tr = tid >> 4, tc = tid & 15;
    int brow = blockIdx.y * 64;
    float acc[4][4] = {{0.f}};
    for (int k0 = 0; k0 < 256; k0 += BK) {
#pragma unroll
        for (int i = 0; i < 4; ++i) {
            int e = tid + i * 256;
            int r = e >> 4, c = e & 15;
            int gr = brow + r;
            As[c][r] = (gr < M) ? A[(long)gr * 256 + k0 + c] : 0.f;
        }
#pragma unroll
        for (int i = 0; i < 4; ++i) {
            int e = tid + i * 256;
            int r = e >> 6, c = e & 63;
            Bs[r][c] = (c < FOUT) ? B[(long)(k0 + r) * FOUT + c] : 0.f;
        }
        __syncthreads();
#pragma unroll
        for (int k = 0; k < BK; ++k) {
            float ra[4], rb[4];
#pragma unroll
            for (int i = 0; i < 4; ++i) ra[i] = As[k][tr * 4 + i];
#pragma unroll
            for (int j = 0; j < 4; ++j) rb[j] = Bs[k][tc * 4 + j];
#pragma unroll
            for (int i = 0; i < 4; ++i)
#pragma unroll
                for (int j = 0; j < 4; ++j) acc[i][j] += ra[i] * rb[j];
        }
        __syncthreads();
    }
#pragma unroll
    for (int i = 0; i < 4; ++i)
#pragma unroll
        for (int j = 0; j < 4; ++j) {
            int gc = tc * 4 + j;
            if (gc < FOUT) tile[tr * 4 + i][gc] = acc[i][j];
        }
    __syncthreads();
    if (tid < 64) {
        int gr = brow + tid;
        float mx = -INFINITY;
        if (gr < M) {
            for (int c = 0; c < FOUT; ++c) mx = fmaxf(mx, tile[tid][c]);
            float s = 0.f;
            for (int c = 0; c < FOUT; ++c) s += __expf(tile[tid][c] - mx);
            lsb[tid] = mx + logf(s);
        }
    }
    __syncthreads();
#pragma unroll
    for (int i = 0; i < 4; ++i) {
        int r = tr * 4 + i;
        int gr = brow + r;
        if (gr >= M) continue;
#pragma unroll
        for (int j = 0; j < 4; ++j) {
            int gc = tc * 4 + j;
            if (gc < FOUT) out[(long)gr * FOUT + gc] = tile[r][gc] - lsb[r];
        }
    }
}

// ---------------- GAT pre-computation (wg_av + bias_proj fused) ----------------
__global__ void gat_prep(const float* __restrict__ W, const float* __restrict__ as_,
                         const float* __restrict__ ad_, const float* __restrict__ b_gat,
                         const float* __restrict__ W_etn,
                         float* __restrict__ asv, float* __restrict__ adv, float* __restrict__ b2) {
    int t = threadIdx.x;
    if (blockIdx.x == FE) {                    // bias_proj: b2 = b_gat @ W_etn
        float s = 0.f;
        for (int i = 0; i < HD; ++i) s += b_gat[i] * W_etn[i * HD + t];
        b2[t] = s;
        return;
    }
    __shared__ float sm[256];
    int i = blockIdx.x;
    float w = W[i * HD + t];
    sm[t] = w * as_[t];
    __syncthreads();
    for (int o = 128; o > 0; o >>= 1) { if (t < o) sm[t] += sm[t + o]; __syncthreads(); }
    if (t == 0) asv[i] = sm[0];
    __syncthreads();
    sm[t] = w * ad_[t];
    __syncthreads();
    for (int o = 128; o > 0; o >>= 1) { if (t < o) sm[t] += sm[t + o]; __syncthreads(); }
    if (t == 0) adv[i] = sm[0];
}

__global__ void edge_scores_conv(const float* __restrict__ et, const float* __restrict__ asv,
                                 const float* __restrict__ adv, float* __restrict__ es,
                                 float* __restrict__ ed, unsigned short* __restrict__ et_bf) {
    int e = blockIdx.x * 4 + (threadIdx.x >> 6);
    int l = threadIdx.x & 63;
    float x = et[(long)e * FE + l];
    et_bf[(long)e * FE + l] = bf16rne(x);
    float vs = x * asv[l];
    float vd = x * adv[l];
    for (int o = 32; o > 0; o >>= 1) { vs += __shfl_down(vs, o); vd += __shfl_down(vd, o); }
    if (l == 0) { es[e] = vs; ed[e] = vd; }
}

// ---------------- GAT: scalar alpha (thread per segment) ----------------
__global__ void seg_alpha(const int* __restrict__ rowptr, const int* __restrict__ adj,
                          const float* __restrict__ es, const float* __restrict__ ed,
                          float* __restrict__ alphaS, float* __restrict__ alphaL) {
    int d = blockIdx.x * 256 + threadIdx.x;
    if (d >= EE) return;
    int b = rowptr[d], e_ = rowptr[d + 1];
    float edd = ed[d];
    float selfsc = leaky02(es[d] + edd);
    float m = selfsc;
    for (int i = b; i < e_; ++i) m = fmaxf(m, leaky02(es[adj[i]] + edd));
    float s = __expf(selfsc - m);
    for (int i = b; i < e_; ++i) s += __expf(leaky02(es[adj[i]] + edd) - m);
    float inv = 1.f / (s + 1e-16f);
    alphaS[d] = __expf(selfsc - m) * inv;
    for (int i = b; i < e_; ++i) alphaL[i] = __expf(leaky02(es[adj[i]] + edd) - m) * inv;
}

// ---------------- GAT: weighted gather (8-lane group per segment, no shuffles) ----------------
__global__ void gat_gather3(const int* __restrict__ rowptr, const int* __restrict__ adj,
                            const float* __restrict__ alphaS, const float* __restrict__ alphaL,
                            const unsigned short* __restrict__ et_bf,
                            unsigned short* __restrict__ agg_et) {
    int d = blockIdx.x * 32 + (threadIdx.x >> 3);
    int hl = threadIdx.x & 7;                  // row = 8 x uint4 (64 bf16)
    if (d >= EE) return;
    int b = rowptr[d], e_ = rowptr[d + 1];
    const uint4* etu = (const uint4*)et_bf;
    float al = alphaS[d];
    uint4 u = etu[(size_t)d * 8 + hl];
    float a0 = al * bflo(u.x), a1 = al * bfhi(u.x), a2 = al * bflo(u.y), a3 = al * bfhi(u.y);
    float a4 = al * bflo(u.z), a5 = al * bfhi(u.z), a6 = al * bflo(u.w), a7 = al * bfhi(u.w);
    for (int i = b; i < e_; ++i) {
        al = alphaL[i];
        u = etu[(size_t)adj[i] * 8 + hl];
        a0 += al * bflo(u.x); a1 += al * bfhi(u.x); a2 += al * bflo(u.y); a3 += al * bfhi(u.y);
        a4 += al * bflo(u.z); a5 += al * bfhi(u.z); a6 += al * bflo(u.w); a7 += al * bfhi(u.w);
    }
    uint4 o;
    o.x = bfpack(a0, a1); o.y = bfpack(a2, a3); o.z = bfpack(a4, a5); o.w = bfpack(a6, a7);
    ((uint4*)agg_et)[(size_t)d * 8 + hl] = o;
}

// ---------------- incidence mean (4 nodes per wave, 16-lane quarters) ----------------
__global__ void etn_gather2(const int* __restrict__ rowptr, const int* __restrict__ adj,
                            const unsigned short* __restrict__ agg_et,
                            unsigned short* __restrict__ agg2, float* __restrict__ degE) {
    int base = (blockIdx.x * 4 + (threadIdx.x >> 6)) * 4;
    int lane = threadIdx.x & 63;
    int q = lane >> 4, hl = lane & 15;
    int n = base + q;
    if (n >= NN) return;
    int b = rowptr[n], e_ = rowptr[n + 1];
    const uint2* au = (const uint2*)agg_et;
    float a0 = 0.f, a1 = 0.f, a2 = 0.f, a3 = 0.f;
    for (int i = b; i < e_; ++i) {
        uint2 u = au[(size_t)adj[i] * 16 + hl];
        a0 += bflo(u.x); a1 += bfhi(u.x); a2 += bflo(u.y); a3 += bfhi(u.y);
    }
    float deg = (float)(e_ - b);
    float inv = 1.f / fmaxf(deg, 1.f);
    uint2 o; o.x = bfpack(a0 * inv, a1 * inv); o.y = bfpack(a2 * inv, a3 * inv);
    ((uint2*)agg2)[(size_t)n * 16 + hl] = o;
    if (hl == 0) degE[n] = deg;
}

// ---------------- SAGE mean (2 nodes per wave, 32-lane halves, uint4 loads) ----------------
__global__ void sage_gather2(const unsigned short* __restrict__ X, const int* __restrict__ rowptr,
                             const int* __restrict__ adjS, unsigned short* __restrict__ mean) {
    int base = (blockIdx.x * 4 + (threadIdx.x >> 6)) * 2;
    int lane = threadIdx.x & 63;
    int half = lane >> 5, hl = lane & 31;
    int n = base + half;
    if (n >= NN) return;
    int b = rowptr[n], e_ = rowptr[n + 1];
    const uint4* Xu = (const uint4*)X;
    float a0 = 0.f, a1 = 0.f, a2 = 0.f, a3 = 0.f, a4 = 0.f, a5 = 0.f, a6 = 0.f, a7 = 0.f;
    for (int i = b; i < e_; ++i) {
        uint4 u = Xu[(size_t)adjS[i] * 32 + hl];
        a0 += bflo(u.x); a1 += bfhi(u.x); a2 += bflo(u.y); a3 += bfhi(u.y);
        a4 += bflo(u.z); a5 += bfhi(u.z); a6 += bflo(u.w); a7 += bfhi(u.w);
    }
    float inv = 1.f / fmaxf((float)(e_ - b), 1.f);
    uint4 o;
    o.x = bfpack(a0 * inv, a1 * inv); o.y = bfpack(a2 * inv, a3 * inv);
    o.z = bfpack(a4 * inv, a5 * inv); o.w = bfpack(a6 * inv, a7 * inv);
    ((uint4*)mean)[(size_t)n * 32 + hl] = o;
}

// ---------------- MixAttention: single-pass online softmax ----------------
__global__ void attn_online(const unsigned short* __restrict__ q, const unsigned short* __restrict__ k,
                            const unsigned short* __restrict__ v, const unsigned short* __restrict__ nrep,
                            const int* __restrict__ rowptr, const int* __restrict__ adjS,
                            float* __restrict__ mixed) {
    int n = blockIdx.x * 4 + (threadIdx.x >> 6);
    int lane = threadIdx.x & 63;
    if (n >= NN) return;
    int half = lane >> 5, hl = lane & 31;
    int b = rowptr[n], e_ = rowptr[n + 1];
    const uint4* qu4 = (const uint4*)q;
    const uint4* ku4 = (const uint4*)k;
    const uint4* vu4 = (const uint4*)v;
    const uint4* nu4 = (const uint4*)nrep;
    uint4 nu = nu4[(size_t)n * 32 + hl];
    float nr0 = bflo(nu.x), nr1 = bfhi(nu.x), nr2 = bflo(nu.y), nr3 = bfhi(nu.y);
    float nr4 = bflo(nu.z), nr5 = bfhi(nu.z), nr6 = bflo(nu.w), nr7 = bfhi(nu.w);
    float* mrow = mixed + (size_t)n * HD;
    if (b == e_) {
        if (half == 0) {
            ((float4*)mrow)[2 * hl]     = make_float4(nr0, nr1, nr2, nr3);
            ((float4*)mrow)[2 * hl + 1] = make_float4(nr4, nr5, nr6, nr7);
        }
        return;
    }
    uint4 qv = qu4[(size_t)n * 32 + hl];
    float q0 = bflo(qv.x), q1 = bfhi(qv.x), q2 = bflo(qv.y), q3 = bfhi(qv.y);
    float q4 = bflo(qv.z), q5 = bfhi(qv.z), q6 = bflo(qv.w), q7 = bfhi(qv.w);
    float m = -INFINITY, srun = 0.f;
    float a0 = 0.f, a1 = 0.f, a2 = 0.f, a3 = 0.f, a4 = 0.f, a5 = 0.f, a6 = 0.f, a7 = 0.f;
    for (int i = b + half; i < e_; i += 2) {
        int s = adjS[i];
        uint4 ku = ku4[(size_t)s * 32 + hl];
        float p = q0 * bflo(ku.x) + q1 * bfhi(ku.x) + q2 * bflo(ku.y) + q3 * bfhi(ku.y)
                + q4 * bflo(ku.z) + q5 * bfhi(ku.z) + q6 * bflo(ku.w) + q7 * bfhi(ku.w);
        p += __shfl_xor(p, 1); p += __shfl_xor(p, 2); p += __shfl_xor(p, 4);
        p += __shfl_xor(p, 8); p += __shfl_xor(p, 16);
        p *= 0.0625f;
        uint4 vu = vu4[(size_t)s * 32 + hl];
        float mn = fmaxf(m, p);
        float scale = exp2f((m - mn) * LOG2E);
        float w = exp2f((p - mn) * LOG2E);
        m = mn;
        srun = srun * scale + w;
        a0 = a0 * scale + w * bflo(vu.x); a1 = a1 * scale + w * bfhi(vu.x);
        a2 = a2 * scale + w * bflo(vu.y); a3 = a3 * scale + w * bfhi(vu.y);
        a4 = a4 * scale + w * bflo(vu.z); a5 = a5 * scale + w * bfhi(vu.z);
        a6 = a6 * scale + w * bflo(vu.w); a7 = a7 * scale + w * bfhi(vu.w);
    }
    float mo = __shfl_xor(m, 32);
    float so = __shfl_xor(srun, 32);
    float mn = fmaxf(m, mo);
    float cs = exp2f((m - mn) * LOG2E);
    float co = exp2f((mo - mn) * LOG2E);
    float st = srun * cs + so * co;
    float inv = 1.f / (st + 1e-16f);
    float o0 = (a0 * cs + __shfl_xor(a0, 32) * co) * inv + nr0;
    float o1 = (a1 * cs + __shfl_xor(a1, 32) * co) * inv + nr1;
    float o2 = (a2 * cs + __shfl_xor(a2, 32) * co) * inv + nr2;
    float o3 = (a3 * cs + __shfl_xor(a3, 32) * co) * inv + nr3;
    float o4 = (a4 * cs + __shfl_xor(a4, 32) * co) * inv + nr4;
    float o5 = (a5 * cs + __shfl_xor(a5, 32) * co) * inv + nr5;
    float o6 = (a6 * cs + __shfl_xor(a6, 32) * co) * inv + nr6;
    float o7 = (a7 * cs + __shfl_xor(a7, 32) * co) * inv + nr7;
    if (half == 0) {
        ((float4*)mrow)[2 * hl]     = make_float4(o0, o1, o2, o3);
        ((float4*)mrow)[2 * hl + 1] = make_float4(o4, o5, o6, o7);
    }
}

extern "C" void kernel_launch(void* const* d_in, const int* in_sizes, int n_in,
                              void* d_out, int out_size, void* d_ws, size_t ws_size,
                              hipStream_t stream) {
    (void)in_sizes; (void)n_in; (void)out_size; (void)ws_size;
    const float* x     = (const float*)d_in[0];
    const float* et    = (const float*)d_in[1];
    const int*   Hm    = (const int*)d_in[2];
    const int*   raw   = (const int*)d_in[3];
    const int*   lg    = (const int*)d_in[4];
    const float* W_gat = (const float*)d_in[5];
    const float* a_src = (const float*)d_in[6];
    const float* a_dst = (const float*)d_in[7];
    const float* b_gat = (const float*)d_in[8];
    const float* W_etn = (const float*)d_in[9];
    const float* W_eg  = (const float*)d_in[10];
    const float* Wr_e1 = (const float*)d_in[11];
    const float* Wn_e1 = (const float*)d_in[12];
    const float* b_e1  = (const float*)d_in[13];
    const float* Wr_e2 = (const float*)d_in[14];
    const float* Wn_e2 = (const float*)d_in[15];
    const float* b_e2  = (const float*)d_in[16];
    const float* Wr_n1 = (const float*)d_in[17];
    const float* Wn_n1 = (const float*)d_in[18];
    const float* b_n1  = (const float*)d_in[19];
    const float* Wr_n2 = (const float*)d_in[20];
    const float* Wn_n2 = (const float*)d_in[21];
    const float* b_n2  = (const float*)d_in[22];
    const float* Wr_n3 = (const float*)d_in[23];
    const float* Wn_n3 = (const float*)d_in[24];
    const float* b_n3  = (const float*)d_in[25];
    const float* Wq    = (const float*)d_in[26];
    const float* Wk    = (const float*)d_in[27];
    const float* Wv    = (const float*)d_in[28];
    const float* W_out = (const float*)d_in[29];

    const int* srcN = raw;
    const int* dstN = raw + EE;
    const int* lgs  = lg;
    const int* lgd  = lg + ELG;

    float* ws = (float*)d_ws;
    size_t off = 0;
    auto alloc = [&](size_t n) { float* p = ws + off; off += (n + 63) & ~(size_t)63; return p; };
    auto allocU = [&](size_t nus) { return (unsigned short*)alloc(nus / 2 + 64); };

    unsigned short* et_bf   = allocU((size_t)EE * FE);
    unsigned short* agg_et  = allocU((size_t)EE * FE);   // reused later as q/k/v
    float* es     = alloc(EE);
    float* ed     = alloc(EE);
    float* alphaS = alloc(EE);
    float* alphaL = alloc(ELG);
    float* Wcomb  = alloc((size_t)FE * HD);
    float* b2     = alloc(HD);
    float* asv    = alloc(FE);
    float* adv    = alloc(FE);
    unsigned short* agg2_bf = allocU((size_t)NN * FE);
    float* degE   = alloc(NN);
    unsigned short* etnL  = allocU((size_t)NN * HD);
    unsigned short* erep  = allocU((size_t)NN * HD);
    unsigned short* meanb = allocU((size_t)NN * HD);
    unsigned short* t1    = allocU((size_t)NN * HD);
    unsigned short* aggr  = allocU((size_t)NN * HD);
    unsigned short* nrep  = allocU((size_t)NN * HD);
    unsigned short* x_bf  = allocU((size_t)NN * HD);
    float* mixed  = alloc((size_t)NN * HD);
    unsigned short* wtb    = allocU((size_t)14 * 65536);
    unsigned short* wcombt = allocU((size_t)HD * FE);
    int* rowptrD  = (int*)alloc(NN + 64);
    int* cursD    = (int*)alloc(NN);
    int* adjS     = (int*)alloc(EE);
    int* rowptrLG = (int*)alloc(EE + 64);
    int* cursLG   = (int*)alloc(EE);
    int* adjLG    = (int*)alloc(ELG);
    int* rowptrH  = (int*)alloc(NN + 64);
    int* cursH    = (int*)alloc(NN);
    int* adjH     = (int*)alloc(2 * EE);
    int* cntAll   = (int*)alloc(NTOTC + 64);
    int* scanAll  = (int*)alloc(NTOTC + 64);
    int* bsum     = (int*)alloc(1024);
    // aliases (lifetime-checked)
    unsigned short* ta = etnL;                 // etnL dead after erep GEMM
    unsigned short* tb = erep;                 // erep dead after edge layer 1
    unsigned short* qb = agg_et;               // agg_et dead after etn_gather
    unsigned short* kb = agg_et + (size_t)NN * HD;
    unsigned short* vb = agg_et + (size_t)2 * NN * HD;
    float* outp = (float*)d_out;

    unsigned short* W_eg_t  = wtb + 0 * 65536;
    unsigned short* Wr_e1_t = wtb + 1 * 65536;
    unsigned short* Wn_e1_t = wtb + 2 * 65536;
    unsigned short* Wr_e2_t = wtb + 3 * 65536;
    unsigned short* Wn_e2_t = wtb + 4 * 65536;
    unsigned short* Wr_n1_t = wtb + 5 * 65536;
    unsigned short* Wn_n1_t = wtb + 6 * 65536;
    unsigned short* Wr_n2_t = wtb + 7 * 65536;
    unsigned short* Wn_n2_t = wtb + 8 * 65536;
    unsigned short* Wr_n3_t = wtb + 9 * 65536;
    unsigned short* Wn_n3_t = wtb + 10 * 65536;
    unsigned short* Wq_t    = wtb + 11 * 65536;
    unsigned short* Wk_t    = wtb + 12 * 65536;
    unsigned short* Wv_t    = wtb + 13 * 65536;

    dim3 gB(4, (NN + 127) / 128);

    // ======== weight conversion + x conversion ========
    Ptr14 p14;
    p14.p[0] = W_eg;  p14.p[1] = Wr_e1; p14.p[2] = Wn_e1; p14.p[3] = Wr_e2;
    p14.p[4] = Wn_e2; p14.p[5] = Wr_n1; p14.p[6] = Wn_n1; p14.p[7] = Wr_n2;
    p14.p[8] = Wn_n2; p14.p[9] = Wr_n3; p14.p[10] = Wn_n3; p14.p[11] = Wq;
    p14.p[12] = Wk;   p14.p[13] = Wv;
    wtrans14<<<14 * 64, 256, 0, stream>>>(p14, wtb);
    conv_bf16<<<(NN * HD / 2 + 255) / 256, 256, 0, stream>>>(x, (unsigned int*)x_bf, NN * HD / 2);

    // ======== consolidated CSR build (7 launches) ========
    zero_i32<<<(NTOTC + 255) / 256, 256, 0, stream>>>(cntAll, NTOTC);
    count_all<<<(NIDX + 255) / 256, 256, 0, stream>>>(dstN, lgd, Hm, cntAll);
    {
        int nb = (NTOTC + 1023) / 1024;
        scan_pass1<<<nb, 256, 0, stream>>>(cntAll, bsum, NTOTC);
        scan_pass2<<<1, 256, 0, stream>>>(bsum, nb);
        scan_pass3<<<nb, 256, 0, stream>>>(cntAll, bsum, scanAll, NTOTC);
    }
    rebase_all<<<(NTOTC + 255) / 256, 256, 0, stream>>>(scanAll, rowptrD, cursD,
                                                        rowptrLG, cursLG, rowptrH, cursH);
    place_all<<<(NIDX + 255) / 256, 256, 0, stream>>>(srcN, dstN, lgs, lgd, Hm,
                                                      cursD, cursLG, cursH, adjS, adjLG, adjH);

    // ======== GAT (folded Wcomb = W_gat@W_etn) ========
    gemm_f32<<<dim3(4, 1), 256, 0, stream>>>(W_gat, W_etn, Wcomb, FE, HD, HD);
    wtrans_one<<<(FE / 32) * (HD / 32), 256, 0, stream>>>(Wcomb, wcombt, FE, HD);
    gat_prep<<<FE + 1, 256, 0, stream>>>(W_gat, a_src, a_dst, b_gat, W_etn, asv, adv, b2);
    edge_scores_conv<<<EE / 4, 256, 0, stream>>>(et, asv, adv, es, ed, et_bf);
    seg_alpha<<<(EE + 255) / 256, 256, 0, stream>>>(rowptrLG, adjLG, es, ed, alphaS, alphaL);
    gat_gather3<<<EE / 32, 256, 0, stream>>>(rowptrLG, adjLG, alphaS, alphaL, et_bf, agg_et);

    // ======== EdgeToNode incidence mean + GEMMs ========
    etn_gather2<<<(NN + 15) / 16, 256, 0, stream>>>(rowptrH, adjH, agg_et, agg2_bf, degE);
    gemm_bf16<<<gB, 256, 0, stream>>>(agg2_bf, nullptr, wcombt, nullptr, b2, degE, etnL, NN, FE, 4);
    gemm_bf16<<<gB, 256, 0, stream>>>(etnL, nullptr, W_eg_t, nullptr, nullptr, nullptr, erep, NN, HD, 0);

    // ======== edge_aggr SAGE (2 layers, dual-K fused) ========
    sage_gather2<<<(NN + 7) / 8, 256, 0, stream>>>(erep, rowptrD, adjS, meanb);
    gemm_bf16<<<gB, 256, 0, stream>>>(erep, meanb, Wr_e1_t, Wn_e1_t, b_e1, nullptr, t1, NN, HD, 1);
    sage_gather2<<<(NN + 7) / 8, 256, 0, stream>>>(t1, rowptrD, adjS, meanb);
    gemm_bf16<<<gB, 256, 0, stream>>>(t1, meanb, Wr_e2_t, Wn_e2_t, b_e2, nullptr, aggr, NN, HD, 0);

    // ======== attr_node SAGE (3 layers, dual-K fused) ========
    sage_gather2<<<(NN + 7) / 8, 256, 0, stream>>>(x_bf, rowptrD, adjS, meanb);
    gemm_bf16<<<gB, 256, 0, stream>>>(x_bf, meanb, Wr_n1_t, Wn_n1_t, b_n1, nullptr, ta, NN, HD, 1);
    sage_gather2<<<(NN + 7) / 8, 256, 0, stream>>>(ta, rowptrD, adjS, meanb);
    gemm_bf16<<<gB, 256, 0, stream>>>(ta, meanb, Wr_n2_t, Wn_n2_t, b_n2, nullptr, tb, NN, HD, 1);
    sage_gather2<<<(NN + 7) / 8, 256, 0, stream>>>(tb, rowptrD, adjS, meanb);
    gemm_bf16<<<gB, 256, 0, stream>>>(tb, meanb, Wr_n3_t, Wn_n3_t, b_n3, nullptr, nrep, NN, HD, 0);

    // ======== MixAttention (q,k,v in ONE launch) ========
    gemm_bf16_tri<<<dim3(12, (NN + 127) / 128), 256, 0, stream>>>(
        nrep, Wq_t, qb, aggr, Wk_t, kb, aggr, Wv_t, vb, NN);
    attn_online<<<(NN + 3) / 4, 256, 0, stream>>>(qb, kb, vb, nrep, rowptrD, adjS, mixed);

    // ======== final linear + log_softmax (fused) ========
    gemm_out_lsm<<<dim3(1, (NN + 63) / 64), 256, 0, stream>>>(mixed, W_out, outp, NN);
}

// Round 8
// 852.217 us; speedup vs baseline: 4.2339x; 1.0371x over previous
//
#include <hip/hip_runtime.h>
#include <math.h>

#define NN   20000
#define EE   320000
#define ELG  600000
#define FE   64
#define HD   256
#define FOUT 40
#define LOG2E 1.44269504f
#define NTOTC (NN + EE + NN)            // concatenated count-buffer size
#define NIDX  (EE + ELG + 2 * EE)       // concatenated index-stream size
#define RD_RANGE  ((NN + 7) / 8)        // 2500 keys per XCD range (D and H sections)
#define RLG_RANGE ((EE + 7) / 8)        // 40000 keys per XCD range (LG section)
#define PCHUNK 4096

typedef __attribute__((ext_vector_type(8))) short bf16x8;
typedef __attribute__((ext_vector_type(4))) float f32x4;

__device__ __forceinline__ float leaky02(float x) { return x > 0.f ? x : 0.2f * x; }

__device__ __forceinline__ unsigned short bf16rne(float f) {
    unsigned int u = __float_as_uint(f);
    u = (u + 0x7FFFu + ((u >> 16) & 1u)) >> 16;
    return (unsigned short)u;
}
__device__ __forceinline__ float bflo(unsigned int u) { return __uint_as_float(u << 16); }
__device__ __forceinline__ float bfhi(unsigned int u) { return __uint_as_float(u & 0xffff0000u); }
__device__ __forceinline__ unsigned int bfpack(float a, float b) {
    return (unsigned int)bf16rne(a) | ((unsigned int)bf16rne(b) << 16);
}

// ---------------- small utility kernels ----------------
__global__ void zero_i32(int* __restrict__ p, int n) {
    int i = blockIdx.x * 256 + threadIdx.x;
    if (i < n) p[i] = 0;
}
__global__ void conv_bf16(const float* __restrict__ in, unsigned int* __restrict__ out, int n2) {
    int i = blockIdx.x * 256 + threadIdx.x;
    if (i < n2) { float2 v = ((const float2*)in)[i]; out[i] = bfpack(v.x, v.y); }
}

// ---------------- consolidated CSR build ----------------
// cntAll sections: [0,NN) = raw-by-dst, [NN,NN+EE) = lg-by-lgd, [NN+EE,NN+EE+NN) = incidence H
__global__ void count_all(const int* __restrict__ dstN, const int* __restrict__ lgd,
                          const int* __restrict__ Hm, int* __restrict__ cntAll) {
    int i = blockIdx.x * 256 + threadIdx.x;
    if (i >= NIDX) return;
    if (i < EE) atomicAdd(&cntAll[dstN[i]], 1);
    else if (i < EE + ELG) atomicAdd(&cntAll[NN + lgd[i - EE]], 1);
    else atomicAdd(&cntAll[NN + EE + Hm[i - EE - ELG]], 1);
}

__global__ void scan_pass1(const int* __restrict__ in, int* __restrict__ bsum, int n) {
    __shared__ int sm[256];
    int base = blockIdx.x * 1024, t = threadIdx.x;
    int s = 0;
#pragma unroll
    for (int j = 0; j < 4; ++j) { int i = base + t * 4 + j; s += (i < n) ? in[i] : 0; }
    sm[t] = s; __syncthreads();
    for (int o = 128; o > 0; o >>= 1) { if (t < o) sm[t] += sm[t + o]; __syncthreads(); }
    if (t == 0) bsum[blockIdx.x] = sm[0];
}
__global__ void scan_pass2(int* __restrict__ bsum, int nb) {
    __shared__ int sm[1024];
    int t = threadIdx.x;
    for (int i = t; i < nb; i += 256) sm[i] = bsum[i];
    __syncthreads();
    if (t == 0) { int run = 0; for (int i = 0; i < nb; ++i) { int v = sm[i]; sm[i] = run; run += v; } }
    __syncthreads();
    for (int i = t; i < nb; i += 256) bsum[i] = sm[i];
}
__global__ void scan_pass3(const int* __restrict__ in, const int* __restrict__ boff,
                           int* __restrict__ out, int n) {
    __shared__ int tsum[256];
    int base = blockIdx.x * 1024, t = threadIdx.x;
    int v[4];
#pragma unroll
    for (int j = 0; j < 4; ++j) { int i = base + t * 4 + j; v[j] = (i < n) ? in[i] : 0; }
    int loc = v[0] + v[1] + v[2] + v[3];
    tsum[t] = loc; __syncthreads();
    for (int o = 1; o < 256; o <<= 1) {
        int x = (t >= o) ? tsum[t - o] : 0;
        __syncthreads();
        tsum[t] += x;
        __syncthreads();
    }
    int off = boff[blockIdx.x] + (tsum[t] - loc);
    int run = 0;
#pragma unroll
    for (int j = 0; j < 4; ++j) { int i = base + t * 4 + j; if (i < n) out[i] = off + run; run += v[j]; }
}

// section-rebased rowptr + cursor init (one pass)
__global__ void rebase_all(const int* __restrict__ scanAll,
                           int* __restrict__ rowptrD, int* __restrict__ cursD,
                           int* __restrict__ rowptrLG, int* __restrict__ cursLG,
                           int* __restrict__ rowptrH, int* __restrict__ cursH) {
    int i = blockIdx.x * 256 + threadIdx.x;
    if (i == 0) { rowptrD[NN] = EE; rowptrLG[EE] = ELG; rowptrH[NN] = 2 * EE; }
    if (i >= NTOTC) return;
    if (i < NN) { int v = scanAll[i]; rowptrD[i] = v; cursD[i] = v; }
    else if (i < NN + EE) { int v = scanAll[i] - EE; rowptrLG[i - NN] = v; cursLG[i - NN] = v; }
    else { int v = scanAll[i] - (EE + ELG); rowptrH[i - NN - EE] = v; cursH[i - NN - EE] = v; }
}

// XCD-range-filtered placement: block (chunk, r=blockIdx&7) processes chunk elements whose
// key falls in range r. All writes to a given adj region come from one blockIdx%8 class
// (-> one XCD under round-robin dispatch) so partial cachelines merge in a single L2.
// Correctness does NOT depend on the XCD mapping; every element is placed exactly once.
__global__ void place_ranged(const int* __restrict__ srcN, const int* __restrict__ dstN,
                             const int* __restrict__ lgs, const int* __restrict__ lgd,
                             const int* __restrict__ Hm,
                             int* __restrict__ cursD, int* __restrict__ cursLG, int* __restrict__ cursH,
                             int* __restrict__ adjS, int* __restrict__ adjLG, int* __restrict__ adjH) {
    int r = blockIdx.x & 7;
    int chunk = blockIdx.x >> 3;
    int beg = chunk * PCHUNK + threadIdx.x;
    int end = chunk * PCHUNK + PCHUNK;
    if (end > NIDX) end = NIDX;
    for (int i = beg; i < end; i += 256) {
        if (i < EE) {
            int key = dstN[i];
            if (key / RD_RANGE == r) {
                int pos = atomicAdd(&cursD[key], 1);
                adjS[pos] = srcN[i];
            }
        } else if (i < EE + ELG) {
            int j = i - EE;
            int key = lgd[j];
            if (key / RLG_RANGE == r) {
                int pos = atomicAdd(&cursLG[key], 1);
                adjLG[pos] = lgs[j];
            }
        } else {
            int j = i - EE - ELG;
            int key = Hm[j];
            if (key / RD_RANGE == r) {
                int pos = atomicAdd(&cursH[key], 1);
                adjH[pos] = (j < EE) ? j : j - EE;
            }
        }
    }
}

// ---------------- weight transpose+convert ----------------
struct Ptr14 { const float* p[14]; };
__global__ void wtrans14(Ptr14 srcs, unsigned short* __restrict__ dst) {
    int m = blockIdx.x >> 6;
    int tile = blockIdx.x & 63;
    const float* src = srcs.p[m];
    unsigned short* out = dst + (size_t)m * 65536;
    int kb = (tile >> 3) * 32, nb = (tile & 7) * 32;
    __shared__ float sm[32][33];
    int t = threadIdx.x;
#pragma unroll
    for (int i = 0; i < 4; ++i) {
        int e = t + i * 256; int r = e >> 5, c = e & 31;
        sm[r][c] = src[(kb + r) * 256 + nb + c];
    }
    __syncthreads();
#pragma unroll
    for (int i = 0; i < 4; ++i) {
        int e = t + i * 256; int nr = e >> 5, kc = e & 31;
        out[(size_t)(nb + nr) * 256 + kb + kc] = bf16rne(sm[kc][nr]);
    }
}
__global__ void wtrans_one(const float* __restrict__ src, unsigned short* __restrict__ dst,
                           int K, int N) {
    int tilesN = N >> 5;
    int kb = (blockIdx.x / tilesN) * 32, nb = (blockIdx.x % tilesN) * 32;
    __shared__ float sm[32][33];
    int t = threadIdx.x;
#pragma unroll
    for (int i = 0; i < 4; ++i) {
        int e = t + i * 256; int r = e >> 5, c = e & 31;
        sm[r][c] = src[(kb + r) * N + nb + c];
    }
    __syncthreads();
#pragma unroll
    for (int i = 0; i < 4; ++i) {
        int e = t + i * 256; int nr = e >> 5, kc = e & 31;
        dst[(size_t)(nb + nr) * K + kb + kc] = bf16rne(sm[kc][nr]);
    }
}

// ---------------- bf16 MFMA GEMM ----------------
// flags: 1=relu, 4=degE-mask + leaky
__global__ __launch_bounds__(256)
void gemm_bf16(const unsigned short* __restrict__ A1, const unsigned short* __restrict__ A2,
               const unsigned short* __restrict__ W1, const unsigned short* __restrict__ W2,
               const float* __restrict__ bias, const float* __restrict__ degmask,
               unsigned short* __restrict__ C, int M, int K1, int flags) {
    __shared__ unsigned short As[128][40];
    __shared__ unsigned short Bs[64][40];
    int tid = threadIdx.x;
    int w = tid >> 6, l = tid & 63;
    int wr = w >> 1, wc = w & 1;
    int brow = blockIdx.y * 128, bcol = blockIdx.x * 64;
    int Ktot = K1 + (A2 ? 256 : 0);
    f32x4 acc[4][2] = {};
    for (int k0 = 0; k0 < Ktot; k0 += 32) {
        const unsigned short* Ap; const unsigned short* Wp; int kk, Klen;
        if (k0 < K1) { Ap = A1; Wp = W1; kk = k0; Klen = K1; }
        else         { Ap = A2; Wp = W2; kk = k0 - K1; Klen = 256; }
#pragma unroll
        for (int i = 0; i < 4; ++i) {
            int q = tid + i * 256;
            int r = q >> 3, kb = (q & 7) * 4;
            int gr = brow + r;
            ushort4 u;
            if (gr < M) u = *(const ushort4*)(Ap + (size_t)gr * Klen + kk + kb);
            else { u.x = 0; u.y = 0; u.z = 0; u.w = 0; }
            *(ushort4*)(&As[r][kb]) = u;
        }
#pragma unroll
        for (int i = 0; i < 2; ++i) {
            int q = tid + i * 256;
            int n = q >> 3, kb = (q & 7) * 4;
            *(ushort4*)(&Bs[n][kb]) = *(const ushort4*)(Wp + (size_t)(bcol + n) * Klen + kk + kb);
        }
        __syncthreads();
        bf16x8 af[4], bfr[2];
#pragma unroll
        for (int fr = 0; fr < 4; ++fr)
            af[fr] = *(const bf16x8*)(&As[wr * 64 + fr * 16 + (l & 15)][(l >> 4) * 8]);
#pragma unroll
        for (int fc = 0; fc < 2; ++fc)
            bfr[fc] = *(const bf16x8*)(&Bs[wc * 32 + fc * 16 + (l & 15)][(l >> 4) * 8]);
#pragma unroll
        for (int fr = 0; fr < 4; ++fr)
#pragma unroll
            for (int fc = 0; fc < 2; ++fc)
                acc[fr][fc] = __builtin_amdgcn_mfma_f32_16x16x32_bf16(af[fr], bfr[fc], acc[fr][fc], 0, 0, 0);
        __syncthreads();
    }
#pragma unroll
    for (int fr = 0; fr < 4; ++fr) {
#pragma unroll
        for (int fc = 0; fc < 2; ++fc) {
            int col = bcol + wc * 32 + fc * 16 + (l & 15);
#pragma unroll
            for (int i = 0; i < 4; ++i) {
                int row = brow + wr * 64 + fr * 16 + (l >> 4) * 4 + i;
                if (row >= M) continue;
                float v = acc[fr][fc][i];
                if (bias) v += bias[col];
                if (flags & 1) v = fmaxf(v, 0.f);
                if (flags & 4) { v = (degmask[row] > 0.f) ? v : 0.f; v = leaky02(v); }
                C[(size_t)row * 256 + col] = bf16rne(v);
            }
        }
    }
}

// three single-K GEMMs in one launch
__global__ __launch_bounds__(256)
void gemm_bf16_tri(const unsigned short* __restrict__ A0, const unsigned short* __restrict__ W0,
                   unsigned short* __restrict__ C0,
                   const unsigned short* __restrict__ A1, const unsigned short* __restrict__ W1,
                   unsigned short* __restrict__ C1,
                   const unsigned short* __restrict__ A2, const unsigned short* __restrict__ W2,
                   unsigned short* __restrict__ C2, int M) {
    __shared__ unsigned short As[128][40];
    __shared__ unsigned short Bs[64][40];
    int sel = blockIdx.x >> 2;
    const unsigned short* A = (sel == 0) ? A0 : (sel == 1) ? A1 : A2;
    const unsigned short* W = (sel == 0) ? W0 : (sel == 1) ? W1 : W2;
    unsigned short* C = (sel == 0) ? C0 : (sel == 1) ? C1 : C2;
    int tid = threadIdx.x;
    int w = tid >> 6, l = tid & 63;
    int wr = w >> 1, wc = w & 1;
    int brow = blockIdx.y * 128, bcol = (blockIdx.x & 3) * 64;
    f32x4 acc[4][2] = {};
    for (int k0 = 0; k0 < 256; k0 += 32) {
#pragma unroll
        for (int i = 0; i < 4; ++i) {
            int q = tid + i * 256;
            int r = q >> 3, kb = (q & 7) * 4;
            int gr = brow + r;
            ushort4 u;
            if (gr < M) u = *(const ushort4*)(A + (size_t)gr * 256 + k0 + kb);
            else { u.x = 0; u.y = 0; u.z = 0; u.w = 0; }
            *(ushort4*)(&As[r][kb]) = u;
        }
#pragma unroll
        for (int i = 0; i < 2; ++i) {
            int q = tid + i * 256;
            int n = q >> 3, kb = (q & 7) * 4;
            *(ushort4*)(&Bs[n][kb]) = *(const ushort4*)(W + (size_t)(bcol + n) * 256 + k0 + kb);
        }
        __syncthreads();
        bf16x8 af[4], bfr[2];
#pragma unroll
        for (int fr = 0; fr < 4; ++fr)
            af[fr] = *(const bf16x8*)(&As[wr * 64 + fr * 16 + (l & 15)][(l >> 4) * 8]);
#pragma unroll
        for (int fc = 0; fc < 2; ++fc)
            bfr[fc] = *(const bf16x8*)(&Bs[wc * 32 + fc * 16 + (l & 15)][(l >> 4) * 8]);
#pragma unroll
        for (int fr = 0; fr < 4; ++fr)
#pragma unroll
            for (int fc = 0; fc < 2; ++fc)
                acc[fr][fc] = __builtin_amdgcn_mfma_f32_16x16x32_bf16(af[fr], bfr[fc], acc[fr][fc], 0, 0, 0);
        __syncthreads();
    }
#pragma unroll
    for (int fr = 0; fr < 4; ++fr) {
#pragma unroll
        for (int fc = 0; fc < 2; ++fc) {
            int col = bcol + wc * 32 + fc * 16 + (l & 15);
#pragma unroll
            for (int i = 0; i < 4; ++i) {
                int row = brow + wr * 64 + fr * 16 + (l >> 4) * 4 + i;
                if (row >= M) continue;
                C[(size_t)row * 256 + col] = bf16rne(acc[fr][fc][i]);
            }
        }
    }
}

// ---------------- fp32 GEMM (Wcomb build only) ----------------
__global__ __launch_bounds__(256)
void gemm_f32(const float* __restrict__ A, const float* __restrict__ B,
              float* __restrict__ C, int M, int N, int K) {
    const int BM = 64, BN = 64, BK = 16;
    __shared__ float As[BK][BM + 1];
    __shared__ float Bs[BK][BN + 1];
    int tid = threadIdx.x;
    int tr = tid >> 4, tc = tid & 15;
    int brow = blockIdx.y * BM, bcol = blockIdx.x * BN;
    float acc[4][4] = {{0.f}};
    for (int k0 = 0; k0 < K; k0 += BK) {
#pragma unroll
        for (int i = 0; i < 4; ++i) {
            int e = tid + i * 256;
            int r = e >> 4, c = e & 15;
            int gr = brow + r, gc = k0 + c;
            As[c][r] = (gr < M && gc < K) ? A[(long)gr * K + gc] : 0.f;
        }
#pragma unroll
        for (int i = 0; i < 4; ++i) {
            int e = tid + i * 256;
            int r = e >> 6, c = e & 63;
            int gr = k0 + r, gc = bcol + c;
            Bs[r][c] = (gr < K && gc < N) ? B[(long)gr * N + gc] : 0.f;
        }
        __syncthreads();
#pragma unroll
        for (int k = 0; k < BK; ++k) {
            float ra[4], rb[4];
#pragma unroll
            for (int i = 0; i < 4; ++i) ra[i] = As[k][tr * 4 + i];
#pragma unroll
            for (int j = 0; j < 4; ++j) rb[j] = Bs[k][tc * 4 + j];
#pragma unroll
            for (int i = 0; i < 4; ++i)
#pragma unroll
                for (int j = 0; j < 4; ++j) acc[i][j] += ra[i] * rb[j];
        }
        __syncthreads();
    }
#pragma unroll
    for (int i = 0; i < 4; ++i) {
        int gr = brow + tr * 4 + i;
        if (gr >= M) continue;
#pragma unroll
        for (int j = 0; j < 4; ++j) {
            int gc = bcol + tc * 4 + j;
            if (gc < N) C[(long)gr * N + gc] = acc[i][j];
        }
    }
}

// ---------------- final linear + log_softmax fused ----------------
__global__ __launch_bounds__(256)
void gemm_out_lsm(const float* __restrict__ A, const float* __restrict__ B,
                  float* __restrict__ out, int M) {
    const int BK = 16;
    __shared__ float As[BK][65];
    __shared__ float Bs[BK][65];
    __shared__ float tile[64][41];
    __shared__ float lsb[64];
    int tid = threadIdx.x;
    int tr = tid >> 4, tc = tid & 15;
    int brow = blockIdx.y * 64;
    float acc[4][4] = {{0.f}};
    for (int k0 = 0; k0 < 256; k0 += BK) {
#pragma unroll
        for (int i = 0; i < 4; ++i) {
            int e = tid + i * 256;
            int r = e >> 4, c = e & 15;
            int gr = brow + r;
            As[c][r] = (gr < M) ? A[(long)gr * 256 + k0 + c] : 0.f;
        }
#pragma unroll
        for (int i = 0; i < 4; ++i) {
            int e = tid + i * 256;
            int r = e >> 6, c = e & 63;
            Bs[r][c] = (c < FOUT) ? B[(long)(k0 + r) * FOUT + c] : 0.f;
        }
        __syncthreads();
#pragma unroll
        for (int k = 0; k < BK; ++k) {
            float ra[4], rb[4];
#pragma unroll
            for (int i = 0; i < 4; ++i) ra[i] = As[k][tr * 4 + i];
#pragma unroll
            for (int j = 0; j < 4; ++j) rb[j] = Bs[k][tc * 4 + j];
#pragma unroll
            for (int i = 0; i < 4; ++i)
#pragma unroll
                for (int j = 0; j < 4; ++j) acc[i][j] += ra[i] * rb[j];
        }
        __syncthreads();
    }
#pragma unroll
    for (int i = 0; i < 4; ++i)
#pragma unroll
        for (int j = 0; j < 4; ++j) {
            int gc = tc * 4 + j;
            if (gc < FOUT) tile[tr * 4 + i][gc] = acc[i][j];
        }
    __syncthreads();
    if (tid < 64) {
        int gr = brow + tid;
        float mx = -INFINITY;
        if (gr < M) {
            for (int c = 0; c < FOUT; ++c) mx = fmaxf(mx, tile[tid][c]);
            float s = 0.f;
            for (int c = 0; c < FOUT; ++c) s += __expf(tile[tid][c] - mx);
            lsb[tid] = mx + logf(s);
        }
    }
    __syncthreads();
#pragma unroll
    for (int i = 0; i < 4; ++i) {
        int r = tr * 4 + i;
        int gr = brow + r;
        if (gr >= M) continue;
#pragma unroll
        for (int j = 0; j < 4; ++j) {
            int gc = tc * 4 + j;
            if (gc < FOUT) out[(long)gr * FOUT + gc] = tile[r][gc] - lsb[r];
        }
    }
}

// ---------------- GAT pre-computation (wg_av + bias_proj fused) ----------------
__global__ void gat_prep(const float* __restrict__ W, const float* __restrict__ as_,
                         const float* __restrict__ ad_, const float* __restrict__ b_gat,
                         const float* __restrict__ W_etn,
                         float* __restrict__ asv, float* __restrict__ adv, float* __restrict__ b2) {
    int t = threadIdx.x;
    if (blockIdx.x == FE) {
        float s = 0.f;
        for (int i = 0; i < HD; ++i) s += b_gat[i] * W_etn[i * HD + t];
        b2[t] = s;
        return;
    }
    __shared__ float sm[256];
    int i = blockIdx.x;
    float w = W[i * HD + t];
    sm[t] = w * as_[t];
    __syncthreads();
    for (int o = 128; o > 0; o >>= 1) { if (t < o) sm[t] += sm[t + o]; __syncthreads(); }
    if (t == 0) asv[i] = sm[0];
    __syncthreads();
    sm[t] = w * ad_[t];
    __syncthreads();
    for (int o = 128; o > 0; o >>= 1) { if (t < o) sm[t] += sm[t + o]; __syncthreads(); }
    if (t == 0) adv[i] = sm[0];
}

__global__ void edge_scores_conv(const float* __restrict__ et, const float* __restrict__ asv,
                                 const float* __restrict__ adv, float* __restrict__ es,
                                 float* __restrict__ ed, unsigned short* __restrict__ et_bf) {
    int e = blockIdx.x * 4 + (threadIdx.x >> 6);
    int l = threadIdx.x & 63;
    float x = et[(long)e * FE + l];
    et_bf[(long)e * FE + l] = bf16rne(x);
    float vs = x * asv[l];
    float vd = x * adv[l];
    for (int o = 32; o > 0; o >>= 1) { vs += __shfl_down(vs, o); vd += __shfl_down(vd, o); }
    if (l == 0) { es[e] = vs; ed[e] = vd; }
}

// ---------------- GAT: scalar alpha (thread per segment) ----------------
__global__ void seg_alpha(const int* __restrict__ rowptr, const int* __restrict__ adj,
                          const float* __restrict__ es, const float* __restrict__ ed,
                          float* __restrict__ alphaS, float* __restrict__ alphaL) {
    int d = blockIdx.x * 256 + threadIdx.x;
    if (d >= EE) return;
    int b = rowptr[d], e_ = rowptr[d + 1];
    float edd = ed[d];
    float selfsc = leaky02(es[d] + edd);
    float m = selfsc;
    for (int i = b; i < e_; ++i) m = fmaxf(m, leaky02(es[adj[i]] + edd));
    float s = __expf(selfsc - m);
    for (int i = b; i < e_; ++i) s += __expf(leaky02(es[adj[i]] + edd) - m);
    float inv = 1.f / (s + 1e-16f);
    alphaS[d] = __expf(selfsc - m) * inv;
    for (int i = b; i < e_; ++i) alphaL[i] = __expf(leaky02(es[adj[i]] + edd) - m) * inv;
}

// ---------------- GAT: weighted gather (8-lane group, prefetched) ----------------
__global__ void gat_gather3(const int* __restrict__ rowptr, const int* __restrict__ adj,
                            const float* __restrict__ alphaS, const float* __restrict__ alphaL,
                            const unsigned short* __restrict__ et_bf,
                            unsigned short* __restrict__ agg_et) {
    int d = blockIdx.x * 32 + (threadIdx.x >> 3);
    int hl = threadIdx.x & 7;                  // row = 8 x uint4 (64 bf16)
    if (d >= EE) return;
    int b = rowptr[d], e_ = rowptr[d + 1];
    const uint4* etu = (const uint4*)et_bf;
    // prefetch first adj entry while handling self
    int i = b;
    float aln = 0.f; uint4 un;
    if (i < e_) { aln = alphaL[i]; un = etu[(size_t)adj[i] * 8 + hl]; }
    float al = alphaS[d];
    uint4 u = etu[(size_t)d * 8 + hl];
    float a0 = al * bflo(u.x), a1 = al * bfhi(u.x), a2 = al * bflo(u.y), a3 = al * bfhi(u.y);
    float a4 = al * bflo(u.z), a5 = al * bfhi(u.z), a6 = al * bflo(u.w), a7 = al * bfhi(u.w);
    while (i < e_) {
        float alc = aln; uint4 uc = un;
        int in = i + 1;
        if (in < e_) { aln = alphaL[in]; un = etu[(size_t)adj[in] * 8 + hl]; }
        a0 += alc * bflo(uc.x); a1 += alc * bfhi(uc.x); a2 += alc * bflo(uc.y); a3 += alc * bfhi(uc.y);
        a4 += alc * bflo(uc.z); a5 += alc * bfhi(uc.z); a6 += alc * bflo(uc.w); a7 += alc * bfhi(uc.w);
        i = in;
    }
    uint4 o;
    o.x = bfpack(a0, a1); o.y = bfpack(a2, a3); o.z = bfpack(a4, a5); o.w = bfpack(a6, a7);
    ((uint4*)agg_et)[(size_t)d * 8 + hl] = o;
}

// ---------------- incidence mean (8-lane group, uint4, prefetched) ----------------
__global__ void etn_gather3(const int* __restrict__ rowptr, const int* __restrict__ adj,
                            const unsigned short* __restrict__ agg_et,
                            unsigned short* __restrict__ agg2, float* __restrict__ degE) {
    int n = blockIdx.x * 32 + (threadIdx.x >> 3);
    int hl = threadIdx.x & 7;
    if (n >= NN) return;
    int b = rowptr[n], e_ = rowptr[n + 1];
    const uint4* au = (const uint4*)agg_et;
    int i = b;
    uint4 un;
    if (i < e_) un = au[(size_t)adj[i] * 8 + hl];
    float a0 = 0.f, a1 = 0.f, a2 = 0.f, a3 = 0.f, a4 = 0.f, a5 = 0.f, a6 = 0.f, a7 = 0.f;
    while (i < e_) {
        uint4 uc = un;
        int in = i + 1;
        if (in < e_) un = au[(size_t)adj[in] * 8 + hl];
        a0 += bflo(uc.x); a1 += bfhi(uc.x); a2 += bflo(uc.y); a3 += bfhi(uc.y);
        a4 += bflo(uc.z); a5 += bfhi(uc.z); a6 += bflo(uc.w); a7 += bfhi(uc.w);
        i = in;
    }
    float deg = (float)(e_ - b);
    float inv = 1.f / fmaxf(deg, 1.f);
    uint4 o;
    o.x = bfpack(a0 * inv, a1 * inv); o.y = bfpack(a2 * inv, a3 * inv);
    o.z = bfpack(a4 * inv, a5 * inv); o.w = bfpack(a6 * inv, a7 * inv);
    ((uint4*)agg2)[(size_t)n * 8 + hl] = o;
    if (hl == 0) degE[n] = deg;
}

// ---------------- SAGE mean (2 nodes/wave, 32-lane halves, prefetched) ----------------
__global__ void sage_gather2(const unsigned short* __restrict__ X, const int* __restrict__ rowptr,
                             const int* __restrict__ adjS, unsigned short* __restrict__ mean) {
    int base = (blockIdx.x * 4 + (threadIdx.x >> 6)) * 2;
    int lane = threadIdx.x & 63;
    int half = lane >> 5, hl = lane & 31;
    int n = base + half;
    if (n >= NN) return;
    int b = rowptr[n], e_ = rowptr[n + 1];
    const uint4* Xu = (const uint4*)X;
    int i = b;
    uint4 un;
    if (i < e_) un = Xu[(size_t)adjS[i] * 32 + hl];
    float a0 = 0.f, a1 = 0.f, a2 = 0.f, a3 = 0.f, a4 = 0.f, a5 = 0.f, a6 = 0.f, a7 = 0.f;
    while (i < e_) {
        uint4 uc = un;
        int in = i + 1;
        if (in < e_) un = Xu[(size_t)adjS[in] * 32 + hl];
        a0 += bflo(uc.x); a1 += bfhi(uc.x); a2 += bflo(uc.y); a3 += bfhi(uc.y);
        a4 += bflo(uc.z); a5 += bfhi(uc.z); a6 += bflo(uc.w); a7 += bfhi(uc.w);
        i = in;
    }
    float inv = 1.f / fmaxf((float)(e_ - b), 1.f);
    uint4 o;
    o.x = bfpack(a0 * inv, a1 * inv); o.y = bfpack(a2 * inv, a3 * inv);
    o.z = bfpack(a4 * inv, a5 * inv); o.w = bfpack(a6 * inv, a7 * inv);
    ((uint4*)mean)[(size_t)n * 32 + hl] = o;
}

// ---------------- MixAttention: online softmax, k/v prefetched 2 ahead ----------------
__global__ void attn_online(const unsigned short* __restrict__ q, const unsigned short* __restrict__ k,
                            const unsigned short* __restrict__ v, const unsigned short* __restrict__ nrep,
                            const int* __restrict__ rowptr, const int* __restrict__ adjS,
                            float* __restrict__ mixed) {
    int n = blockIdx.x * 4 + (threadIdx.x >> 6);
    int lane = threadIdx.x & 63;
    if (n >= NN) return;
    int half = lane >> 5, hl = lane & 31;
    int b = rowptr[n], e_ = rowptr[n + 1];
    const uint4* qu4 = (const uint4*)q;
    const uint4* ku4 = (const uint4*)k;
    const uint4* vu4 = (const uint4*)v;
    const uint4* nu4 = (const uint4*)nrep;
    uint4 nu = nu4[(size_t)n * 32 + hl];
    float nr0 = bflo(nu.x), nr1 = bfhi(nu.x), nr2 = bflo(nu.y), nr3 = bfhi(nu.y);
    float nr4 = bflo(nu.z), nr5 = bfhi(nu.z), nr6 = bflo(nu.w), nr7 = bfhi(nu.w);
    float* mrow = mixed + (size_t)n * HD;
    if (b == e_) {
        if (half == 0) {
            ((float4*)mrow)[2 * hl]     = make_float4(nr0, nr1, nr2, nr3);
            ((float4*)mrow)[2 * hl + 1] = make_float4(nr4, nr5, nr6, nr7);
        }
        return;
    }
    uint4 qv = qu4[(size_t)n * 32 + hl];
    float q0 = bflo(qv.x), q1 = bfhi(qv.x), q2 = bflo(qv.y), q3 = bfhi(qv.y);
    float q4 = bflo(qv.z), q5 = bfhi(qv.z), q6 = bflo(qv.w), q7 = bfhi(qv.w);
    float m = -INFINITY, srun = 0.f;
    float a0 = 0.f, a1 = 0.f, a2 = 0.f, a3 = 0.f, a4 = 0.f, a5 = 0.f, a6 = 0.f, a7 = 0.f;
    int i = b + half;
    uint4 ku, vu;
    if (i < e_) {
        int s0 = adjS[i];
        ku = ku4[(size_t)s0 * 32 + hl];
        vu = vu4[(size_t)s0 * 32 + hl];
    }
    while (i < e_) {
        int in = i + 2;
        uint4 kn, vn;
        if (in < e_) {
            int s1 = adjS[in];
            kn = ku4[(size_t)s1 * 32 + hl];
            vn = vu4[(size_t)s1 * 32 + hl];
        }
        float p = q0 * bflo(ku.x) + q1 * bfhi(ku.x) + q2 * bflo(ku.y) + q3 * bfhi(ku.y)
                + q4 * bflo(ku.z) + q5 * bfhi(ku.z) + q6 * bflo(ku.w) + q7 * bfhi(ku.w);
        p += __shfl_xor(p, 1); p += __shfl_xor(p, 2); p += __shfl_xor(p, 4);
        p += __shfl_xor(p, 8); p += __shfl_xor(p, 16);
        p *= 0.0625f;
        float mn = fmaxf(m, p);
        float scale = exp2f((m - mn) * LOG2E);
        float w = exp2f((p - mn) * LOG2E);
        m = mn;
        srun = srun * scale + w;
        a0 = a0 * scale + w * bflo(vu.x); a1 = a1 * scale + w * bfhi(vu.x);
        a2 = a2 * scale + w * bflo(vu.y); a3 = a3 * scale + w * bfhi(vu.y);
        a4 = a4 * scale + w * bflo(vu.z); a5 = a5 * scale + w * bfhi(vu.z);
        a6 = a6 * scale + w * bflo(vu.w); a7 = a7 * scale + w * bfhi(vu.w);
        i = in; ku = kn; vu = vn;
    }
    float mo = __shfl_xor(m, 32);
    float so = __shfl_xor(srun, 32);
    float mn = fmaxf(m, mo);
    float cs = exp2f((m - mn) * LOG2E);
    float co = exp2f((mo - mn) * LOG2E);
    float st = srun * cs + so * co;
    float inv = 1.f / (st + 1e-16f);
    float o0 = (a0 * cs + __shfl_xor(a0, 32) * co) * inv + nr0;
    float o1 = (a1 * cs + __shfl_xor(a1, 32) * co) * inv + nr1;
    float o2 = (a2 * cs + __shfl_xor(a2, 32) * co) * inv + nr2;
    float o3 = (a3 * cs + __shfl_xor(a3, 32) * co) * inv + nr3;
    float o4 = (a4 * cs + __shfl_xor(a4, 32) * co) * inv + nr4;
    float o5 = (a5 * cs + __shfl_xor(a5, 32) * co) * inv + nr5;
    float o6 = (a6 * cs + __shfl_xor(a6, 32) * co) * inv + nr6;
    float o7 = (a7 * cs + __shfl_xor(a7, 32) * co) * inv + nr7;
    if (half == 0) {
        ((float4*)mrow)[2 * hl]     = make_float4(o0, o1, o2, o3);
        ((float4*)mrow)[2 * hl + 1] = make_float4(o4, o5, o6, o7);
    }
}

extern "C" void kernel_launch(void* const* d_in, const int* in_sizes, int n_in,
                              void* d_out, int out_size, void* d_ws, size_t ws_size,
                              hipStream_t stream) {
    (void)in_sizes; (void)n_in; (void)out_size; (void)ws_size;
    const float* x     = (const float*)d_in[0];
    const float* et    = (const float*)d_in[1];
    const int*   Hm    = (const int*)d_in[2];
    const int*   raw   = (const int*)d_in[3];
    const int*   lg    = (const int*)d_in[4];
    const float* W_gat = (const float*)d_in[5];
    const float* a_src = (const float*)d_in[6];
    const float* a_dst = (const float*)d_in[7];
    const float* b_gat = (const float*)d_in[8];
    const float* W_etn = (const float*)d_in[9];
    const float* W_eg  = (const float*)d_in[10];
    const float* Wr_e1 = (const float*)d_in[11];
    const float* Wn_e1 = (const float*)d_in[12];
    const float* b_e1  = (const float*)d_in[13];
    const float* Wr_e2 = (const float*)d_in[14];
    const float* Wn_e2 = (const float*)d_in[15];
    const float* b_e2  = (const float*)d_in[16];
    const float* Wr_n1 = (const float*)d_in[17];
    const float* Wn_n1 = (const float*)d_in[18];
    const float* b_n1  = (const float*)d_in[19];
    const float* Wr_n2 = (const float*)d_in[20];
    const float* Wn_n2 = (const float*)d_in[21];
    const float* b_n2  = (const float*)d_in[22];
    const float* Wr_n3 = (const float*)d_in[23];
    const float* Wn_n3 = (const float*)d_in[24];
    const float* b_n3  = (const float*)d_in[25];
    const float* Wq    = (const float*)d_in[26];
    const float* Wk    = (const float*)d_in[27];
    const float* Wv    = (const float*)d_in[28];
    const float* W_out = (const float*)d_in[29];

    const int* srcN = raw;
    const int* dstN = raw + EE;
    const int* lgs  = lg;
    const int* lgd  = lg + ELG;

    float* ws = (float*)d_ws;
    size_t off = 0;
    auto alloc = [&](size_t n) { float* p = ws + off; off += (n + 63) & ~(size_t)63; return p; };
    auto allocU = [&](size_t nus) { return (unsigned short*)alloc(nus / 2 + 64); };

    unsigned short* et_bf   = allocU((size_t)EE * FE);
    unsigned short* agg_et  = allocU((size_t)EE * FE);   // reused later as q/k/v
    float* es     = alloc(EE);
    float* ed     = alloc(EE);
    float* alphaS = alloc(EE);
    float* alphaL = alloc(ELG);
    float* Wcomb  = alloc((size_t)FE * HD);
    float* b2     = alloc(HD);
    float* asv    = alloc(FE);
    float* adv    = alloc(FE);
    unsigned short* agg2_bf = allocU((size_t)NN * FE);
    float* degE   = alloc(NN);
    unsigned short* etnL  = allocU((size_t)NN * HD);
    unsigned short* erep  = allocU((size_t)NN * HD);
    unsigned short* meanb = allocU((size_t)NN * HD);
    unsigned short* t1    = allocU((size_t)NN * HD);
    unsigned short* aggr  = allocU((size_t)NN * HD);
    unsigned short* nrep  = allocU((size_t)NN * HD);
    unsigned short* x_bf  = allocU((size_t)NN * HD);
    float* mixed  = alloc((size_t)NN * HD);
    unsigned short* wtb    = allocU((size_t)14 * 65536);
    unsigned short* wcombt = allocU((size_t)HD * FE);
    int* rowptrD  = (int*)alloc(NN + 64);
    int* cursD    = (int*)alloc(NN);
    int* adjS     = (int*)alloc(EE);
    int* rowptrLG = (int*)alloc(EE + 64);
    int* cursLG   = (int*)alloc(EE);
    int* adjLG    = (int*)alloc(ELG);
    int* rowptrH  = (int*)alloc(NN + 64);
    int* cursH    = (int*)alloc(NN);
    int* adjH     = (int*)alloc(2 * EE);
    int* cntAll   = (int*)alloc(NTOTC + 64);
    int* scanAll  = (int*)alloc(NTOTC + 64);
    int* bsum     = (int*)alloc(1024);
    // aliases (lifetime-checked)
    unsigned short* ta = etnL;                 // etnL dead after erep GEMM
    unsigned short* tb = erep;                 // erep dead after edge layer 1
    unsigned short* qb = agg_et;               // agg_et dead after etn_gather
    unsigned short* kb = agg_et + (size_t)NN * HD;
    unsigned short* vb = agg_et + (size_t)2 * NN * HD;
    float* outp = (float*)d_out;

    unsigned short* W_eg_t  = wtb + 0 * 65536;
    unsigned short* Wr_e1_t = wtb + 1 * 65536;
    unsigned short* Wn_e1_t = wtb + 2 * 65536;
    unsigned short* Wr_e2_t = wtb + 3 * 65536;
    unsigned short* Wn_e2_t = wtb + 4 * 65536;
    unsigned short* Wr_n1_t = wtb + 5 * 65536;
    unsigned short* Wn_n1_t = wtb + 6 * 65536;
    unsigned short* Wr_n2_t = wtb + 7 * 65536;
    unsigned short* Wn_n2_t = wtb + 8 * 65536;
    unsigned short* Wr_n3_t = wtb + 9 * 65536;
    unsigned short* Wn_n3_t = wtb + 10 * 65536;
    unsigned short* Wq_t    = wtb + 11 * 65536;
    unsigned short* Wk_t    = wtb + 12 * 65536;
    unsigned short* Wv_t    = wtb + 13 * 65536;

    dim3 gB(4, (NN + 127) / 128);

    // ======== weight conversion + x conversion ========
    Ptr14 p14;
    p14.p[0] = W_eg;  p14.p[1] = Wr_e1; p14.p[2] = Wn_e1; p14.p[3] = Wr_e2;
    p14.p[4] = Wn_e2; p14.p[5] = Wr_n1; p14.p[6] = Wn_n1; p14.p[7] = Wr_n2;
    p14.p[8] = Wn_n2; p14.p[9] = Wr_n3; p14.p[10] = Wn_n3; p14.p[11] = Wq;
    p14.p[12] = Wk;   p14.p[13] = Wv;
    wtrans14<<<14 * 64, 256, 0, stream>>>(p14, wtb);
    conv_bf16<<<(NN * HD / 2 + 255) / 256, 256, 0, stream>>>(x, (unsigned int*)x_bf, NN * HD / 2);

    // ======== consolidated CSR build ========
    zero_i32<<<(NTOTC + 255) / 256, 256, 0, stream>>>(cntAll, NTOTC);
    count_all<<<(NIDX + 255) / 256, 256, 0, stream>>>(dstN, lgd, Hm, cntAll);
    {
        int nb = (NTOTC + 1023) / 1024;
        scan_pass1<<<nb, 256, 0, stream>>>(cntAll, bsum, NTOTC);
        scan_pass2<<<1, 256, 0, stream>>>(bsum, nb);
        scan_pass3<<<nb, 256, 0, stream>>>(cntAll, bsum, scanAll, NTOTC);
    }
    rebase_all<<<(NTOTC + 255) / 256, 256, 0, stream>>>(scanAll, rowptrD, cursD,
                                                        rowptrLG, cursLG, rowptrH, cursH);
    {
        int nch = (NIDX + PCHUNK - 1) / PCHUNK;
        place_ranged<<<nch * 8, 256, 0, stream>>>(srcN, dstN, lgs, lgd, Hm,
                                                  cursD, cursLG, cursH, adjS, adjLG, adjH);
    }

    // ======== GAT (folded Wcomb = W_gat@W_etn) ========
    gemm_f32<<<dim3(4, 1), 256, 0, stream>>>(W_gat, W_etn, Wcomb, FE, HD, HD);
    wtrans_one<<<(FE / 32) * (HD / 32), 256, 0, stream>>>(Wcomb, wcombt, FE, HD);
    gat_prep<<<FE + 1, 256, 0, stream>>>(W_gat, a_src, a_dst, b_gat, W_etn, asv, adv, b2);
    edge_scores_conv<<<EE / 4, 256, 0, stream>>>(et, asv, adv, es, ed, et_bf);
    seg_alpha<<<(EE + 255) / 256, 256, 0, stream>>>(rowptrLG, adjLG, es, ed, alphaS, alphaL);
    gat_gather3<<<EE / 32, 256, 0, stream>>>(rowptrLG, adjLG, alphaS, alphaL, et_bf, agg_et);

    // ======== EdgeToNode incidence mean + GEMMs ========
    etn_gather3<<<(NN + 31) / 32, 256, 0, stream>>>(rowptrH, adjH, agg_et, agg2_bf, degE);
    gemm_bf16<<<gB, 256, 0, stream>>>(agg2_bf, nullptr, wcombt, nullptr, b2, degE, etnL, NN, FE, 4);
    gemm_bf16<<<gB, 256, 0, stream>>>(etnL, nullptr, W_eg_t, nullptr, nullptr, nullptr, erep, NN, HD, 0);

    // ======== edge_aggr SAGE (2 layers, dual-K fused) ========
    sage_gather2<<<(NN + 7) / 8, 256, 0, stream>>>(erep, rowptrD, adjS, meanb);
    gemm_bf16<<<gB, 256, 0, stream>>>(erep, meanb, Wr_e1_t, Wn_e1_t, b_e1, nullptr, t1, NN, HD, 1);
    sage_gather2<<<(NN + 7) / 8, 256, 0, stream>>>(t1, rowptrD, adjS, meanb);
    gemm_bf16<<<gB, 256, 0, stream>>>(t1, meanb, Wr_e2_t, Wn_e2_t, b_e2, nullptr, aggr, NN, HD, 0);

    // ======== attr_node SAGE (3 layers, dual-K fused) ========
    sage_gather2<<<(NN + 7) / 8, 256, 0, stream>>>(x_bf, rowptrD, adjS, meanb);
    gemm_bf16<<<gB, 256, 0, stream>>>(x_bf, meanb, Wr_n1_t, Wn_n1_t, b_n1, nullptr, ta, NN, HD, 1);
    sage_gather2<<<(NN + 7) / 8, 256, 0, stream>>>(ta, rowptrD, adjS, meanb);
    gemm_bf16<<<gB, 256, 0, stream>>>(ta, meanb, Wr_n2_t, Wn_n2_t, b_n2, nullptr, tb, NN, HD, 1);
    sage_gather2<<<(NN + 7) / 8, 256, 0, stream>>>(tb, rowptrD, adjS, meanb);
    gemm_bf16<<<gB, 256, 0, stream>>>(tb, meanb, Wr_n3_t, Wn_n3_t, b_n3, nullptr, nrep, NN, HD, 0);

    // ======== MixAttention (q,k,v in ONE launch) ========
    gemm_bf16_tri<<<dim3(12, (NN + 127) / 128), 256, 0, stream>>>(
        nrep, Wq_t, qb, aggr, Wk_t, kb, aggr, Wv_t, vb, NN);
    attn_online<<<(NN + 3) / 4, 256, 0, stream>>>(qb, kb, vb, nrep, rowptrD, adjS, mixed);

    // ======== final linear + log_softmax (fused) ========
    gemm_out_lsm<<<dim3(1, (NN + 63) / 64), 256, 0, stream>>>(mixed, W_out, outp, NN);
}